// Round 5
// baseline (8366.651 us; speedup 1.0000x reference)
//
#include <hip/hip_runtime.h>
#include <hip/hip_bf16.h>

typedef __hip_bfloat16 bf16;

__device__ __forceinline__ float b2f(bf16 v) { return __bfloat162float(v); }
__device__ __forceinline__ bf16  f2b(float v) { return __float2bfloat16(v); }

#define NB 128   // batch
#define NN 128   // nodes per graph
#define KNN 16   // neighbors
#define M_NODES (NB * NN)          // 16384
#define NPOS ((long)M_NODES * KNN) // 262144 edge rows

// ---------------- zero a small float buffer ----------------
__global__ void zero_kernel(float* __restrict__ p, int n) {
    int i = blockIdx.x * blockDim.x + threadIdx.x;
    if (i < n) p[i] = 0.f;
}

// ---------------- kNN over f32 features -------------------
// x: [M, C] f32, use first D columns. One block per batch, thread i = node i.
__global__ __launch_bounds__(128) void knn_kernel(const float* __restrict__ x, int C, int D,
                                                  int* __restrict__ idx) {
    const int b = blockIdx.x, i = threadIdx.x;
    __shared__ float sf[128 * 65];
    __shared__ float ssq[128];
    float dot[128];
#pragma unroll
    for (int j = 0; j < 128; ++j) dot[j] = 0.f;
    float sqi = 0.f;
    for (int d0 = 0; d0 < D; d0 += 64) {
        int dw = D - d0; if (dw > 64) dw = 64;
        for (int d = 0; d < dw; ++d) sf[i * 65 + d] = x[(size_t)(b * NN + i) * C + d0 + d];
        __syncthreads();
        for (int d = 0; d < dw; ++d) {
            float fi = sf[i * 65 + d];
            sqi += fi * fi;
#pragma unroll
            for (int j = 0; j < 128; ++j) dot[j] += fi * sf[j * 65 + d];
        }
        __syncthreads();
    }
    ssq[i] = sqi;
    __syncthreads();
    unsigned long long sel0 = 0ull, sel1 = 0ull;
    for (int k = 0; k < KNN; ++k) {
        float best = 3.0e38f; int bj = 0;
#pragma unroll
        for (int j = 0; j < 128; ++j) {
            float dj = sqi + ssq[j] - 2.0f * dot[j];
            bool excl = (j == i) || ((j < 64) ? ((sel0 >> j) & 1ull) : ((sel1 >> (j - 64)) & 1ull));
            if (!excl && dj < best) { best = dj; bj = j; }
        }
        if (bj < 64) sel0 |= (1ull << bj); else sel1 |= (1ull << (bj - 64));
        idx[(size_t)(b * NN + i) * KNN + k] = bj;
    }
}

// ---------------- node GEMM: T1 = x@(Wt-Wb)+bias, T2 = x@Wb (all f32) ----------------
// x:[M,F] f32, W:[2F,O] f32. 64x64 tile, 4x4 per thread.
__global__ __launch_bounds__(256) void node_gemm_kernel(const float* __restrict__ x, int F, int O,
                                                        const float* __restrict__ W, const float* __restrict__ bias,
                                                        float* __restrict__ T1, float* __restrict__ T2) {
    __shared__ float As[16][65];  // [k][m]
    __shared__ float Bt[16][65];  // [k][c] top half of W
    __shared__ float Bb[16][65];  // [k][c] bottom half
    const int tid = threadIdx.x;
    const int tx = tid & 15, ty = tid >> 4;
    const int m0 = blockIdx.y * 64, c0 = blockIdx.x * 64;
    float aT[4][4], aB[4][4];
#pragma unroll
    for (int r = 0; r < 4; ++r)
#pragma unroll
        for (int c = 0; c < 4; ++c) { aT[r][c] = 0.f; aB[r][c] = 0.f; }
    for (int k0 = 0; k0 < F; k0 += 16) {
        for (int l = tid; l < 1024; l += 256) {
            int k = l & 15, m = l >> 4;
            int kk = k0 + k;
            As[k][m] = (kk < F) ? x[(size_t)(m0 + m) * F + kk] : 0.f;
        }
        for (int l = tid; l < 1024; l += 256) {
            int c = l & 63, k = l >> 6;
            int kk = k0 + k;
            Bt[k][c] = (kk < F) ? W[(size_t)kk * O + c0 + c] : 0.f;
            Bb[k][c] = (kk < F) ? W[(size_t)(F + kk) * O + c0 + c] : 0.f;
        }
        __syncthreads();
        for (int k = 0; k < 16; ++k) {
            float av[4], bt[4], bb[4];
#pragma unroll
            for (int r = 0; r < 4; ++r) av[r] = As[k][ty + 16 * r];
#pragma unroll
            for (int c = 0; c < 4; ++c) { bt[c] = Bt[k][tx + 16 * c]; bb[c] = Bb[k][tx + 16 * c]; }
#pragma unroll
            for (int r = 0; r < 4; ++r)
#pragma unroll
                for (int c = 0; c < 4; ++c) { aT[r][c] += av[r] * bt[c]; aB[r][c] += av[r] * bb[c]; }
        }
        __syncthreads();
    }
    float bc[4];
#pragma unroll
    for (int c = 0; c < 4; ++c) bc[c] = bias[c0 + tx + 16 * c];
#pragma unroll
    for (int r = 0; r < 4; ++r)
#pragma unroll
        for (int c = 0; c < 4; ++c) {
            size_t m = m0 + ty + 16 * r, cc = c0 + tx + 16 * c;
            T1[m * O + cc] = aT[r][c] - aB[r][c] + bc[c];
            T2[m * O + cc] = aB[r][c];
        }
}

// ---------------- stats of layer-0 output h0 = T1[n] + T2[nbr], never materialized ------
template<int O>
__global__ __launch_bounds__(256) void stats0_kernel(const float* __restrict__ T1,
        const float* __restrict__ T2, const int* __restrict__ idx, float* __restrict__ st0) {
    constexpr int OSH = (O == 64) ? 6 : (O == 128 ? 7 : 8);
    __shared__ float ls[256], lss[256];
    const int t = threadIdx.x;
    const long n = NPOS * O;
    float s = 0.f, ss = 0.f;
    // grid-stride is a multiple of 256 and 256 % O == 0, so channel == t & (O-1) always.
    for (long i = (long)blockIdx.x * 256 + t; i < n; i += (long)gridDim.x * 256) {
        int c = (int)(i & (O - 1));
        long e = i >> OSH;           // edge row
        int nd = (int)(e >> 4);      // node
        int j = idx[e];              // neighbor (node-local)
        int g = ((nd >> 7) << 7) + j;
        float v = T1[(size_t)nd * O + c] + T2[(size_t)g * O + c];
        s += v; ss += v * v;
    }
    ls[t] = s; lss[t] = ss;
    __syncthreads();
    for (int off = 128; off >= O; off >>= 1) {
        if (t < off) { ls[t] += ls[t + off]; lss[t] += lss[t + off]; }
        __syncthreads();
    }
    if (t < O) { atomicAdd(&st0[t], ls[t]); atomicAdd(&st0[O + t], lss[t]); }
}

// ---------------- fused conv stage kernel (recompute pipeline) ----------------
// Per 64-edge-row tile (= 4 nodes x 16 neighbors):
//   A0 = relu(bn0(T1[n] + T2[nbr]))              (built in LDS, bf16)
//   h1 = A0 @ W1 + b1                            (f32 registers)
//   STAGE1: accumulate per-channel sum/sumsq of h1 -> st1, done.
//   A1 = relu(bn1(h1)); h2 = A1 @ W2 + b2
//   STAGE2: accumulate stats of h2 -> st2, done.
//   STAGE3: A2 = relu(bn2(h2)); xnew[n] = [mean_k A2, xold[n]]
template<int O, int STAGE>
__global__ __launch_bounds__(256) void conv_stage_kernel(
    const float* __restrict__ T1, const float* __restrict__ T2, const int* __restrict__ idx,
    const float* __restrict__ W1, const float* __restrict__ bias1,
    const float* __restrict__ W2, const float* __restrict__ bias2,
    const float* __restrict__ gm0, const float* __restrict__ bt0,
    const float* __restrict__ gm1, const float* __restrict__ bt1,
    const float* __restrict__ gm2, const float* __restrict__ bt2,
    const float* __restrict__ st0, float* __restrict__ st1, float* __restrict__ st2,
    const float* __restrict__ xold, float* __restrict__ xnew, int F, float inv_n)
{
    constexpr int NC = O / 16;
    constexpr int OSH = (O == 64) ? 6 : (O == 128 ? 7 : 8);
    __shared__ bf16 As[O][66];          // activations (bf16)
    __shared__ float Bs[16][O + 2];     // weights (f32)
    __shared__ float sc0[O], sh0[O], sc1[O], sh1[O], sc2[O], sh2[O];
    __shared__ int gArr[64];
    const int tid = threadIdx.x;
    const int tx = tid & 15, ty = tid >> 4;
    const int e0 = blockIdx.x * 64;
    const int node0 = e0 >> 4;

    if (tid < O) {
        {
            float mean = st0[tid] * inv_n;
            float var = fmaxf(st0[O + tid] * inv_n - mean * mean, 0.f);
            float r = rsqrtf(var + 1e-5f);
            float s = r * gm0[tid];
            sc0[tid] = s; sh0[tid] = bt0[tid] - mean * s;
        }
        if (STAGE >= 2) {
            float mean = st1[tid] * inv_n;
            float var = fmaxf(st1[O + tid] * inv_n - mean * mean, 0.f);
            float r = rsqrtf(var + 1e-5f);
            float s = r * gm1[tid];
            sc1[tid] = s; sh1[tid] = bt1[tid] - mean * s;
        }
        if (STAGE == 3) {
            float mean = st2[tid] * inv_n;
            float var = fmaxf(st2[O + tid] * inv_n - mean * mean, 0.f);
            float r = rsqrtf(var + 1e-5f);
            float s = r * gm2[tid];
            sc2[tid] = s; sh2[tid] = bt2[tid] - mean * s;
        }
    }
    if (tid < 64) {
        int e = e0 + tid;
        int nd = e >> 4;
        gArr[tid] = ((nd >> 7) << 7) + idx[e];
    }
    __syncthreads();

    // build A0 in LDS
    for (int l = tid; l < 64 * O; l += 256) {
        int m = l >> OSH, c = l & (O - 1);
        int nd = node0 + (m >> 4);
        float v = T1[(size_t)nd * O + c] + T2[(size_t)gArr[m] * O + c];
        v = v * sc0[c] + sh0[c];
        As[c][m] = f2b(fmaxf(v, 0.f));
    }
    float acc[4][NC];
#pragma unroll
    for (int r = 0; r < 4; ++r)
#pragma unroll
        for (int c = 0; c < NC; ++c) acc[r][c] = 0.f;
    __syncthreads();

    // GEMM1: h1 = A0 @ W1
    for (int k0 = 0; k0 < O; k0 += 16) {
        for (int l = tid; l < 16 * O; l += 256) {
            int c = l & (O - 1), k = l >> OSH;
            Bs[k][c] = W1[(size_t)(k0 + k) * O + c];
        }
        __syncthreads();
#pragma unroll
        for (int k = 0; k < 16; ++k) {
            float av[4], bv[NC];
#pragma unroll
            for (int r = 0; r < 4; ++r) av[r] = b2f(As[k0 + k][ty + 16 * r]);
#pragma unroll
            for (int c = 0; c < NC; ++c) bv[c] = Bs[k][tx + 16 * c];
#pragma unroll
            for (int r = 0; r < 4; ++r)
#pragma unroll
                for (int c = 0; c < NC; ++c) acc[r][c] += av[r] * bv[c];
        }
        __syncthreads();
    }
#pragma unroll
    for (int c = 0; c < NC; ++c) {
        float bb = bias1[tx + 16 * c];
#pragma unroll
        for (int r = 0; r < 4; ++r) acc[r][c] += bb;
    }

    if (STAGE == 1) {
        // write h1 tile (transposed) and reduce per-channel stats
#pragma unroll
        for (int r = 0; r < 4; ++r)
#pragma unroll
            for (int c = 0; c < NC; ++c) As[tx + 16 * c][ty + 16 * r] = f2b(acc[r][c]);
        __syncthreads();
        if (tid < O) {
            float s = 0.f, ss = 0.f;
            for (int m = 0; m < 64; ++m) { float v = b2f(As[tid][m]); s += v; ss += v * v; }
            atomicAdd(&st1[tid], s); atomicAdd(&st1[O + tid], ss);
        }
        return;
    }

    // A1 = relu(bn1(h1)) into LDS
#pragma unroll
    for (int r = 0; r < 4; ++r)
#pragma unroll
        for (int c = 0; c < NC; ++c) {
            int col = tx + 16 * c, row = ty + 16 * r;
            float v = acc[r][c] * sc1[col] + sh1[col];
            As[col][row] = f2b(fmaxf(v, 0.f));
        }
#pragma unroll
    for (int r = 0; r < 4; ++r)
#pragma unroll
        for (int c = 0; c < NC; ++c) acc[r][c] = 0.f;
    __syncthreads();

    // GEMM2: h2 = A1 @ W2
    for (int k0 = 0; k0 < O; k0 += 16) {
        for (int l = tid; l < 16 * O; l += 256) {
            int c = l & (O - 1), k = l >> OSH;
            Bs[k][c] = W2[(size_t)(k0 + k) * O + c];
        }
        __syncthreads();
#pragma unroll
        for (int k = 0; k < 16; ++k) {
            float av[4], bv[NC];
#pragma unroll
            for (int r = 0; r < 4; ++r) av[r] = b2f(As[k0 + k][ty + 16 * r]);
#pragma unroll
            for (int c = 0; c < NC; ++c) bv[c] = Bs[k][tx + 16 * c];
#pragma unroll
            for (int r = 0; r < 4; ++r)
#pragma unroll
                for (int c = 0; c < NC; ++c) acc[r][c] += av[r] * bv[c];
        }
        __syncthreads();
    }
#pragma unroll
    for (int c = 0; c < NC; ++c) {
        float bb = bias2[tx + 16 * c];
#pragma unroll
        for (int r = 0; r < 4; ++r) acc[r][c] += bb;
    }

    if (STAGE == 2) {
#pragma unroll
        for (int r = 0; r < 4; ++r)
#pragma unroll
            for (int c = 0; c < NC; ++c) As[tx + 16 * c][ty + 16 * r] = f2b(acc[r][c]);
        __syncthreads();
        if (tid < O) {
            float s = 0.f, ss = 0.f;
            for (int m = 0; m < 64; ++m) { float v = b2f(As[tid][m]); s += v; ss += v * v; }
            atomicAdd(&st2[tid], s); atomicAdd(&st2[O + tid], ss);
        }
        return;
    }

    // STAGE3: A2 = relu(bn2(h2)); mean over k per node; skip-concat xold
#pragma unroll
    for (int r = 0; r < 4; ++r)
#pragma unroll
        for (int c = 0; c < NC; ++c) {
            int col = tx + 16 * c, row = ty + 16 * r;
            float v = acc[r][c] * sc2[col] + sh2[col];
            As[col][row] = f2b(fmaxf(v, 0.f));
        }
    __syncthreads();
    const int Cnew = O + F;
    for (int l = tid; l < 4 * O; l += 256) {
        int nd = l >> OSH, c = l & (O - 1);
        float s = 0.f;
        for (int kk = 0; kk < 16; ++kk) s += b2f(As[c][nd * 16 + kk]);
        xnew[(size_t)(node0 + nd) * Cnew + c] = s * (1.0f / 16.0f);
    }
    for (int l = tid; l < 4 * F; l += 256) {
        int nd = l / F, c = l - nd * F;
        xnew[(size_t)(node0 + nd) * Cnew + O + c] = xold[(size_t)(node0 + nd) * F + c];
    }
}

// ---------------- global mean pool over nodes ----------------
__global__ __launch_bounds__(256) void pool_kernel(const float* __restrict__ x, float* __restrict__ pooled, int C) {
    int b = blockIdx.x, t = threadIdx.x;
    for (int c = t; c < C; c += 256) {
        float s = 0.f;
        for (int n = 0; n < NN; ++n) s += x[(size_t)(b * NN + n) * C + c];
        pooled[b * C + c] = s * (1.0f / NN);
    }
}

// ---------------- fc1 (no act) + fc2 ----------------
__global__ __launch_bounds__(256) void fc_kernel(const float* __restrict__ pooled,
                                                 const float* __restrict__ W1, const float* __restrict__ b1,
                                                 const float* __restrict__ W2, const float* __restrict__ b2,
                                                 float* __restrict__ out, int C) {
    __shared__ float px[451];
    __shared__ float h1[256];
    int b = blockIdx.x, t = threadIdx.x;
    for (int c = t; c < C; c += 256) px[c] = pooled[b * C + c];
    __syncthreads();
    float s = 0.f;
    for (int i = 0; i < C; ++i) s += px[i] * W1[(size_t)i * 256 + t];
    h1[t] = s + b1[t];
    __syncthreads();
    if (t < 5) {
        float s2 = 0.f;
        for (int j = 0; j < 256; ++j) s2 += h1[j] * W2[j * 5 + t];
        out[b * 5 + t] = s2 + b2[t];
    }
}

extern "C" void kernel_launch(void* const* d_in, const int* in_sizes, int n_in,
                              void* d_out, int out_size, void* d_ws, size_t ws_size,
                              hipStream_t stream) {
    const float* xin = (const float*)d_in[0];
    auto Wp = [&](int c, int l) { return (const float*)d_in[1 + c * 12 + l * 4 + 0]; };
    auto Bp = [&](int c, int l) { return (const float*)d_in[1 + c * 12 + l * 4 + 1]; };
    auto Gp = [&](int c, int l) { return (const float*)d_in[1 + c * 12 + l * 4 + 2]; };
    auto Ep = [&](int c, int l) { return (const float*)d_in[1 + c * 12 + l * 4 + 3]; };
    const float* fcW1 = (const float*)d_in[37];
    const float* fcb1 = (const float*)d_in[38];
    const float* fcW2 = (const float*)d_in[39];
    const float* fcb2 = (const float*)d_in[40];

    char* ws = (char*)d_ws;
    size_t off = 0;
    auto alloc = [&](size_t bytes) -> void* {
        void* p = ws + off;
        off += (bytes + 255) & ~(size_t)255;
        return p;
    };
    const int M = M_NODES;
    float* x1     = (float*)alloc((size_t)M * 67 * 4);   //  4.4 MB
    float* x2     = (float*)alloc((size_t)M * 195 * 4);  // 12.8 MB
    float* x3     = (float*)alloc((size_t)M * 451 * 4);  // 29.6 MB
    float* T1     = (float*)alloc((size_t)M * 256 * 4);  // 16.8 MB
    float* T2     = (float*)alloc((size_t)M * 256 * 4);  // 16.8 MB
    int*   idxb   = (int*)alloc((size_t)M * KNN * 4);    //  1.0 MB
    float* stats  = (float*)alloc(1536 * 4);             // st0/st1/st2
    float* pooled = (float*)alloc((size_t)NB * 451 * 4); //  0.23 MB
    (void)ws_size; (void)in_sizes; (void)n_in; (void)out_size; // total ~82 MiB

    float* st0 = stats, *st1 = stats + 512, *st2 = stats + 1024;
    const float inv_n = 1.0f / (float)NPOS;

    auto run_conv = [&](const float* xc, float* xn, int F, int D, int O, int c) {
        knn_kernel<<<NB, NN, 0, stream>>>(xc, F, D, idxb);
        node_gemm_kernel<<<dim3(O / 64, M / 64), 256, 0, stream>>>(xc, F, O, Wp(c, 0), Bp(c, 0), T1, T2);
        zero_kernel<<<6, 256, 0, stream>>>(stats, 1536);
        const int grid = (int)(NPOS / 64);
        if (O == 64) {
            stats0_kernel<64><<<512, 256, 0, stream>>>(T1, T2, idxb, st0);
            conv_stage_kernel<64, 1><<<grid, 256, 0, stream>>>(T1, T2, idxb,
                Wp(c,1), Bp(c,1), Wp(c,2), Bp(c,2), Gp(c,0), Ep(c,0), Gp(c,1), Ep(c,1),
                Gp(c,2), Ep(c,2), st0, st1, st2, xc, xn, F, inv_n);
            conv_stage_kernel<64, 2><<<grid, 256, 0, stream>>>(T1, T2, idxb,
                Wp(c,1), Bp(c,1), Wp(c,2), Bp(c,2), Gp(c,0), Ep(c,0), Gp(c,1), Ep(c,1),
                Gp(c,2), Ep(c,2), st0, st1, st2, xc, xn, F, inv_n);
            conv_stage_kernel<64, 3><<<grid, 256, 0, stream>>>(T1, T2, idxb,
                Wp(c,1), Bp(c,1), Wp(c,2), Bp(c,2), Gp(c,0), Ep(c,0), Gp(c,1), Ep(c,1),
                Gp(c,2), Ep(c,2), st0, st1, st2, xc, xn, F, inv_n);
        } else if (O == 128) {
            stats0_kernel<128><<<512, 256, 0, stream>>>(T1, T2, idxb, st0);
            conv_stage_kernel<128, 1><<<grid, 256, 0, stream>>>(T1, T2, idxb,
                Wp(c,1), Bp(c,1), Wp(c,2), Bp(c,2), Gp(c,0), Ep(c,0), Gp(c,1), Ep(c,1),
                Gp(c,2), Ep(c,2), st0, st1, st2, xc, xn, F, inv_n);
            conv_stage_kernel<128, 2><<<grid, 256, 0, stream>>>(T1, T2, idxb,
                Wp(c,1), Bp(c,1), Wp(c,2), Bp(c,2), Gp(c,0), Ep(c,0), Gp(c,1), Ep(c,1),
                Gp(c,2), Ep(c,2), st0, st1, st2, xc, xn, F, inv_n);
            conv_stage_kernel<128, 3><<<grid, 256, 0, stream>>>(T1, T2, idxb,
                Wp(c,1), Bp(c,1), Wp(c,2), Bp(c,2), Gp(c,0), Ep(c,0), Gp(c,1), Ep(c,1),
                Gp(c,2), Ep(c,2), st0, st1, st2, xc, xn, F, inv_n);
        } else {
            stats0_kernel<256><<<1024, 256, 0, stream>>>(T1, T2, idxb, st0);
            conv_stage_kernel<256, 1><<<grid, 256, 0, stream>>>(T1, T2, idxb,
                Wp(c,1), Bp(c,1), Wp(c,2), Bp(c,2), Gp(c,0), Ep(c,0), Gp(c,1), Ep(c,1),
                Gp(c,2), Ep(c,2), st0, st1, st2, xc, xn, F, inv_n);
            conv_stage_kernel<256, 2><<<grid, 256, 0, stream>>>(T1, T2, idxb,
                Wp(c,1), Bp(c,1), Wp(c,2), Bp(c,2), Gp(c,0), Ep(c,0), Gp(c,1), Ep(c,1),
                Gp(c,2), Ep(c,2), st0, st1, st2, xc, xn, F, inv_n);
            conv_stage_kernel<256, 3><<<grid, 256, 0, stream>>>(T1, T2, idxb,
                Wp(c,1), Bp(c,1), Wp(c,2), Bp(c,2), Gp(c,0), Ep(c,0), Gp(c,1), Ep(c,1),
                Gp(c,2), Ep(c,2), st0, st1, st2, xc, xn, F, inv_n);
        }
    };

    run_conv(xin, x1, 3, 2, 64, 0);     // -> x1: C=67
    run_conv(x1, x2, 67, 67, 128, 1);   // -> x2: C=195
    run_conv(x2, x3, 195, 195, 256, 2); // -> x3: C=451
    pool_kernel<<<NB, 256, 0, stream>>>(x3, pooled, 451);
    fc_kernel<<<NB, 256, 0, stream>>>(pooled, fcW1, fcb1, fcW2, fcb2, (float*)d_out, 451);
}

// Round 6
// 3436.709 us; speedup vs baseline: 2.4345x; 2.4345x over previous
//
#include <hip/hip_runtime.h>
#include <hip/hip_bf16.h>

typedef __hip_bfloat16 bf16;
typedef short v8s __attribute__((ext_vector_type(8)));
typedef float v4f __attribute__((ext_vector_type(4)));

__device__ __forceinline__ float b2f(bf16 v) { return __bfloat162float(v); }
__device__ __forceinline__ bf16  f2b(float v) { return __float2bfloat16(v); }
__device__ __forceinline__ short f2bs(float v) {
    bf16 b = f2b(v); short s; __builtin_memcpy(&s, &b, 2); return s;
}
__device__ __forceinline__ float bs2f(short s) {
    bf16 b; __builtin_memcpy(&b, &s, 2); return b2f(b);
}

#define NB 128   // batch
#define NN 128   // nodes per graph
#define KNN 16   // neighbors
#define M_NODES (NB * NN)          // 16384
#define NPOS ((long)M_NODES * KNN) // 262144 edge rows

// ---------------- zero a small float buffer ----------------
__global__ void zero_kernel(float* __restrict__ p, int n) {
    int i = blockIdx.x * blockDim.x + threadIdx.x;
    if (i < n) p[i] = 0.f;
}

// ---------------- kNN over f32 features -------------------
__global__ __launch_bounds__(128) void knn_kernel(const float* __restrict__ x, int C, int D,
                                                  int* __restrict__ idx) {
    const int b = blockIdx.x, i = threadIdx.x;
    __shared__ float sf[128 * 65];
    __shared__ float ssq[128];
    float dot[128];
#pragma unroll
    for (int j = 0; j < 128; ++j) dot[j] = 0.f;
    float sqi = 0.f;
    for (int d0 = 0; d0 < D; d0 += 64) {
        int dw = D - d0; if (dw > 64) dw = 64;
        for (int d = 0; d < dw; ++d) sf[i * 65 + d] = x[(size_t)(b * NN + i) * C + d0 + d];
        __syncthreads();
        for (int d = 0; d < dw; ++d) {
            float fi = sf[i * 65 + d];
            sqi += fi * fi;
#pragma unroll
            for (int j = 0; j < 128; ++j) dot[j] += fi * sf[j * 65 + d];
        }
        __syncthreads();
    }
    ssq[i] = sqi;
    __syncthreads();
    unsigned long long sel0 = 0ull, sel1 = 0ull;
    for (int k = 0; k < KNN; ++k) {
        float best = 3.0e38f; int bj = 0;
#pragma unroll
        for (int j = 0; j < 128; ++j) {
            float dj = sqi + ssq[j] - 2.0f * dot[j];
            bool excl = (j == i) || ((j < 64) ? ((sel0 >> j) & 1ull) : ((sel1 >> (j - 64)) & 1ull));
            if (!excl && dj < best) { best = dj; bj = j; }
        }
        if (bj < 64) sel0 |= (1ull << bj); else sel1 |= (1ull << (bj - 64));
        idx[(size_t)(b * NN + i) * KNN + k] = bj;
    }
}

// ---------------- node GEMM: T1 = x@(Wt-Wb)+bias, T2 = x@Wb (all f32) ----------------
__global__ __launch_bounds__(256) void node_gemm_kernel(const float* __restrict__ x, int F, int O,
                                                        const float* __restrict__ W, const float* __restrict__ bias,
                                                        float* __restrict__ T1, float* __restrict__ T2) {
    __shared__ float As[16][65];  // [k][m]
    __shared__ float Bt[16][65];  // [k][c] top half of W
    __shared__ float Bb[16][65];  // [k][c] bottom half
    const int tid = threadIdx.x;
    const int tx = tid & 15, ty = tid >> 4;
    const int m0 = blockIdx.y * 64, c0 = blockIdx.x * 64;
    float aT[4][4], aB[4][4];
#pragma unroll
    for (int r = 0; r < 4; ++r)
#pragma unroll
        for (int c = 0; c < 4; ++c) { aT[r][c] = 0.f; aB[r][c] = 0.f; }
    for (int k0 = 0; k0 < F; k0 += 16) {
        for (int l = tid; l < 1024; l += 256) {
            int k = l & 15, m = l >> 4;
            int kk = k0 + k;
            As[k][m] = (kk < F) ? x[(size_t)(m0 + m) * F + kk] : 0.f;
        }
        for (int l = tid; l < 1024; l += 256) {
            int c = l & 63, k = l >> 6;
            int kk = k0 + k;
            Bt[k][c] = (kk < F) ? W[(size_t)kk * O + c0 + c] : 0.f;
            Bb[k][c] = (kk < F) ? W[(size_t)(F + kk) * O + c0 + c] : 0.f;
        }
        __syncthreads();
        for (int k = 0; k < 16; ++k) {
            float av[4], bt[4], bb[4];
#pragma unroll
            for (int r = 0; r < 4; ++r) av[r] = As[k][ty + 16 * r];
#pragma unroll
            for (int c = 0; c < 4; ++c) { bt[c] = Bt[k][tx + 16 * c]; bb[c] = Bb[k][tx + 16 * c]; }
#pragma unroll
            for (int r = 0; r < 4; ++r)
#pragma unroll
                for (int c = 0; c < 4; ++c) { aT[r][c] += av[r] * bt[c]; aB[r][c] += av[r] * bb[c]; }
        }
        __syncthreads();
    }
    float bc[4];
#pragma unroll
    for (int c = 0; c < 4; ++c) bc[c] = bias[c0 + tx + 16 * c];
#pragma unroll
    for (int r = 0; r < 4; ++r)
#pragma unroll
        for (int c = 0; c < 4; ++c) {
            size_t m = m0 + ty + 16 * r, cc = c0 + tx + 16 * c;
            T1[m * O + cc] = aT[r][c] - aB[r][c] + bc[c];
            T2[m * O + cc] = aB[r][c];
        }
}

// ---------------- stats of layer-0 output h0 = T1[n] + T2[nbr], never materialized ------
template<int O>
__global__ __launch_bounds__(256) void stats0_kernel(const float* __restrict__ T1,
        const float* __restrict__ T2, const int* __restrict__ idx, float* __restrict__ st0) {
    constexpr int OSH = (O == 64) ? 6 : (O == 128 ? 7 : 8);
    __shared__ float ls[256], lss[256];
    const int t = threadIdx.x;
    const long n = NPOS * O;
    float s = 0.f, ss = 0.f;
    for (long i = (long)blockIdx.x * 256 + t; i < n; i += (long)gridDim.x * 256) {
        int c = (int)(i & (O - 1));
        long e = i >> OSH;           // edge row
        int nd = (int)(e >> 4);      // node
        int j = idx[e];              // neighbor (node-local)
        int g = ((nd >> 7) << 7) + j;
        float v = T1[(size_t)nd * O + c] + T2[(size_t)g * O + c];
        s += v; ss += v * v;
    }
    ls[t] = s; lss[t] = ss;
    __syncthreads();
    for (int off = 128; off >= O; off >>= 1) {
        if (t < off) { ls[t] += ls[t + off]; lss[t] += lss[t + off]; }
        __syncthreads();
    }
    if (t < O) { atomicAdd(&st0[t], ls[t]); atomicAdd(&st0[O + t], lss[t]); }
}

// ---------------- fused conv stage kernel (MFMA recompute pipeline) ----------------
// Per 64-edge tile (4 nodes x 16 nbrs), 4 waves x 16 rows:
//   A0 = relu(bn0(T1[n]+T2[nbr])) -> LDS bf16 [m][k]
//   h1 = A0 @ W1 + b1  via mfma_f32_16x16x32_bf16, W split hi+lo (~f32 weight precision)
//   STAGE1: per-channel sum/sumsq of h1 -> st1.
//   A1 = relu(bn1(h1)) in-register -> LDS; h2 = A1 @ W2 + b2
//   STAGE2: stats of h2 -> st2.
//   STAGE3: A2 = relu(bn2(h2)); xnew[node] = [mean_k A2, xold]  (shfl k-reduction)
template<int O, int STAGE>
__global__ __launch_bounds__(256) void conv_stage_kernel(
    const float* __restrict__ T1, const float* __restrict__ T2, const int* __restrict__ idx,
    const float* __restrict__ W1, const float* __restrict__ bias1,
    const float* __restrict__ W2, const float* __restrict__ bias2,
    const float* __restrict__ gm0, const float* __restrict__ bt0,
    const float* __restrict__ gm1, const float* __restrict__ bt1,
    const float* __restrict__ gm2, const float* __restrict__ bt2,
    const float* __restrict__ st0, float* __restrict__ st1, float* __restrict__ st2,
    const float* __restrict__ xold, float* __restrict__ xnew, int F, float inv_n)
{
    constexpr int NCT = O / 16;                       // col-tiles per wave
    constexpr int OSH = (O == 64) ? 6 : (O == 128 ? 7 : 8);
    constexpr int AP = O + 8;                         // A row pitch (2-way-free b128 reads)
    __shared__ __align__(16) short Am[64][AP];        // activations bf16 [m][k]
    __shared__ __align__(16) short Wt[O][40];         // W K-slice transposed [c][kk], pitch 40
    __shared__ float sc0[O], sh0[O], sc1[O], sh1[O], sc2[O], sh2[O];
    __shared__ float red[4 * O], redq[4 * O];
    __shared__ int gArr[64];
    const int tid = threadIdx.x;
    const int lane = tid & 63, wave = tid >> 6;
    const int l15 = lane & 15, quad = lane >> 4;
    const int e0 = blockIdx.x * 64;                   // first edge row
    const int nb0 = e0 >> 4;                          // first node (4 per block)

    if (tid < O) {
        {
            float mean = st0[tid] * inv_n;
            float var = fmaxf(st0[O + tid] * inv_n - mean * mean, 0.f);
            float s = rsqrtf(var + 1e-5f) * gm0[tid];
            sc0[tid] = s; sh0[tid] = bt0[tid] - mean * s;
        }
        if (STAGE >= 2) {
            float mean = st1[tid] * inv_n;
            float var = fmaxf(st1[O + tid] * inv_n - mean * mean, 0.f);
            float s = rsqrtf(var + 1e-5f) * gm1[tid];
            sc1[tid] = s; sh1[tid] = bt1[tid] - mean * s;
        }
        if (STAGE == 3) {
            float mean = st2[tid] * inv_n;
            float var = fmaxf(st2[O + tid] * inv_n - mean * mean, 0.f);
            float s = rsqrtf(var + 1e-5f) * gm2[tid];
            sc2[tid] = s; sh2[tid] = bt2[tid] - mean * s;
        }
    }
    if (tid < 64) {
        int e = e0 + tid;
        int nd = e >> 4;
        gArr[tid] = ((nd >> 7) << 7) + idx[e];
    }
    __syncthreads();

    // A0 build into Am[m][k]
    for (int l = tid; l < 64 * O; l += 256) {
        int m = l >> OSH, c = l & (O - 1);
        float v = T1[(size_t)(nb0 + (m >> 4)) * O + c] + T2[(size_t)gArr[m] * O + c];
        v = v * sc0[c] + sh0[c];
        Am[m][c] = f2bs(fmaxf(v, 0.f));
    }

    v4f acc[NCT];
    auto do_gemm = [&](const float* __restrict__ Wg) {
#pragma unroll
        for (int ct = 0; ct < NCT; ++ct)
#pragma unroll
            for (int r = 0; r < 4; ++r) acc[ct][r] = 0.f;
        for (int half = 0; half < 2; ++half) {
            for (int k0 = 0; k0 < O; k0 += 32) {
                __syncthreads();   // protect Wt overwrite (also orders Am writes on 1st pass)
                for (int l = tid; l < 32 * O; l += 256) {
                    int c = l & (O - 1), kk = l >> OSH;
                    float w = Wg[(size_t)(k0 + kk) * O + c];
                    short hi = f2bs(w);
                    Wt[c][kk] = (half == 0) ? hi : f2bs(w - bs2f(hi));
                }
                __syncthreads();
                v8s av = *(const v8s*)&Am[wave * 16 + l15][k0 + quad * 8];
#pragma unroll
                for (int ct = 0; ct < NCT; ++ct) {
                    v8s bv = *(const v8s*)&Wt[ct * 16 + l15][quad * 8];
                    acc[ct] = __builtin_amdgcn_mfma_f32_16x16x32_bf16(av, bv, acc[ct], 0, 0, 0);
                }
            }
        }
    };

    // GEMM1: h1 = A0 @ W1 + b1
    do_gemm(W1);
#pragma unroll
    for (int ct = 0; ct < NCT; ++ct) {
        float bb = bias1[ct * 16 + l15];
#pragma unroll
        for (int r = 0; r < 4; ++r) acc[ct][r] += bb;
    }

    if (STAGE == 1) {
#pragma unroll
        for (int ct = 0; ct < NCT; ++ct) {
            int c = ct * 16 + l15;
            float s = 0.f, q = 0.f;
#pragma unroll
            for (int r = 0; r < 4; ++r) { float v = acc[ct][r]; s += v; q += v * v; }
            s += __shfl_down(s, 32); s += __shfl_down(s, 16);
            q += __shfl_down(q, 32); q += __shfl_down(q, 16);
            if (quad == 0) { red[wave * O + c] = s; redq[wave * O + c] = q; }
        }
        __syncthreads();
        if (tid < O) {
            float s = red[tid] + red[O + tid] + red[2 * O + tid] + red[3 * O + tid];
            float q = redq[tid] + redq[O + tid] + redq[2 * O + tid] + redq[3 * O + tid];
            atomicAdd(&st1[tid], s); atomicAdd(&st1[O + tid], q);
        }
        return;
    }

    // A1 = relu(bn1(h1)) -> Am (each wave overwrites only its own rows, already consumed)
#pragma unroll
    for (int ct = 0; ct < NCT; ++ct) {
        int c = ct * 16 + l15;
        float sc = sc1[c], sh = sh1[c];
#pragma unroll
        for (int r = 0; r < 4; ++r) {
            float v = fmaxf(acc[ct][r] * sc + sh, 0.f);
            Am[wave * 16 + quad * 4 + r][c] = f2bs(v);
        }
    }

    // GEMM2: h2 = A1 @ W2 + b2
    do_gemm(W2);
#pragma unroll
    for (int ct = 0; ct < NCT; ++ct) {
        float bb = bias2[ct * 16 + l15];
#pragma unroll
        for (int r = 0; r < 4; ++r) acc[ct][r] += bb;
    }

    if (STAGE == 2) {
#pragma unroll
        for (int ct = 0; ct < NCT; ++ct) {
            int c = ct * 16 + l15;
            float s = 0.f, q = 0.f;
#pragma unroll
            for (int r = 0; r < 4; ++r) { float v = acc[ct][r]; s += v; q += v * v; }
            s += __shfl_down(s, 32); s += __shfl_down(s, 16);
            q += __shfl_down(q, 32); q += __shfl_down(q, 16);
            if (quad == 0) { red[wave * O + c] = s; redq[wave * O + c] = q; }
        }
        __syncthreads();
        if (tid < O) {
            float s = red[tid] + red[O + tid] + red[2 * O + tid] + red[3 * O + tid];
            float q = redq[tid] + redq[O + tid] + redq[2 * O + tid] + redq[3 * O + tid];
            atomicAdd(&st2[tid], s); atomicAdd(&st2[O + tid], q);
        }
        return;
    }

    // STAGE3: A2 = relu(bn2(h2)); wave w's 16 rows are node (nb0+w)'s neighbors ->
    // shfl-reduce over quads gives the k-mean directly.
    const int Cnew = O + F;
#pragma unroll
    for (int ct = 0; ct < NCT; ++ct) {
        int c = ct * 16 + l15;
        float sc = sc2[c], sh = sh2[c];
        float s = 0.f;
#pragma unroll
        for (int r = 0; r < 4; ++r) s += fmaxf(acc[ct][r] * sc + sh, 0.f);
        s += __shfl_down(s, 32); s += __shfl_down(s, 16);
        if (quad == 0) xnew[(size_t)(nb0 + wave) * Cnew + c] = s * (1.0f / 16.0f);
    }
    for (int l = tid; l < 4 * F; l += 256) {
        int nd = l / F, c = l - nd * F;
        xnew[(size_t)(nb0 + nd) * Cnew + O + c] = xold[(size_t)(nb0 + nd) * F + c];
    }
}

// ---------------- global mean pool over nodes ----------------
__global__ __launch_bounds__(256) void pool_kernel(const float* __restrict__ x, float* __restrict__ pooled, int C) {
    int b = blockIdx.x, t = threadIdx.x;
    for (int c = t; c < C; c += 256) {
        float s = 0.f;
        for (int n = 0; n < NN; ++n) s += x[(size_t)(b * NN + n) * C + c];
        pooled[b * C + c] = s * (1.0f / NN);
    }
}

// ---------------- fc1 (no act) + fc2 ----------------
__global__ __launch_bounds__(256) void fc_kernel(const float* __restrict__ pooled,
                                                 const float* __restrict__ W1, const float* __restrict__ b1,
                                                 const float* __restrict__ W2, const float* __restrict__ b2,
                                                 float* __restrict__ out, int C) {
    __shared__ float px[451];
    __shared__ float h1[256];
    int b = blockIdx.x, t = threadIdx.x;
    for (int c = t; c < C; c += 256) px[c] = pooled[b * C + c];
    __syncthreads();
    float s = 0.f;
    for (int i = 0; i < C; ++i) s += px[i] * W1[(size_t)i * 256 + t];
    h1[t] = s + b1[t];
    __syncthreads();
    if (t < 5) {
        float s2 = 0.f;
        for (int j = 0; j < 256; ++j) s2 += h1[j] * W2[j * 5 + t];
        out[b * 5 + t] = s2 + b2[t];
    }
}

extern "C" void kernel_launch(void* const* d_in, const int* in_sizes, int n_in,
                              void* d_out, int out_size, void* d_ws, size_t ws_size,
                              hipStream_t stream) {
    const float* xin = (const float*)d_in[0];
    auto Wp = [&](int c, int l) { return (const float*)d_in[1 + c * 12 + l * 4 + 0]; };
    auto Bp = [&](int c, int l) { return (const float*)d_in[1 + c * 12 + l * 4 + 1]; };
    auto Gp = [&](int c, int l) { return (const float*)d_in[1 + c * 12 + l * 4 + 2]; };
    auto Ep = [&](int c, int l) { return (const float*)d_in[1 + c * 12 + l * 4 + 3]; };
    const float* fcW1 = (const float*)d_in[37];
    const float* fcb1 = (const float*)d_in[38];
    const float* fcW2 = (const float*)d_in[39];
    const float* fcb2 = (const float*)d_in[40];

    char* ws = (char*)d_ws;
    size_t off = 0;
    auto alloc = [&](size_t bytes) -> void* {
        void* p = ws + off;
        off += (bytes + 255) & ~(size_t)255;
        return p;
    };
    const int M = M_NODES;
    float* x1     = (float*)alloc((size_t)M * 67 * 4);   //  4.4 MB
    float* x2     = (float*)alloc((size_t)M * 195 * 4);  // 12.8 MB
    float* x3     = (float*)alloc((size_t)M * 451 * 4);  // 29.6 MB
    float* T1     = (float*)alloc((size_t)M * 256 * 4);  // 16.8 MB
    float* T2     = (float*)alloc((size_t)M * 256 * 4);  // 16.8 MB
    int*   idxb   = (int*)alloc((size_t)M * KNN * 4);    //  1.0 MB
    float* stats  = (float*)alloc(1536 * 4);             // st0/st1/st2
    float* pooled = (float*)alloc((size_t)NB * 451 * 4); //  0.23 MB
    (void)ws_size; (void)in_sizes; (void)n_in; (void)out_size; // total ~82 MiB

    float* st0 = stats, *st1 = stats + 512, *st2 = stats + 1024;
    const float inv_n = 1.0f / (float)NPOS;

    auto run_conv = [&](const float* xc, float* xn, int F, int D, int O, int c) {
        knn_kernel<<<NB, NN, 0, stream>>>(xc, F, D, idxb);
        node_gemm_kernel<<<dim3(O / 64, M / 64), 256, 0, stream>>>(xc, F, O, Wp(c, 0), Bp(c, 0), T1, T2);
        zero_kernel<<<6, 256, 0, stream>>>(stats, 1536);
        const int grid = (int)(NPOS / 64);
        if (O == 64) {
            stats0_kernel<64><<<512, 256, 0, stream>>>(T1, T2, idxb, st0);
            conv_stage_kernel<64, 1><<<grid, 256, 0, stream>>>(T1, T2, idxb,
                Wp(c,1), Bp(c,1), Wp(c,2), Bp(c,2), Gp(c,0), Ep(c,0), Gp(c,1), Ep(c,1),
                Gp(c,2), Ep(c,2), st0, st1, st2, xc, xn, F, inv_n);
            conv_stage_kernel<64, 2><<<grid, 256, 0, stream>>>(T1, T2, idxb,
                Wp(c,1), Bp(c,1), Wp(c,2), Bp(c,2), Gp(c,0), Ep(c,0), Gp(c,1), Ep(c,1),
                Gp(c,2), Ep(c,2), st0, st1, st2, xc, xn, F, inv_n);
            conv_stage_kernel<64, 3><<<grid, 256, 0, stream>>>(T1, T2, idxb,
                Wp(c,1), Bp(c,1), Wp(c,2), Bp(c,2), Gp(c,0), Ep(c,0), Gp(c,1), Ep(c,1),
                Gp(c,2), Ep(c,2), st0, st1, st2, xc, xn, F, inv_n);
        } else if (O == 128) {
            stats0_kernel<128><<<512, 256, 0, stream>>>(T1, T2, idxb, st0);
            conv_stage_kernel<128, 1><<<grid, 256, 0, stream>>>(T1, T2, idxb,
                Wp(c,1), Bp(c,1), Wp(c,2), Bp(c,2), Gp(c,0), Ep(c,0), Gp(c,1), Ep(c,1),
                Gp(c,2), Ep(c,2), st0, st1, st2, xc, xn, F, inv_n);
            conv_stage_kernel<128, 2><<<grid, 256, 0, stream>>>(T1, T2, idxb,
                Wp(c,1), Bp(c,1), Wp(c,2), Bp(c,2), Gp(c,0), Ep(c,0), Gp(c,1), Ep(c,1),
                Gp(c,2), Ep(c,2), st0, st1, st2, xc, xn, F, inv_n);
            conv_stage_kernel<128, 3><<<grid, 256, 0, stream>>>(T1, T2, idxb,
                Wp(c,1), Bp(c,1), Wp(c,2), Bp(c,2), Gp(c,0), Ep(c,0), Gp(c,1), Ep(c,1),
                Gp(c,2), Ep(c,2), st0, st1, st2, xc, xn, F, inv_n);
        } else {
            stats0_kernel<256><<<1024, 256, 0, stream>>>(T1, T2, idxb, st0);
            conv_stage_kernel<256, 1><<<grid, 256, 0, stream>>>(T1, T2, idxb,
                Wp(c,1), Bp(c,1), Wp(c,2), Bp(c,2), Gp(c,0), Ep(c,0), Gp(c,1), Ep(c,1),
                Gp(c,2), Ep(c,2), st0, st1, st2, xc, xn, F, inv_n);
            conv_stage_kernel<256, 2><<<grid, 256, 0, stream>>>(T1, T2, idxb,
                Wp(c,1), Bp(c,1), Wp(c,2), Bp(c,2), Gp(c,0), Ep(c,0), Gp(c,1), Ep(c,1),
                Gp(c,2), Ep(c,2), st0, st1, st2, xc, xn, F, inv_n);
            conv_stage_kernel<256, 3><<<grid, 256, 0, stream>>>(T1, T2, idxb,
                Wp(c,1), Bp(c,1), Wp(c,2), Bp(c,2), Gp(c,0), Ep(c,0), Gp(c,1), Ep(c,1),
                Gp(c,2), Ep(c,2), st0, st1, st2, xc, xn, F, inv_n);
        }
    };

    run_conv(xin, x1, 3, 2, 64, 0);     // -> x1: C=67
    run_conv(x1, x2, 67, 67, 128, 1);   // -> x2: C=195
    run_conv(x2, x3, 195, 195, 256, 2); // -> x3: C=451
    pool_kernel<<<NB, 256, 0, stream>>>(x3, pooled, 451);
    fc_kernel<<<NB, 256, 0, stream>>>(pooled, fcW1, fcb1, fcW2, fcb2, (float*)d_out, 451);
}

// Round 7
// 2965.230 us; speedup vs baseline: 2.8216x; 1.1590x over previous
//
#include <hip/hip_runtime.h>
#include <hip/hip_bf16.h>

typedef __hip_bfloat16 bf16;
typedef short v8s __attribute__((ext_vector_type(8)));
typedef short v4s __attribute__((ext_vector_type(4)));
typedef short v2s __attribute__((ext_vector_type(2)));
typedef float v4f __attribute__((ext_vector_type(4)));

__device__ __forceinline__ float b2f(bf16 v) { return __bfloat162float(v); }
__device__ __forceinline__ bf16  f2b(float v) { return __float2bfloat16(v); }
__device__ __forceinline__ short f2bs(float v) {
    bf16 b = f2b(v); short s; __builtin_memcpy(&s, &b, 2); return s;
}
__device__ __forceinline__ float bs2f(short s) {
    bf16 b; __builtin_memcpy(&b, &s, 2); return b2f(b);
}

#define NB 128   // batch
#define NN 128   // nodes per graph
#define KNN 16   // neighbors
#define M_NODES (NB * NN)          // 16384
#define NPOS ((long)M_NODES * KNN) // 262144 edge rows

// ---------------- zero a small float buffer ----------------
__global__ void zero_kernel(float* __restrict__ p, int n) {
    int i = blockIdx.x * blockDim.x + threadIdx.x;
    if (i < n) p[i] = 0.f;
}

// ---------------- weight precompute: transposed bf16 hi/lo split ----------------
// Whi_t[c*O+k] = bf16(W[k*O+c]);  Wlo_t[c*O+k] = bf16(W[k*O+c] - float(hi))
__global__ __launch_bounds__(256) void wconv_kernel(const float* __restrict__ W,
        short* __restrict__ Whi, short* __restrict__ Wlo, int O) {
    int d = blockIdx.x * 256 + threadIdx.x;      // d = c*O + k
    int c = d / O, k = d - c * O;
    float w = W[(size_t)k * O + c];
    short hi = f2bs(w);
    Whi[d] = hi;
    Wlo[d] = f2bs(w - bs2f(hi));
}

// ---------------- kNN over f32 features -------------------
__global__ __launch_bounds__(128) void knn_kernel(const float* __restrict__ x, int C, int D,
                                                  int* __restrict__ idx) {
    const int b = blockIdx.x, i = threadIdx.x;
    __shared__ float sf[128 * 65];
    __shared__ float ssq[128];
    float dot[128];
#pragma unroll
    for (int j = 0; j < 128; ++j) dot[j] = 0.f;
    float sqi = 0.f;
    for (int d0 = 0; d0 < D; d0 += 64) {
        int dw = D - d0; if (dw > 64) dw = 64;
        for (int d = 0; d < dw; ++d) sf[i * 65 + d] = x[(size_t)(b * NN + i) * C + d0 + d];
        __syncthreads();
        for (int d = 0; d < dw; ++d) {
            float fi = sf[i * 65 + d];
            sqi += fi * fi;
#pragma unroll
            for (int j = 0; j < 128; ++j) dot[j] += fi * sf[j * 65 + d];
        }
        __syncthreads();
    }
    ssq[i] = sqi;
    __syncthreads();
    unsigned long long sel0 = 0ull, sel1 = 0ull;
    for (int k = 0; k < KNN; ++k) {
        float best = 3.0e38f; int bj = 0;
#pragma unroll
        for (int j = 0; j < 128; ++j) {
            float dj = sqi + ssq[j] - 2.0f * dot[j];
            bool excl = (j == i) || ((j < 64) ? ((sel0 >> j) & 1ull) : ((sel1 >> (j - 64)) & 1ull));
            if (!excl && dj < best) { best = dj; bj = j; }
        }
        if (bj < 64) sel0 |= (1ull << bj); else sel1 |= (1ull << (bj - 64));
        idx[(size_t)(b * NN + i) * KNN + k] = bj;
    }
}

// ---------------- node GEMM: T1 = x@(Wt-Wb)+bias, T2 = x@Wb (all f32) ----------------
__global__ __launch_bounds__(256) void node_gemm_kernel(const float* __restrict__ x, int F, int O,
                                                        const float* __restrict__ W, const float* __restrict__ bias,
                                                        float* __restrict__ T1, float* __restrict__ T2) {
    __shared__ float As[16][65];  // [k][m]
    __shared__ float Bt[16][65];  // [k][c] top half of W
    __shared__ float Bb[16][65];  // [k][c] bottom half
    const int tid = threadIdx.x;
    const int tx = tid & 15, ty = tid >> 4;
    const int m0 = blockIdx.y * 64, c0 = blockIdx.x * 64;
    float aT[4][4], aB[4][4];
#pragma unroll
    for (int r = 0; r < 4; ++r)
#pragma unroll
        for (int c = 0; c < 4; ++c) { aT[r][c] = 0.f; aB[r][c] = 0.f; }
    for (int k0 = 0; k0 < F; k0 += 16) {
        for (int l = tid; l < 1024; l += 256) {
            int k = l & 15, m = l >> 4;
            int kk = k0 + k;
            As[k][m] = (kk < F) ? x[(size_t)(m0 + m) * F + kk] : 0.f;
        }
        for (int l = tid; l < 1024; l += 256) {
            int c = l & 63, k = l >> 6;
            int kk = k0 + k;
            Bt[k][c] = (kk < F) ? W[(size_t)kk * O + c0 + c] : 0.f;
            Bb[k][c] = (kk < F) ? W[(size_t)(F + kk) * O + c0 + c] : 0.f;
        }
        __syncthreads();
        for (int k = 0; k < 16; ++k) {
            float av[4], bt[4], bb[4];
#pragma unroll
            for (int r = 0; r < 4; ++r) av[r] = As[k][ty + 16 * r];
#pragma unroll
            for (int c = 0; c < 4; ++c) { bt[c] = Bt[k][tx + 16 * c]; bb[c] = Bb[k][tx + 16 * c]; }
#pragma unroll
            for (int r = 0; r < 4; ++r)
#pragma unroll
                for (int c = 0; c < 4; ++c) { aT[r][c] += av[r] * bt[c]; aB[r][c] += av[r] * bb[c]; }
        }
        __syncthreads();
    }
    float bc[4];
#pragma unroll
    for (int c = 0; c < 4; ++c) bc[c] = bias[c0 + tx + 16 * c];
#pragma unroll
    for (int r = 0; r < 4; ++r)
#pragma unroll
        for (int c = 0; c < 4; ++c) {
            size_t m = m0 + ty + 16 * r, cc = c0 + tx + 16 * c;
            T1[m * O + cc] = aT[r][c] - aB[r][c] + bc[c];
            T2[m * O + cc] = aB[r][c];
        }
}

// ---------------- stats of layer-0 output h0 = T1[n] + T2[nbr], never materialized ------
template<int O>
__global__ __launch_bounds__(256) void stats0_kernel(const float* __restrict__ T1,
        const float* __restrict__ T2, const int* __restrict__ idx, float* __restrict__ st0) {
    constexpr int OSH = (O == 64) ? 6 : (O == 128 ? 7 : 8);
    __shared__ float ls[256], lss[256];
    const int t = threadIdx.x;
    const long n = NPOS * O;
    float s = 0.f, ss = 0.f;
    for (long i = (long)blockIdx.x * 256 + t; i < n; i += (long)gridDim.x * 256) {
        int c = (int)(i & (O - 1));
        long e = i >> OSH;           // edge row
        int nd = (int)(e >> 4);      // node
        int j = idx[e];              // neighbor (node-local)
        int g = ((nd >> 7) << 7) + j;
        float v = T1[(size_t)nd * O + c] + T2[(size_t)g * O + c];
        s += v; ss += v * v;
    }
    ls[t] = s; lss[t] = ss;
    __syncthreads();
    for (int off = 128; off >= O; off >>= 1) {
        if (t < off) { ls[t] += ls[t + off]; lss[t] += lss[t + off]; }
        __syncthreads();
    }
    if (t < O) { atomicAdd(&st0[t], ls[t]); atomicAdd(&st0[O + t], lss[t]); }
}

// ---------------- fused conv stage kernel (MFMA recompute pipeline) ----------------
// Per 64-edge tile (4 nodes x 16 nbrs), 4 waves x 16 rows:
//   A0 = relu(bn0(T1[n]+T2[nbr])) -> LDS bf16 [m][k]
//   h1 = A0 @ W1 + b1  (mfma 16x16x32 bf16; W pre-split hi+lo => ~f32 weight precision)
//   STAGE1: per-channel sum/sumsq of h1 -> st1.
//   A1 = relu(bn1(h1)) -> LDS; h2 = A1 @ W2 + b2
//   STAGE2: stats of h2 -> st2.
//   STAGE3: A2 = relu(bn2(h2)); xnew[node] = [mean_k A2, xold]  (shfl k-reduction)
template<int O, int STAGE>
__global__ __launch_bounds__(256) void conv_stage_kernel(
    const float* __restrict__ T1, const float* __restrict__ T2, const int* __restrict__ idx,
    const short* __restrict__ W1hi, const short* __restrict__ W1lo, const float* __restrict__ bias1,
    const short* __restrict__ W2hi, const short* __restrict__ W2lo, const float* __restrict__ bias2,
    const float* __restrict__ gm0, const float* __restrict__ bt0,
    const float* __restrict__ gm1, const float* __restrict__ bt1,
    const float* __restrict__ gm2, const float* __restrict__ bt2,
    const float* __restrict__ st0, float* __restrict__ st1, float* __restrict__ st2,
    const float* __restrict__ xold, float* __restrict__ xnew, int F, float inv_n)
{
    constexpr int NCT = O / 16;                       // col-tiles per wave
    constexpr int OSH = (O == 64) ? 6 : (O == 128 ? 7 : 8);
    constexpr int AP = O + 8;                         // A row pitch (2-way-free b128 reads)
    __shared__ __align__(16) short Am[64][AP];        // activations bf16 [m][k]
    __shared__ __align__(16) short Wt[O][40];         // W K-slice transposed [c][kk], pitch 40
    __shared__ float sc0[O], sh0[O], sc1[O], sh1[O], sc2[O], sh2[O];
    __shared__ float red[4 * O], redq[4 * O];
    __shared__ int gArr[64];
    const int tid = threadIdx.x;
    const int lane = tid & 63, wave = tid >> 6;
    const int l15 = lane & 15, quad = lane >> 4;
    const int e0 = blockIdx.x * 64;                   // first edge row
    const int nb0 = e0 >> 4;                          // first node (4 per block)

    if (tid < O) {
        {
            float mean = st0[tid] * inv_n;
            float var = fmaxf(st0[O + tid] * inv_n - mean * mean, 0.f);
            float s = rsqrtf(var + 1e-5f) * gm0[tid];
            sc0[tid] = s; sh0[tid] = bt0[tid] - mean * s;
        }
        if (STAGE >= 2) {
            float mean = st1[tid] * inv_n;
            float var = fmaxf(st1[O + tid] * inv_n - mean * mean, 0.f);
            float s = rsqrtf(var + 1e-5f) * gm1[tid];
            sc1[tid] = s; sh1[tid] = bt1[tid] - mean * s;
        }
        if (STAGE == 3) {
            float mean = st2[tid] * inv_n;
            float var = fmaxf(st2[O + tid] * inv_n - mean * mean, 0.f);
            float s = rsqrtf(var + 1e-5f) * gm2[tid];
            sc2[tid] = s; sh2[tid] = bt2[tid] - mean * s;
        }
    }
    if (tid < 64) {
        int e = e0 + tid;
        int nd = e >> 4;
        gArr[tid] = ((nd >> 7) << 7) + idx[e];
    }
    __syncthreads();

    // A0 build into Am[m][k], float2 loads + paired bf16 stores
    for (int l = tid; l < 32 * O; l += 256) {
        int m = l >> (OSH - 1);
        int c = (l & (O / 2 - 1)) * 2;
        const float2 t1 = *(const float2*)&T1[(size_t)(nb0 + (m >> 4)) * O + c];
        const float2 t2 = *(const float2*)&T2[(size_t)gArr[m] * O + c];
        float v0 = fmaxf((t1.x + t2.x) * sc0[c] + sh0[c], 0.f);
        float v1 = fmaxf((t1.y + t2.y) * sc0[c + 1] + sh0[c + 1], 0.f);
        v2s pr; pr[0] = f2bs(v0); pr[1] = f2bs(v1);
        *(v2s*)&Am[m][c] = pr;
    }

    v4f acc[NCT];
    // Staging map: thread l copies 4 consecutive kk in row c = c0+(l>>3) -> conflict-free.
    const int sc_ = tid >> 3;            // row offset within 32-row group
    const int skk = (tid & 7) * 4;       // kk start
    auto do_gemm = [&](const short* __restrict__ Wa, const short* __restrict__ Wb) {
#pragma unroll
        for (int ct = 0; ct < NCT; ++ct)
#pragma unroll
            for (int r = 0; r < 4; ++r) acc[ct][r] = 0.f;
        for (int half = 0; half < 2; ++half) {
            const short* __restrict__ Wg = half ? Wb : Wa;
            for (int k0 = 0; k0 < O; k0 += 32) {
                __syncthreads();   // protect Wt overwrite (also orders Am writes on 1st pass)
#pragma unroll
                for (int c0 = 0; c0 < O; c0 += 32) {
                    int c = c0 + sc_;
                    *(v4s*)&Wt[c][skk] = *(const v4s*)&Wg[(size_t)c * O + k0 + skk];
                }
                __syncthreads();
                v8s av = *(const v8s*)&Am[wave * 16 + l15][k0 + quad * 8];
#pragma unroll
                for (int ct = 0; ct < NCT; ++ct) {
                    v8s bv = *(const v8s*)&Wt[ct * 16 + l15][quad * 8];
                    acc[ct] = __builtin_amdgcn_mfma_f32_16x16x32_bf16(av, bv, acc[ct], 0, 0, 0);
                }
            }
        }
    };

    // GEMM1: h1 = A0 @ W1 + b1
    do_gemm(W1hi, W1lo);
#pragma unroll
    for (int ct = 0; ct < NCT; ++ct) {
        float bb = bias1[ct * 16 + l15];
#pragma unroll
        for (int r = 0; r < 4; ++r) acc[ct][r] += bb;
    }

    if (STAGE == 1) {
#pragma unroll
        for (int ct = 0; ct < NCT; ++ct) {
            int c = ct * 16 + l15;
            float s = 0.f, q = 0.f;
#pragma unroll
            for (int r = 0; r < 4; ++r) { float v = acc[ct][r]; s += v; q += v * v; }
            s += __shfl_down(s, 32); s += __shfl_down(s, 16);
            q += __shfl_down(q, 32); q += __shfl_down(q, 16);
            if (quad == 0) { red[wave * O + c] = s; redq[wave * O + c] = q; }
        }
        __syncthreads();
        if (tid < O) {
            float s = red[tid] + red[O + tid] + red[2 * O + tid] + red[3 * O + tid];
            float q = redq[tid] + redq[O + tid] + redq[2 * O + tid] + redq[3 * O + tid];
            atomicAdd(&st1[tid], s); atomicAdd(&st1[O + tid], q);
        }
        return;
    }

    // A1 = relu(bn1(h1)) -> Am (each wave overwrites only its own rows, already consumed)
#pragma unroll
    for (int ct = 0; ct < NCT; ++ct) {
        int c = ct * 16 + l15;
        float sc = sc1[c], sh = sh1[c];
#pragma unroll
        for (int r = 0; r < 4; ++r) {
            float v = fmaxf(acc[ct][r] * sc + sh, 0.f);
            Am[wave * 16 + quad * 4 + r][c] = f2bs(v);
        }
    }

    // GEMM2: h2 = A1 @ W2 + b2
    do_gemm(W2hi, W2lo);
#pragma unroll
    for (int ct = 0; ct < NCT; ++ct) {
        float bb = bias2[ct * 16 + l15];
#pragma unroll
        for (int r = 0; r < 4; ++r) acc[ct][r] += bb;
    }

    if (STAGE == 2) {
#pragma unroll
        for (int ct = 0; ct < NCT; ++ct) {
            int c = ct * 16 + l15;
            float s = 0.f, q = 0.f;
#pragma unroll
            for (int r = 0; r < 4; ++r) { float v = acc[ct][r]; s += v; q += v * v; }
            s += __shfl_down(s, 32); s += __shfl_down(s, 16);
            q += __shfl_down(q, 32); q += __shfl_down(q, 16);
            if (quad == 0) { red[wave * O + c] = s; redq[wave * O + c] = q; }
        }
        __syncthreads();
        if (tid < O) {
            float s = red[tid] + red[O + tid] + red[2 * O + tid] + red[3 * O + tid];
            float q = redq[tid] + redq[O + tid] + redq[2 * O + tid] + redq[3 * O + tid];
            atomicAdd(&st2[tid], s); atomicAdd(&st2[O + tid], q);
        }
        return;
    }

    // STAGE3: A2 = relu(bn2(h2)); wave w's 16 rows are node (nb0+w)'s neighbors ->
    // shfl-reduce over quads gives the k-mean directly.
    const int Cnew = O + F;
#pragma unroll
    for (int ct = 0; ct < NCT; ++ct) {
        int c = ct * 16 + l15;
        float sc = sc2[c], sh = sh2[c];
        float s = 0.f;
#pragma unroll
        for (int r = 0; r < 4; ++r) s += fmaxf(acc[ct][r] * sc + sh, 0.f);
        s += __shfl_down(s, 32); s += __shfl_down(s, 16);
        if (quad == 0) xnew[(size_t)(nb0 + wave) * Cnew + c] = s * (1.0f / 16.0f);
    }
    for (int l = tid; l < 4 * F; l += 256) {
        int nd = l / F, c = l - nd * F;
        xnew[(size_t)(nb0 + nd) * Cnew + O + c] = xold[(size_t)(nb0 + nd) * F + c];
    }
}

// ---------------- global mean pool over nodes ----------------
__global__ __launch_bounds__(256) void pool_kernel(const float* __restrict__ x, float* __restrict__ pooled, int C) {
    int b = blockIdx.x, t = threadIdx.x;
    for (int c = t; c < C; c += 256) {
        float s = 0.f;
        for (int n = 0; n < NN; ++n) s += x[(size_t)(b * NN + n) * C + c];
        pooled[b * C + c] = s * (1.0f / NN);
    }
}

// ---------------- fc1 (no act) + fc2 ----------------
__global__ __launch_bounds__(256) void fc_kernel(const float* __restrict__ pooled,
                                                 const float* __restrict__ W1, const float* __restrict__ b1,
                                                 const float* __restrict__ W2, const float* __restrict__ b2,
                                                 float* __restrict__ out, int C) {
    __shared__ float px[451];
    __shared__ float h1[256];
    int b = blockIdx.x, t = threadIdx.x;
    for (int c = t; c < C; c += 256) px[c] = pooled[b * C + c];
    __syncthreads();
    float s = 0.f;
    for (int i = 0; i < C; ++i) s += px[i] * W1[(size_t)i * 256 + t];
    h1[t] = s + b1[t];
    __syncthreads();
    if (t < 5) {
        float s2 = 0.f;
        for (int j = 0; j < 256; ++j) s2 += h1[j] * W2[j * 5 + t];
        out[b * 5 + t] = s2 + b2[t];
    }
}

extern "C" void kernel_launch(void* const* d_in, const int* in_sizes, int n_in,
                              void* d_out, int out_size, void* d_ws, size_t ws_size,
                              hipStream_t stream) {
    const float* xin = (const float*)d_in[0];
    auto Wp = [&](int c, int l) { return (const float*)d_in[1 + c * 12 + l * 4 + 0]; };
    auto Bp = [&](int c, int l) { return (const float*)d_in[1 + c * 12 + l * 4 + 1]; };
    auto Gp = [&](int c, int l) { return (const float*)d_in[1 + c * 12 + l * 4 + 2]; };
    auto Ep = [&](int c, int l) { return (const float*)d_in[1 + c * 12 + l * 4 + 3]; };
    const float* fcW1 = (const float*)d_in[37];
    const float* fcb1 = (const float*)d_in[38];
    const float* fcW2 = (const float*)d_in[39];
    const float* fcb2 = (const float*)d_in[40];

    char* ws = (char*)d_ws;
    size_t off = 0;
    auto alloc = [&](size_t bytes) -> void* {
        void* p = ws + off;
        off += (bytes + 255) & ~(size_t)255;
        return p;
    };
    const int M = M_NODES;
    float* x1     = (float*)alloc((size_t)M * 67 * 4);   //  4.4 MB
    float* x2     = (float*)alloc((size_t)M * 195 * 4);  // 12.8 MB
    float* x3     = (float*)alloc((size_t)M * 451 * 4);  // 29.6 MB
    float* T1     = (float*)alloc((size_t)M * 256 * 4);  // 16.8 MB
    float* T2     = (float*)alloc((size_t)M * 256 * 4);  // 16.8 MB
    int*   idxb   = (int*)alloc((size_t)M * KNN * 4);    //  1.0 MB
    float* stats  = (float*)alloc(1536 * 4);             // st0/st1/st2
    float* pooled = (float*)alloc((size_t)NB * 451 * 4); //  0.23 MB
    short* W1hi   = (short*)alloc(256 * 256 * 2);        // transposed bf16 weights
    short* W1lo   = (short*)alloc(256 * 256 * 2);
    short* W2hi   = (short*)alloc(256 * 256 * 2);
    short* W2lo   = (short*)alloc(256 * 256 * 2);
    (void)ws_size; (void)in_sizes; (void)n_in; (void)out_size; // total ~83 MiB

    float* st0 = stats, *st1 = stats + 512, *st2 = stats + 1024;
    const float inv_n = 1.0f / (float)NPOS;

    auto run_conv = [&](const float* xc, float* xn, int F, int D, int O, int c) {
        knn_kernel<<<NB, NN, 0, stream>>>(xc, F, D, idxb);
        node_gemm_kernel<<<dim3(O / 64, M / 64), 256, 0, stream>>>(xc, F, O, Wp(c, 0), Bp(c, 0), T1, T2);
        wconv_kernel<<<O * O / 256, 256, 0, stream>>>(Wp(c, 1), W1hi, W1lo, O);
        wconv_kernel<<<O * O / 256, 256, 0, stream>>>(Wp(c, 2), W2hi, W2lo, O);
        zero_kernel<<<6, 256, 0, stream>>>(stats, 1536);
        const int grid = (int)(NPOS / 64);
        if (O == 64) {
            stats0_kernel<64><<<512, 256, 0, stream>>>(T1, T2, idxb, st0);
            conv_stage_kernel<64, 1><<<grid, 256, 0, stream>>>(T1, T2, idxb,
                W1hi, W1lo, Bp(c,1), W2hi, W2lo, Bp(c,2), Gp(c,0), Ep(c,0), Gp(c,1), Ep(c,1),
                Gp(c,2), Ep(c,2), st0, st1, st2, xc, xn, F, inv_n);
            conv_stage_kernel<64, 2><<<grid, 256, 0, stream>>>(T1, T2, idxb,
                W1hi, W1lo, Bp(c,1), W2hi, W2lo, Bp(c,2), Gp(c,0), Ep(c,0), Gp(c,1), Ep(c,1),
                Gp(c,2), Ep(c,2), st0, st1, st2, xc, xn, F, inv_n);
            conv_stage_kernel<64, 3><<<grid, 256, 0, stream>>>(T1, T2, idxb,
                W1hi, W1lo, Bp(c,1), W2hi, W2lo, Bp(c,2), Gp(c,0), Ep(c,0), Gp(c,1), Ep(c,1),
                Gp(c,2), Ep(c,2), st0, st1, st2, xc, xn, F, inv_n);
        } else if (O == 128) {
            stats0_kernel<128><<<512, 256, 0, stream>>>(T1, T2, idxb, st0);
            conv_stage_kernel<128, 1><<<grid, 256, 0, stream>>>(T1, T2, idxb,
                W1hi, W1lo, Bp(c,1), W2hi, W2lo, Bp(c,2), Gp(c,0), Ep(c,0), Gp(c,1), Ep(c,1),
                Gp(c,2), Ep(c,2), st0, st1, st2, xc, xn, F, inv_n);
            conv_stage_kernel<128, 2><<<grid, 256, 0, stream>>>(T1, T2, idxb,
                W1hi, W1lo, Bp(c,1), W2hi, W2lo, Bp(c,2), Gp(c,0), Ep(c,0), Gp(c,1), Ep(c,1),
                Gp(c,2), Ep(c,2), st0, st1, st2, xc, xn, F, inv_n);
            conv_stage_kernel<128, 3><<<grid, 256, 0, stream>>>(T1, T2, idxb,
                W1hi, W1lo, Bp(c,1), W2hi, W2lo, Bp(c,2), Gp(c,0), Ep(c,0), Gp(c,1), Ep(c,1),
                Gp(c,2), Ep(c,2), st0, st1, st2, xc, xn, F, inv_n);
        } else {
            stats0_kernel<256><<<1024, 256, 0, stream>>>(T1, T2, idxb, st0);
            conv_stage_kernel<256, 1><<<grid, 256, 0, stream>>>(T1, T2, idxb,
                W1hi, W1lo, Bp(c,1), W2hi, W2lo, Bp(c,2), Gp(c,0), Ep(c,0), Gp(c,1), Ep(c,1),
                Gp(c,2), Ep(c,2), st0, st1, st2, xc, xn, F, inv_n);
            conv_stage_kernel<256, 2><<<grid, 256, 0, stream>>>(T1, T2, idxb,
                W1hi, W1lo, Bp(c,1), W2hi, W2lo, Bp(c,2), Gp(c,0), Ep(c,0), Gp(c,1), Ep(c,1),
                Gp(c,2), Ep(c,2), st0, st1, st2, xc, xn, F, inv_n);
            conv_stage_kernel<256, 3><<<grid, 256, 0, stream>>>(T1, T2, idxb,
                W1hi, W1lo, Bp(c,1), W2hi, W2lo, Bp(c,2), Gp(c,0), Ep(c,0), Gp(c,1), Ep(c,1),
                Gp(c,2), Ep(c,2), st0, st1, st2, xc, xn, F, inv_n);
        }
    };

    run_conv(xin, x1, 3, 2, 64, 0);     // -> x1: C=67
    run_conv(x1, x2, 67, 67, 128, 1);   // -> x2: C=195
    run_conv(x2, x3, 195, 195, 256, 2); // -> x3: C=451
    pool_kernel<<<NB, 256, 0, stream>>>(x3, pooled, 451);
    fc_kernel<<<NB, 256, 0, stream>>>(pooled, fcW1, fcb1, fcW2, fcb2, (float*)d_out, 451);
}

// Round 8
// 2424.932 us; speedup vs baseline: 3.4503x; 1.2228x over previous
//
#include <hip/hip_runtime.h>
#include <hip/hip_bf16.h>

typedef __hip_bfloat16 bf16;
typedef short v8s __attribute__((ext_vector_type(8)));
typedef short v4s __attribute__((ext_vector_type(4)));
typedef short v2s __attribute__((ext_vector_type(2)));
typedef float v4f __attribute__((ext_vector_type(4)));

__device__ __forceinline__ float b2f(bf16 v) { return __bfloat162float(v); }
__device__ __forceinline__ bf16  f2b(float v) { return __float2bfloat16(v); }
__device__ __forceinline__ short f2bs(float v) {
    bf16 b = f2b(v); short s; __builtin_memcpy(&s, &b, 2); return s;
}
__device__ __forceinline__ float bs2f(short s) {
    bf16 b; __builtin_memcpy(&b, &s, 2); return b2f(b);
}

#define NB 128   // batch
#define NN 128   // nodes per graph
#define KNN 16   // neighbors
#define M_NODES (NB * NN)          // 16384
#define NPOS ((long)M_NODES * KNN) // 262144 edge rows

// ---------------- zero a small float buffer ----------------
__global__ void zero_kernel(float* __restrict__ p, int n) {
    int i = blockIdx.x * blockDim.x + threadIdx.x;
    if (i < n) p[i] = 0.f;
}

// ---------------- weight precompute: transposed bf16 hi/lo split ----------------
__global__ __launch_bounds__(256) void wconv_kernel(const float* __restrict__ W,
        short* __restrict__ Whi, short* __restrict__ Wlo, int O) {
    int d = blockIdx.x * 256 + threadIdx.x;      // d = c*O + k
    int c = d / O, k = d - c * O;
    float w = W[(size_t)k * O + c];
    short hi = f2bs(w);
    Whi[d] = hi;
    Wlo[d] = f2bs(w - bs2f(hi));
}

// ---------------- kNN part 1: per-node squared norm over first D dims ----------------
__global__ __launch_bounds__(256) void sq_kernel(const float* __restrict__ x, int C, int D,
                                                 float* __restrict__ sq) {
    int n = blockIdx.x * 256 + threadIdx.x;
    if (n >= M_NODES) return;
    float s = 0.f;
    for (int d = 0; d < D; ++d) { float v = x[(size_t)n * C + d]; s += v * v; }
    sq[n] = s;
}

// ---------------- kNN part 2: d2[node][j] = sq_i + sq_j - 2 dot (+1e9 on diag) --------
// 64x64 tile per block; grid (2, M/64). Accumulation order matches the old serial loop.
__global__ __launch_bounds__(256) void dist_kernel(const float* __restrict__ x, int C, int D,
                                                   const float* __restrict__ sq,
                                                   float* __restrict__ d2) {
    __shared__ float As[16][65];  // [k][m] row nodes
    __shared__ float Bs[16][65];  // [k][j] col nodes (same batch)
    const int tid = threadIdx.x;
    const int tx = tid & 15, ty = tid >> 4;
    const int m0 = blockIdx.y * 64;          // global row node
    const int b  = m0 >> 7;                  // batch
    const int c0 = blockIdx.x * 64;          // col within batch
    float acc[4][4];
#pragma unroll
    for (int r = 0; r < 4; ++r)
#pragma unroll
        for (int c = 0; c < 4; ++c) acc[r][c] = 0.f;
    for (int k0 = 0; k0 < D; k0 += 16) {
        for (int l = tid; l < 1024; l += 256) {
            int k = l & 15, m = l >> 4;
            int kk = k0 + k;
            As[k][m] = (kk < D) ? x[(size_t)(m0 + m) * C + kk] : 0.f;
            Bs[k][m] = (kk < D) ? x[(size_t)(b * NN + c0 + m) * C + kk] : 0.f;
        }
        __syncthreads();
        for (int k = 0; k < 16; ++k) {
            float av[4], bv[4];
#pragma unroll
            for (int r = 0; r < 4; ++r) av[r] = As[k][ty + 16 * r];
#pragma unroll
            for (int c = 0; c < 4; ++c) bv[c] = Bs[k][tx + 16 * c];
#pragma unroll
            for (int r = 0; r < 4; ++r)
#pragma unroll
                for (int c = 0; c < 4; ++c) acc[r][c] += av[r] * bv[c];
        }
        __syncthreads();
    }
#pragma unroll
    for (int r = 0; r < 4; ++r)
#pragma unroll
        for (int c = 0; c < 4; ++c) {
            int m = m0 + ty + 16 * r;            // global row node
            int jl = c0 + tx + 16 * c;           // col within batch
            int jg = b * NN + jl;                // global col node
            float v = sq[m] + sq[jg] - 2.0f * acc[r][c];
            if (m == jg) v += 1e9f;
            d2[(size_t)m * NN + jl] = v;
        }
}

// ---------------- kNN part 3: wave-per-node top-16 select (ties -> lower j) ----------
__global__ __launch_bounds__(256) void knn_select_kernel(const float* __restrict__ d2,
                                                         int* __restrict__ idx) {
    const int node = blockIdx.x * 4 + (threadIdx.x >> 6);
    const int lane = threadIdx.x & 63;
    const float* row = d2 + (size_t)node * NN;
    float v0 = row[lane], v1 = row[lane + 64];
    int j0 = lane, j1 = lane + 64;
    int myIdx = 0;
#pragma unroll
    for (int k = 0; k < KNN; ++k) {
        float bv; int bj;
        if (v1 < v0 || (v1 == v0 && j1 < j0)) { bv = v1; bj = j1; }
        else                                 { bv = v0; bj = j0; }
#pragma unroll
        for (int off = 32; off; off >>= 1) {
            float ov = __shfl_xor(bv, off);
            int oj = __shfl_xor(bj, off);
            if (ov < bv || (ov == bv && oj < bj)) { bv = ov; bj = oj; }
        }
        if (bj == j0) v0 = 3.0e38f;
        if (bj == j1) v1 = 3.0e38f;
        if (lane == k) myIdx = bj;
    }
    if (lane < KNN) idx[(size_t)node * KNN + lane] = myIdx;
}

// ---------------- node GEMM: T1 = x@(Wt-Wb)+bias, T2 = x@Wb (all f32) ----------------
__global__ __launch_bounds__(256) void node_gemm_kernel(const float* __restrict__ x, int F, int O,
                                                        const float* __restrict__ W, const float* __restrict__ bias,
                                                        float* __restrict__ T1, float* __restrict__ T2) {
    __shared__ float As[16][65];  // [k][m]
    __shared__ float Bt[16][65];  // [k][c] top half of W
    __shared__ float Bb[16][65];  // [k][c] bottom half
    const int tid = threadIdx.x;
    const int tx = tid & 15, ty = tid >> 4;
    const int m0 = blockIdx.y * 64, c0 = blockIdx.x * 64;
    float aT[4][4], aB[4][4];
#pragma unroll
    for (int r = 0; r < 4; ++r)
#pragma unroll
        for (int c = 0; c < 4; ++c) { aT[r][c] = 0.f; aB[r][c] = 0.f; }
    for (int k0 = 0; k0 < F; k0 += 16) {
        for (int l = tid; l < 1024; l += 256) {
            int k = l & 15, m = l >> 4;
            int kk = k0 + k;
            As[k][m] = (kk < F) ? x[(size_t)(m0 + m) * F + kk] : 0.f;
        }
        for (int l = tid; l < 1024; l += 256) {
            int c = l & 63, k = l >> 6;
            int kk = k0 + k;
            Bt[k][c] = (kk < F) ? W[(size_t)kk * O + c0 + c] : 0.f;
            Bb[k][c] = (kk < F) ? W[(size_t)(F + kk) * O + c0 + c] : 0.f;
        }
        __syncthreads();
        for (int k = 0; k < 16; ++k) {
            float av[4], bt[4], bb[4];
#pragma unroll
            for (int r = 0; r < 4; ++r) av[r] = As[k][ty + 16 * r];
#pragma unroll
            for (int c = 0; c < 4; ++c) { bt[c] = Bt[k][tx + 16 * c]; bb[c] = Bb[k][tx + 16 * c]; }
#pragma unroll
            for (int r = 0; r < 4; ++r)
#pragma unroll
                for (int c = 0; c < 4; ++c) { aT[r][c] += av[r] * bt[c]; aB[r][c] += av[r] * bb[c]; }
        }
        __syncthreads();
    }
    float bc[4];
#pragma unroll
    for (int c = 0; c < 4; ++c) bc[c] = bias[c0 + tx + 16 * c];
#pragma unroll
    for (int r = 0; r < 4; ++r)
#pragma unroll
        for (int c = 0; c < 4; ++c) {
            size_t m = m0 + ty + 16 * r, cc = c0 + tx + 16 * c;
            T1[m * O + cc] = aT[r][c] - aB[r][c] + bc[c];
            T2[m * O + cc] = aB[r][c];
        }
}

// ---------------- stats of layer-0 output h0 = T1[n] + T2[nbr], never materialized ------
template<int O>
__global__ __launch_bounds__(256) void stats0_kernel(const float* __restrict__ T1,
        const float* __restrict__ T2, const int* __restrict__ idx, float* __restrict__ st0) {
    constexpr int OSH = (O == 64) ? 6 : (O == 128 ? 7 : 8);
    __shared__ float ls[256], lss[256];
    const int t = threadIdx.x;
    const long n = NPOS * O;
    float s = 0.f, ss = 0.f;
    for (long i = (long)blockIdx.x * 256 + t; i < n; i += (long)gridDim.x * 256) {
        int c = (int)(i & (O - 1));
        long e = i >> OSH;           // edge row
        int nd = (int)(e >> 4);      // node
        int j = idx[e];              // neighbor (node-local)
        int g = ((nd >> 7) << 7) + j;
        float v = T1[(size_t)nd * O + c] + T2[(size_t)g * O + c];
        s += v; ss += v * v;
    }
    ls[t] = s; lss[t] = ss;
    __syncthreads();
    for (int off = 128; off >= O; off >>= 1) {
        if (t < off) { ls[t] += ls[t + off]; lss[t] += lss[t + off]; }
        __syncthreads();
    }
    if (t < O) { atomicAdd(&st0[t], ls[t]); atomicAdd(&st0[O + t], lss[t]); }
}

// ---------------- fused conv stage kernel (MFMA recompute pipeline) ----------------
template<int O, int STAGE>
__global__ __launch_bounds__(256) void conv_stage_kernel(
    const float* __restrict__ T1, const float* __restrict__ T2, const int* __restrict__ idx,
    const short* __restrict__ W1hi, const short* __restrict__ W1lo, const float* __restrict__ bias1,
    const short* __restrict__ W2hi, const short* __restrict__ W2lo, const float* __restrict__ bias2,
    const float* __restrict__ gm0, const float* __restrict__ bt0,
    const float* __restrict__ gm1, const float* __restrict__ bt1,
    const float* __restrict__ gm2, const float* __restrict__ bt2,
    const float* __restrict__ st0, float* __restrict__ st1, float* __restrict__ st2,
    const float* __restrict__ xold, float* __restrict__ xnew, int F, float inv_n)
{
    constexpr int NCT = O / 16;                       // col-tiles per wave
    constexpr int OSH = (O == 64) ? 6 : (O == 128 ? 7 : 8);
    constexpr int AP = O + 8;                         // A row pitch
    __shared__ __align__(16) short Am[64][AP];        // activations bf16 [m][k]
    __shared__ __align__(16) short Wt[O][40];         // W K-slice transposed [c][kk]
    __shared__ float sc0[O], sh0[O], sc1[O], sh1[O], sc2[O], sh2[O];
    __shared__ float red[4 * O], redq[4 * O];
    __shared__ int gArr[64];
    const int tid = threadIdx.x;
    const int lane = tid & 63, wave = tid >> 6;
    const int l15 = lane & 15, quad = lane >> 4;
    const int e0 = blockIdx.x * 64;                   // first edge row
    const int nb0 = e0 >> 4;                          // first node (4 per block)

    if (tid < O) {
        {
            float mean = st0[tid] * inv_n;
            float var = fmaxf(st0[O + tid] * inv_n - mean * mean, 0.f);
            float s = rsqrtf(var + 1e-5f) * gm0[tid];
            sc0[tid] = s; sh0[tid] = bt0[tid] - mean * s;
        }
        if (STAGE >= 2) {
            float mean = st1[tid] * inv_n;
            float var = fmaxf(st1[O + tid] * inv_n - mean * mean, 0.f);
            float s = rsqrtf(var + 1e-5f) * gm1[tid];
            sc1[tid] = s; sh1[tid] = bt1[tid] - mean * s;
        }
        if (STAGE == 3) {
            float mean = st2[tid] * inv_n;
            float var = fmaxf(st2[O + tid] * inv_n - mean * mean, 0.f);
            float s = rsqrtf(var + 1e-5f) * gm2[tid];
            sc2[tid] = s; sh2[tid] = bt2[tid] - mean * s;
        }
    }
    if (tid < 64) {
        int e = e0 + tid;
        int nd = e >> 4;
        gArr[tid] = ((nd >> 7) << 7) + idx[e];
    }
    __syncthreads();

    // A0 build into Am[m][k], float2 loads + paired bf16 stores
    for (int l = tid; l < 32 * O; l += 256) {
        int m = l >> (OSH - 1);
        int c = (l & (O / 2 - 1)) * 2;
        const float2 t1 = *(const float2*)&T1[(size_t)(nb0 + (m >> 4)) * O + c];
        const float2 t2 = *(const float2*)&T2[(size_t)gArr[m] * O + c];
        float v0 = fmaxf((t1.x + t2.x) * sc0[c] + sh0[c], 0.f);
        float v1 = fmaxf((t1.y + t2.y) * sc0[c + 1] + sh0[c + 1], 0.f);
        v2s pr; pr[0] = f2bs(v0); pr[1] = f2bs(v1);
        *(v2s*)&Am[m][c] = pr;
    }

    v4f acc[NCT];
    const int sc_ = tid >> 3;            // staging row offset (conflict-free map)
    const int skk = (tid & 7) * 4;       // kk start
    auto do_gemm = [&](const short* __restrict__ Wa, const short* __restrict__ Wb) {
#pragma unroll
        for (int ct = 0; ct < NCT; ++ct)
#pragma unroll
            for (int r = 0; r < 4; ++r) acc[ct][r] = 0.f;
        for (int half = 0; half < 2; ++half) {
            const short* __restrict__ Wg = half ? Wb : Wa;
            for (int k0 = 0; k0 < O; k0 += 32) {
                __syncthreads();
#pragma unroll
                for (int c0 = 0; c0 < O; c0 += 32) {
                    int c = c0 + sc_;
                    *(v4s*)&Wt[c][skk] = *(const v4s*)&Wg[(size_t)c * O + k0 + skk];
                }
                __syncthreads();
                v8s av = *(const v8s*)&Am[wave * 16 + l15][k0 + quad * 8];
#pragma unroll
                for (int ct = 0; ct < NCT; ++ct) {
                    v8s bv = *(const v8s*)&Wt[ct * 16 + l15][quad * 8];
                    acc[ct] = __builtin_amdgcn_mfma_f32_16x16x32_bf16(av, bv, acc[ct], 0, 0, 0);
                }
            }
        }
    };

    // GEMM1: h1 = A0 @ W1 + b1
    do_gemm(W1hi, W1lo);
#pragma unroll
    for (int ct = 0; ct < NCT; ++ct) {
        float bb = bias1[ct * 16 + l15];
#pragma unroll
        for (int r = 0; r < 4; ++r) acc[ct][r] += bb;
    }

    if (STAGE == 1) {
#pragma unroll
        for (int ct = 0; ct < NCT; ++ct) {
            int c = ct * 16 + l15;
            float s = 0.f, q = 0.f;
#pragma unroll
            for (int r = 0; r < 4; ++r) { float v = acc[ct][r]; s += v; q += v * v; }
            s += __shfl_down(s, 32); s += __shfl_down(s, 16);
            q += __shfl_down(q, 32); q += __shfl_down(q, 16);
            if (quad == 0) { red[wave * O + c] = s; redq[wave * O + c] = q; }
        }
        __syncthreads();
        if (tid < O) {
            float s = red[tid] + red[O + tid] + red[2 * O + tid] + red[3 * O + tid];
            float q = redq[tid] + redq[O + tid] + redq[2 * O + tid] + redq[3 * O + tid];
            atomicAdd(&st1[tid], s); atomicAdd(&st1[O + tid], q);
        }
        return;
    }

    // A1 = relu(bn1(h1)) -> Am
#pragma unroll
    for (int ct = 0; ct < NCT; ++ct) {
        int c = ct * 16 + l15;
        float sc = sc1[c], sh = sh1[c];
#pragma unroll
        for (int r = 0; r < 4; ++r) {
            float v = fmaxf(acc[ct][r] * sc + sh, 0.f);
            Am[wave * 16 + quad * 4 + r][c] = f2bs(v);
        }
    }

    // GEMM2: h2 = A1 @ W2 + b2
    do_gemm(W2hi, W2lo);
#pragma unroll
    for (int ct = 0; ct < NCT; ++ct) {
        float bb = bias2[ct * 16 + l15];
#pragma unroll
        for (int r = 0; r < 4; ++r) acc[ct][r] += bb;
    }

    if (STAGE == 2) {
#pragma unroll
        for (int ct = 0; ct < NCT; ++ct) {
            int c = ct * 16 + l15;
            float s = 0.f, q = 0.f;
#pragma unroll
            for (int r = 0; r < 4; ++r) { float v = acc[ct][r]; s += v; q += v * v; }
            s += __shfl_down(s, 32); s += __shfl_down(s, 16);
            q += __shfl_down(q, 32); q += __shfl_down(q, 16);
            if (quad == 0) { red[wave * O + c] = s; redq[wave * O + c] = q; }
        }
        __syncthreads();
        if (tid < O) {
            float s = red[tid] + red[O + tid] + red[2 * O + tid] + red[3 * O + tid];
            float q = redq[tid] + redq[O + tid] + redq[2 * O + tid] + redq[3 * O + tid];
            atomicAdd(&st2[tid], s); atomicAdd(&st2[O + tid], q);
        }
        return;
    }

    // STAGE3: A2 = relu(bn2(h2)); k-mean via shfl; skip-concat
    const int Cnew = O + F;
#pragma unroll
    for (int ct = 0; ct < NCT; ++ct) {
        int c = ct * 16 + l15;
        float sc = sc2[c], sh = sh2[c];
        float s = 0.f;
#pragma unroll
        for (int r = 0; r < 4; ++r) s += fmaxf(acc[ct][r] * sc + sh, 0.f);
        s += __shfl_down(s, 32); s += __shfl_down(s, 16);
        if (quad == 0) xnew[(size_t)(nb0 + wave) * Cnew + c] = s * (1.0f / 16.0f);
    }
    for (int l = tid; l < 4 * F; l += 256) {
        int nd = l / F, c = l - nd * F;
        xnew[(size_t)(nb0 + nd) * Cnew + O + c] = xold[(size_t)(nb0 + nd) * F + c];
    }
}

// ---------------- global mean pool over nodes ----------------
__global__ __launch_bounds__(256) void pool_kernel(const float* __restrict__ x, float* __restrict__ pooled, int C) {
    int b = blockIdx.x, t = threadIdx.x;
    for (int c = t; c < C; c += 256) {
        float s = 0.f;
        for (int n = 0; n < NN; ++n) s += x[(size_t)(b * NN + n) * C + c];
        pooled[b * C + c] = s * (1.0f / NN);
    }
}

// ---------------- fc1 (no act) + fc2 ----------------
__global__ __launch_bounds__(256) void fc_kernel(const float* __restrict__ pooled,
                                                 const float* __restrict__ W1, const float* __restrict__ b1,
                                                 const float* __restrict__ W2, const float* __restrict__ b2,
                                                 float* __restrict__ out, int C) {
    __shared__ float px[451];
    __shared__ float h1[256];
    int b = blockIdx.x, t = threadIdx.x;
    for (int c = t; c < C; c += 256) px[c] = pooled[b * C + c];
    __syncthreads();
    float s = 0.f;
    for (int i = 0; i < C; ++i) s += px[i] * W1[(size_t)i * 256 + t];
    h1[t] = s + b1[t];
    __syncthreads();
    if (t < 5) {
        float s2 = 0.f;
        for (int j = 0; j < 256; ++j) s2 += h1[j] * W2[j * 5 + t];
        out[b * 5 + t] = s2 + b2[t];
    }
}

extern "C" void kernel_launch(void* const* d_in, const int* in_sizes, int n_in,
                              void* d_out, int out_size, void* d_ws, size_t ws_size,
                              hipStream_t stream) {
    const float* xin = (const float*)d_in[0];
    auto Wp = [&](int c, int l) { return (const float*)d_in[1 + c * 12 + l * 4 + 0]; };
    auto Bp = [&](int c, int l) { return (const float*)d_in[1 + c * 12 + l * 4 + 1]; };
    auto Gp = [&](int c, int l) { return (const float*)d_in[1 + c * 12 + l * 4 + 2]; };
    auto Ep = [&](int c, int l) { return (const float*)d_in[1 + c * 12 + l * 4 + 3]; };
    const float* fcW1 = (const float*)d_in[37];
    const float* fcb1 = (const float*)d_in[38];
    const float* fcW2 = (const float*)d_in[39];
    const float* fcb2 = (const float*)d_in[40];

    char* ws = (char*)d_ws;
    size_t off = 0;
    auto alloc = [&](size_t bytes) -> void* {
        void* p = ws + off;
        off += (bytes + 255) & ~(size_t)255;
        return p;
    };
    const int M = M_NODES;
    float* x1     = (float*)alloc((size_t)M * 67 * 4);   //  4.4 MB
    float* x2     = (float*)alloc((size_t)M * 195 * 4);  // 12.8 MB
    float* x3     = (float*)alloc((size_t)M * 451 * 4);  // 29.6 MB
    float* T1     = (float*)alloc((size_t)M * 256 * 4);  // 16.8 MB
    float* T2     = (float*)alloc((size_t)M * 256 * 4);  // 16.8 MB
    int*   idxb   = (int*)alloc((size_t)M * KNN * 4);    //  1.0 MB
    float* stats  = (float*)alloc(1536 * 4);             // st0/st1/st2
    float* pooled = (float*)alloc((size_t)NB * 451 * 4); //  0.23 MB
    short* W1hi   = (short*)alloc(256 * 256 * 2);        // transposed bf16 weights
    short* W1lo   = (short*)alloc(256 * 256 * 2);
    short* W2hi   = (short*)alloc(256 * 256 * 2);
    short* W2lo   = (short*)alloc(256 * 256 * 2);
    float* d2buf  = (float*)alloc((size_t)M * NN * 4);   //  8.4 MB
    float* sqbuf  = (float*)alloc((size_t)M * 4);        //  64 KB
    (void)ws_size; (void)in_sizes; (void)n_in; (void)out_size; // total ~92 MiB

    float* st0 = stats, *st1 = stats + 512, *st2 = stats + 1024;
    const float inv_n = 1.0f / (float)NPOS;

    auto run_conv = [&](const float* xc, float* xn, int F, int D, int O, int c) {
        sq_kernel<<<M / 256, 256, 0, stream>>>(xc, F, D, sqbuf);
        dist_kernel<<<dim3(2, M / 64), 256, 0, stream>>>(xc, F, D, sqbuf, d2buf);
        knn_select_kernel<<<M / 4, 256, 0, stream>>>(d2buf, idxb);
        node_gemm_kernel<<<dim3(O / 64, M / 64), 256, 0, stream>>>(xc, F, O, Wp(c, 0), Bp(c, 0), T1, T2);
        wconv_kernel<<<O * O / 256, 256, 0, stream>>>(Wp(c, 1), W1hi, W1lo, O);
        wconv_kernel<<<O * O / 256, 256, 0, stream>>>(Wp(c, 2), W2hi, W2lo, O);
        zero_kernel<<<6, 256, 0, stream>>>(stats, 1536);
        const int grid = (int)(NPOS / 64);
        if (O == 64) {
            stats0_kernel<64><<<512, 256, 0, stream>>>(T1, T2, idxb, st0);
            conv_stage_kernel<64, 1><<<grid, 256, 0, stream>>>(T1, T2, idxb,
                W1hi, W1lo, Bp(c,1), W2hi, W2lo, Bp(c,2), Gp(c,0), Ep(c,0), Gp(c,1), Ep(c,1),
                Gp(c,2), Ep(c,2), st0, st1, st2, xc, xn, F, inv_n);
            conv_stage_kernel<64, 2><<<grid, 256, 0, stream>>>(T1, T2, idxb,
                W1hi, W1lo, Bp(c,1), W2hi, W2lo, Bp(c,2), Gp(c,0), Ep(c,0), Gp(c,1), Ep(c,1),
                Gp(c,2), Ep(c,2), st0, st1, st2, xc, xn, F, inv_n);
            conv_stage_kernel<64, 3><<<grid, 256, 0, stream>>>(T1, T2, idxb,
                W1hi, W1lo, Bp(c,1), W2hi, W2lo, Bp(c,2), Gp(c,0), Ep(c,0), Gp(c,1), Ep(c,1),
                Gp(c,2), Ep(c,2), st0, st1, st2, xc, xn, F, inv_n);
        } else if (O == 128) {
            stats0_kernel<128><<<512, 256, 0, stream>>>(T1, T2, idxb, st0);
            conv_stage_kernel<128, 1><<<grid, 256, 0, stream>>>(T1, T2, idxb,
                W1hi, W1lo, Bp(c,1), W2hi, W2lo, Bp(c,2), Gp(c,0), Ep(c,0), Gp(c,1), Ep(c,1),
                Gp(c,2), Ep(c,2), st0, st1, st2, xc, xn, F, inv_n);
            conv_stage_kernel<128, 2><<<grid, 256, 0, stream>>>(T1, T2, idxb,
                W1hi, W1lo, Bp(c,1), W2hi, W2lo, Bp(c,2), Gp(c,0), Ep(c,0), Gp(c,1), Ep(c,1),
                Gp(c,2), Ep(c,2), st0, st1, st2, xc, xn, F, inv_n);
            conv_stage_kernel<128, 3><<<grid, 256, 0, stream>>>(T1, T2, idxb,
                W1hi, W1lo, Bp(c,1), W2hi, W2lo, Bp(c,2), Gp(c,0), Ep(c,0), Gp(c,1), Ep(c,1),
                Gp(c,2), Ep(c,2), st0, st1, st2, xc, xn, F, inv_n);
        } else {
            stats0_kernel<256><<<1024, 256, 0, stream>>>(T1, T2, idxb, st0);
            conv_stage_kernel<256, 1><<<grid, 256, 0, stream>>>(T1, T2, idxb,
                W1hi, W1lo, Bp(c,1), W2hi, W2lo, Bp(c,2), Gp(c,0), Ep(c,0), Gp(c,1), Ep(c,1),
                Gp(c,2), Ep(c,2), st0, st1, st2, xc, xn, F, inv_n);
            conv_stage_kernel<256, 2><<<grid, 256, 0, stream>>>(T1, T2, idxb,
                W1hi, W1lo, Bp(c,1), W2hi, W2lo, Bp(c,2), Gp(c,0), Ep(c,0), Gp(c,1), Ep(c,1),
                Gp(c,2), Ep(c,2), st0, st1, st2, xc, xn, F, inv_n);
            conv_stage_kernel<256, 3><<<grid, 256, 0, stream>>>(T1, T2, idxb,
                W1hi, W1lo, Bp(c,1), W2hi, W2lo, Bp(c,2), Gp(c,0), Ep(c,0), Gp(c,1), Ep(c,1),
                Gp(c,2), Ep(c,2), st0, st1, st2, xc, xn, F, inv_n);
        }
    };

    run_conv(xin, x1, 3, 2, 64, 0);     // -> x1: C=67
    run_conv(x1, x2, 67, 67, 128, 1);   // -> x2: C=195
    run_conv(x2, x3, 195, 195, 256, 2); // -> x3: C=451
    pool_kernel<<<NB, 256, 0, stream>>>(x3, pooled, 451);
    fc_kernel<<<NB, 256, 0, stream>>>(pooled, fcW1, fcb1, fcW2, fcb2, (float*)d_out, 451);
}

// Round 9
// 1741.904 us; speedup vs baseline: 4.8032x; 1.3921x over previous
//
#include <hip/hip_runtime.h>
#include <hip/hip_bf16.h>

typedef __hip_bfloat16 bf16;
typedef short v8s __attribute__((ext_vector_type(8)));
typedef short v4s __attribute__((ext_vector_type(4)));
typedef short v2s __attribute__((ext_vector_type(2)));
typedef float v4f __attribute__((ext_vector_type(4)));

__device__ __forceinline__ float b2f(bf16 v) { return __bfloat162float(v); }
__device__ __forceinline__ bf16  f2b(float v) { return __float2bfloat16(v); }
__device__ __forceinline__ short f2bs(float v) {
    bf16 b = f2b(v); short s; __builtin_memcpy(&s, &b, 2); return s;
}
__device__ __forceinline__ float bs2f(short s) {
    bf16 b; __builtin_memcpy(&b, &s, 2); return b2f(b);
}

#define NB 128
#define NN 128
#define KNN 16
#define M_NODES (NB * NN)          // 16384
#define NPOS ((long)M_NODES * KNN) // 262144 edge rows

// ---------------- zero a small float buffer ----------------
__global__ void zero_kernel(float* __restrict__ p, int n) {
    int i = blockIdx.x * blockDim.x + threadIdx.x;
    if (i < n) p[i] = 0.f;
}

// ---------------- weight precompute: transposed bf16 ----------------
__global__ __launch_bounds__(256) void wconv_kernel(const float* __restrict__ W,
        short* __restrict__ Wt, int O) {
    int d = blockIdx.x * 256 + threadIdx.x;      // d = c*O + k
    int c = d / O, k = d - c * O;
    Wt[d] = f2bs(W[(size_t)k * O + c]);
}

// ---------------- kNN part 1: per-node squared norm ----------------
__global__ __launch_bounds__(256) void sq_kernel(const float* __restrict__ x, int C, int D,
                                                 float* __restrict__ sq) {
    int n = blockIdx.x * 256 + threadIdx.x;
    if (n >= M_NODES) return;
    float s = 0.f;
    for (int d = 0; d < D; ++d) { float v = x[(size_t)n * C + d]; s += v * v; }
    sq[n] = s;
}

// ---------------- kNN part 2: d2 tile GEMM ----------------
__global__ __launch_bounds__(256) void dist_kernel(const float* __restrict__ x, int C, int D,
                                                   const float* __restrict__ sq,
                                                   float* __restrict__ d2) {
    __shared__ float As[16][65];
    __shared__ float Bs[16][65];
    const int tid = threadIdx.x;
    const int tx = tid & 15, ty = tid >> 4;
    const int m0 = blockIdx.y * 64;
    const int b  = m0 >> 7;
    const int c0 = blockIdx.x * 64;
    float acc[4][4];
#pragma unroll
    for (int r = 0; r < 4; ++r)
#pragma unroll
        for (int c = 0; c < 4; ++c) acc[r][c] = 0.f;
    for (int k0 = 0; k0 < D; k0 += 16) {
        for (int l = tid; l < 1024; l += 256) {
            int k = l & 15, m = l >> 4;
            int kk = k0 + k;
            As[k][m] = (kk < D) ? x[(size_t)(m0 + m) * C + kk] : 0.f;
            Bs[k][m] = (kk < D) ? x[(size_t)(b * NN + c0 + m) * C + kk] : 0.f;
        }
        __syncthreads();
        for (int k = 0; k < 16; ++k) {
            float av[4], bv[4];
#pragma unroll
            for (int r = 0; r < 4; ++r) av[r] = As[k][ty + 16 * r];
#pragma unroll
            for (int c = 0; c < 4; ++c) bv[c] = Bs[k][tx + 16 * c];
#pragma unroll
            for (int r = 0; r < 4; ++r)
#pragma unroll
                for (int c = 0; c < 4; ++c) acc[r][c] += av[r] * bv[c];
        }
        __syncthreads();
    }
#pragma unroll
    for (int r = 0; r < 4; ++r)
#pragma unroll
        for (int c = 0; c < 4; ++c) {
            int m = m0 + ty + 16 * r;
            int jl = c0 + tx + 16 * c;
            int jg = b * NN + jl;
            float v = sq[m] + sq[jg] - 2.0f * acc[r][c];
            if (m == jg) v += 1e9f;
            d2[(size_t)m * NN + jl] = v;
        }
}

// ---------------- kNN part 3: wave-per-node top-16 ----------------
__global__ __launch_bounds__(256) void knn_select_kernel(const float* __restrict__ d2,
                                                         int* __restrict__ idx) {
    const int node = blockIdx.x * 4 + (threadIdx.x >> 6);
    const int lane = threadIdx.x & 63;
    const float* row = d2 + (size_t)node * NN;
    float v0 = row[lane], v1 = row[lane + 64];
    int j0 = lane, j1 = lane + 64;
    int myIdx = 0;
#pragma unroll
    for (int k = 0; k < KNN; ++k) {
        float bv; int bj;
        if (v1 < v0 || (v1 == v0 && j1 < j0)) { bv = v1; bj = j1; }
        else                                 { bv = v0; bj = j0; }
#pragma unroll
        for (int off = 32; off; off >>= 1) {
            float ov = __shfl_xor(bv, off);
            int oj = __shfl_xor(bj, off);
            if (ov < bv || (ov == bv && oj < bj)) { bv = ov; bj = oj; }
        }
        if (bj == j0) v0 = 3.0e38f;
        if (bj == j1) v1 = 3.0e38f;
        if (lane == k) myIdx = bj;
    }
    if (lane < KNN) idx[(size_t)node * KNN + lane] = myIdx;
}

// ---------------- node GEMM: T1 = x@(Wt-Wb)+bias, T2 = x@Wb (f32) ----------------
__global__ __launch_bounds__(256) void node_gemm_kernel(const float* __restrict__ x, int F, int O,
                                                        const float* __restrict__ W, const float* __restrict__ bias,
                                                        float* __restrict__ T1, float* __restrict__ T2) {
    __shared__ float As[16][65];
    __shared__ float Bt[16][65];
    __shared__ float Bb[16][65];
    const int tid = threadIdx.x;
    const int tx = tid & 15, ty = tid >> 4;
    const int m0 = blockIdx.y * 64, c0 = blockIdx.x * 64;
    float aT[4][4], aB[4][4];
#pragma unroll
    for (int r = 0; r < 4; ++r)
#pragma unroll
        for (int c = 0; c < 4; ++c) { aT[r][c] = 0.f; aB[r][c] = 0.f; }
    for (int k0 = 0; k0 < F; k0 += 16) {
        for (int l = tid; l < 1024; l += 256) {
            int k = l & 15, m = l >> 4;
            int kk = k0 + k;
            As[k][m] = (kk < F) ? x[(size_t)(m0 + m) * F + kk] : 0.f;
        }
        for (int l = tid; l < 1024; l += 256) {
            int c = l & 63, k = l >> 6;
            int kk = k0 + k;
            Bt[k][c] = (kk < F) ? W[(size_t)kk * O + c0 + c] : 0.f;
            Bb[k][c] = (kk < F) ? W[(size_t)(F + kk) * O + c0 + c] : 0.f;
        }
        __syncthreads();
        for (int k = 0; k < 16; ++k) {
            float av[4], bt[4], bb[4];
#pragma unroll
            for (int r = 0; r < 4; ++r) av[r] = As[k][ty + 16 * r];
#pragma unroll
            for (int c = 0; c < 4; ++c) { bt[c] = Bt[k][tx + 16 * c]; bb[c] = Bb[k][tx + 16 * c]; }
#pragma unroll
            for (int r = 0; r < 4; ++r)
#pragma unroll
                for (int c = 0; c < 4; ++c) { aT[r][c] += av[r] * bt[c]; aB[r][c] += av[r] * bb[c]; }
        }
        __syncthreads();
    }
    float bc[4];
#pragma unroll
    for (int c = 0; c < 4; ++c) bc[c] = bias[c0 + tx + 16 * c];
#pragma unroll
    for (int r = 0; r < 4; ++r)
#pragma unroll
        for (int c = 0; c < 4; ++c) {
            size_t m = m0 + ty + 16 * r, cc = c0 + tx + 16 * c;
            T1[m * O + cc] = aT[r][c] - aB[r][c] + bc[c];
            T2[m * O + cc] = aB[r][c];
        }
}

// ---------------- stats of h0 = T1[n] + T2[nbr] (not materialized) ------
template<int O>
__global__ __launch_bounds__(256) void stats0_kernel(const float* __restrict__ T1,
        const float* __restrict__ T2, const int* __restrict__ idx, float* __restrict__ st0) {
    constexpr int OSH = (O == 64) ? 6 : (O == 128 ? 7 : 8);
    __shared__ float ls[256], lss[256];
    const int t = threadIdx.x;
    const long n = NPOS * O;
    float s = 0.f, ss = 0.f;
    for (long i = (long)blockIdx.x * 256 + t; i < n; i += (long)gridDim.x * 256) {
        int c = (int)(i & (O - 1));
        long e = i >> OSH;
        int nd = (int)(e >> 4);
        int j = idx[e];
        int g = ((nd >> 7) << 7) + j;
        float v = T1[(size_t)nd * O + c] + T2[(size_t)g * O + c];
        s += v; ss += v * v;
    }
    ls[t] = s; lss[t] = ss;
    __syncthreads();
    for (int off = 128; off >= O; off >>= 1) {
        if (t < off) { ls[t] += ls[t + off]; lss[t] += lss[t + off]; }
        __syncthreads();
    }
    if (t < O) { atomicAdd(&st0[t], ls[t]); atomicAdd(&st0[O + t], lss[t]); }
}

// ======================= shared GEMM helpers (macros via templates) ==================

// ---------------- gemm1: A0-build -> h1 = A0@W1 + b1 -> write h (bf16) + st1 ---------
template<int O>
__global__ __launch_bounds__(256) void gemm1_kernel(
    const float* __restrict__ T1, const float* __restrict__ T2, const int* __restrict__ idx,
    const short* __restrict__ W1, const float* __restrict__ bias1,
    const float* __restrict__ gm0, const float* __restrict__ bt0,
    const float* __restrict__ st0, float* __restrict__ st1,
    short* __restrict__ h, float inv_n)
{
    constexpr int NCT = O / 16;
    constexpr int OSH = (O == 64) ? 6 : (O == 128 ? 7 : 8);
    constexpr int AP = O + 8;
    __shared__ __align__(16) short Am[64][AP];
    __shared__ __align__(16) short Wt[O][40];
    __shared__ float sc0[O], sh0[O];
    __shared__ float red[4 * O], redq[4 * O];
    __shared__ int gArr[64];
    const int tid = threadIdx.x;
    const int lane = tid & 63, wave = tid >> 6;
    const int l15 = lane & 15, quad = lane >> 4;
    const int e0 = blockIdx.x * 64;
    const int nb0 = e0 >> 4;

    if (tid < O) {
        float mean = st0[tid] * inv_n;
        float var = fmaxf(st0[O + tid] * inv_n - mean * mean, 0.f);
        float s = rsqrtf(var + 1e-5f) * gm0[tid];
        sc0[tid] = s; sh0[tid] = bt0[tid] - mean * s;
    }
    if (tid < 64) {
        int e = e0 + tid;
        int nd = e >> 4;
        gArr[tid] = ((nd >> 7) << 7) + idx[e];
    }
    __syncthreads();

    // A0 build
    for (int l = tid; l < 32 * O; l += 256) {
        int m = l >> (OSH - 1);
        int c = (l & (O / 2 - 1)) * 2;
        const float2 t1 = *(const float2*)&T1[(size_t)(nb0 + (m >> 4)) * O + c];
        const float2 t2 = *(const float2*)&T2[(size_t)gArr[m] * O + c];
        float v0 = fmaxf((t1.x + t2.x) * sc0[c] + sh0[c], 0.f);
        float v1 = fmaxf((t1.y + t2.y) * sc0[c + 1] + sh0[c + 1], 0.f);
        v2s pr; pr[0] = f2bs(v0); pr[1] = f2bs(v1);
        *(v2s*)&Am[m][c] = pr;
    }

    v4f acc[NCT];
#pragma unroll
    for (int ct = 0; ct < NCT; ++ct)
#pragma unroll
        for (int r = 0; r < 4; ++r) acc[ct][r] = 0.f;
    const int swc = tid >> 2;            // staging row (64 rows per round)
    const int skk = (tid & 3) * 8;       // kk start (v8s)
    for (int k0 = 0; k0 < O; k0 += 32) {
        __syncthreads();
#pragma unroll
        for (int c0 = 0; c0 < O; c0 += 64) {
            int c = c0 + swc;
            *(v8s*)&Wt[c][skk] = *(const v8s*)&W1[(size_t)c * O + k0 + skk];
        }
        __syncthreads();
        v8s av = *(const v8s*)&Am[wave * 16 + l15][k0 + quad * 8];
#pragma unroll
        for (int ct = 0; ct < NCT; ++ct) {
            v8s bv = *(const v8s*)&Wt[ct * 16 + l15][quad * 8];
            acc[ct] = __builtin_amdgcn_mfma_f32_16x16x32_bf16(av, bv, acc[ct], 0, 0, 0);
        }
    }
#pragma unroll
    for (int ct = 0; ct < NCT; ++ct) {
        float bb = bias1[ct * 16 + l15];
#pragma unroll
        for (int r = 0; r < 4; ++r) acc[ct][r] += bb;
    }
    // stats
#pragma unroll
    for (int ct = 0; ct < NCT; ++ct) {
        int c = ct * 16 + l15;
        float s = 0.f, q = 0.f;
#pragma unroll
        for (int r = 0; r < 4; ++r) { float v = acc[ct][r]; s += v; q += v * v; }
        s += __shfl_down(s, 32); s += __shfl_down(s, 16);
        q += __shfl_down(q, 32); q += __shfl_down(q, 16);
        if (quad == 0) { red[wave * O + c] = s; redq[wave * O + c] = q; }
    }
    __syncthreads();     // also guarantees all GEMM Am reads complete
    if (tid < O) {
        float s = red[tid] + red[O + tid] + red[2 * O + tid] + red[3 * O + tid];
        float q = redq[tid] + redq[O + tid] + redq[2 * O + tid] + redq[3 * O + tid];
        atomicAdd(&st1[tid], s); atomicAdd(&st1[O + tid], q);
    }
    // scatter acc -> Am (C layout: row = quad*4+r, col = ct*16+l15), then coalesced store
#pragma unroll
    for (int ct = 0; ct < NCT; ++ct) {
        int c = ct * 16 + l15;
#pragma unroll
        for (int r = 0; r < 4; ++r) Am[wave * 16 + quad * 4 + r][c] = f2bs(acc[ct][r]);
    }
    __syncthreads();
    for (int g = tid; g < 8 * O; g += 256) {
        int row = g >> (OSH - 3);
        int c8 = (g & (O / 8 - 1)) * 8;
        *(v8s*)&h[(size_t)(e0 + row) * O + c8] = *(const v8s*)&Am[row][c8];
    }
}

// ---------------- gemm2: read h -> bn1+relu -> h2 = A1@W2 + b2 -> h (in place) + st2 --
template<int O>
__global__ __launch_bounds__(256) void gemm2_kernel(
    short* __restrict__ h,
    const short* __restrict__ W2, const float* __restrict__ bias2,
    const float* __restrict__ gm1, const float* __restrict__ bt1,
    const float* __restrict__ st1, float* __restrict__ st2, float inv_n)
{
    constexpr int NCT = O / 16;
    constexpr int OSH = (O == 64) ? 6 : (O == 128 ? 7 : 8);
    constexpr int AP = O + 8;
    __shared__ __align__(16) short Am[64][AP];
    __shared__ __align__(16) short Wt[O][40];
    __shared__ float sc1[O], sh1[O];
    __shared__ float red[4 * O], redq[4 * O];
    const int tid = threadIdx.x;
    const int lane = tid & 63, wave = tid >> 6;
    const int l15 = lane & 15, quad = lane >> 4;
    const int e0 = blockIdx.x * 64;

    if (tid < O) {
        float mean = st1[tid] * inv_n;
        float var = fmaxf(st1[O + tid] * inv_n - mean * mean, 0.f);
        float s = rsqrtf(var + 1e-5f) * gm1[tid];
        sc1[tid] = s; sh1[tid] = bt1[tid] - mean * s;
    }
    __syncthreads();

    // load h rows, bn1+relu, -> Am
    for (int g = tid; g < 8 * O; g += 256) {
        int row = g >> (OSH - 3);
        int c8 = (g & (O / 8 - 1)) * 8;
        v8s hv = *(const v8s*)&h[(size_t)(e0 + row) * O + c8];
        v8s ov;
#pragma unroll
        for (int j = 0; j < 8; ++j) {
            float v = bs2f(hv[j]) * sc1[c8 + j] + sh1[c8 + j];
            ov[j] = f2bs(fmaxf(v, 0.f));
        }
        *(v8s*)&Am[row][c8] = ov;
    }

    v4f acc[NCT];
#pragma unroll
    for (int ct = 0; ct < NCT; ++ct)
#pragma unroll
        for (int r = 0; r < 4; ++r) acc[ct][r] = 0.f;
    const int swc = tid >> 2;
    const int skk = (tid & 3) * 8;
    for (int k0 = 0; k0 < O; k0 += 32) {
        __syncthreads();
#pragma unroll
        for (int c0 = 0; c0 < O; c0 += 64) {
            int c = c0 + swc;
            *(v8s*)&Wt[c][skk] = *(const v8s*)&W2[(size_t)c * O + k0 + skk];
        }
        __syncthreads();
        v8s av = *(const v8s*)&Am[wave * 16 + l15][k0 + quad * 8];
#pragma unroll
        for (int ct = 0; ct < NCT; ++ct) {
            v8s bv = *(const v8s*)&Wt[ct * 16 + l15][quad * 8];
            acc[ct] = __builtin_amdgcn_mfma_f32_16x16x32_bf16(av, bv, acc[ct], 0, 0, 0);
        }
    }
#pragma unroll
    for (int ct = 0; ct < NCT; ++ct) {
        float bb = bias2[ct * 16 + l15];
#pragma unroll
        for (int r = 0; r < 4; ++r) acc[ct][r] += bb;
    }
#pragma unroll
    for (int ct = 0; ct < NCT; ++ct) {
        int c = ct * 16 + l15;
        float s = 0.f, q = 0.f;
#pragma unroll
        for (int r = 0; r < 4; ++r) { float v = acc[ct][r]; s += v; q += v * v; }
        s += __shfl_down(s, 32); s += __shfl_down(s, 16);
        q += __shfl_down(q, 32); q += __shfl_down(q, 16);
        if (quad == 0) { red[wave * O + c] = s; redq[wave * O + c] = q; }
    }
    __syncthreads();
    if (tid < O) {
        float s = red[tid] + red[O + tid] + red[2 * O + tid] + red[3 * O + tid];
        float q = redq[tid] + redq[O + tid] + redq[2 * O + tid] + redq[3 * O + tid];
        atomicAdd(&st2[tid], s); atomicAdd(&st2[O + tid], q);
    }
#pragma unroll
    for (int ct = 0; ct < NCT; ++ct) {
        int c = ct * 16 + l15;
#pragma unroll
        for (int r = 0; r < 4; ++r) Am[wave * 16 + quad * 4 + r][c] = f2bs(acc[ct][r]);
    }
    __syncthreads();
    for (int g = tid; g < 8 * O; g += 256) {
        int row = g >> (OSH - 3);
        int c8 = (g & (O / 8 - 1)) * 8;
        *(v8s*)&h[(size_t)(e0 + row) * O + c8] = *(const v8s*)&Am[row][c8];
    }
}

// ---------------- finish: stream h2, bn2+relu, k-mean, skip-concat ----------------
template<int O>
__global__ __launch_bounds__(256) void finish_kernel(
    const short* __restrict__ h,
    const float* __restrict__ st2, const float* __restrict__ gm2, const float* __restrict__ bt2,
    const float* __restrict__ xold, float* __restrict__ xnew, int F, float inv_n)
{
    constexpr int G = 256 / O;            // row groups per block (1/2/4)
    constexpr int RPG = 64 / G;           // rows per group (64/32/16)
    constexpr int NPG = RPG / 16;         // nodes per group (4/2/1)
    const int tid = threadIdx.x;
    const int c = tid & (O - 1);
    const int rg = tid / O;
    const int e0 = blockIdx.x * 64;
    const int nb0 = e0 >> 4;
    float mean = st2[c] * inv_n;
    float var = fmaxf(st2[O + c] * inv_n - mean * mean, 0.f);
    float sc = rsqrtf(var + 1e-5f) * gm2[c];
    float sh = bt2[c] - mean * sc;
    float s[NPG];
#pragma unroll
    for (int i = 0; i < NPG; ++i) s[i] = 0.f;
    const int m0 = rg * RPG;
#pragma unroll
    for (int r = 0; r < RPG; ++r) {
        float v = bs2f(h[(size_t)(e0 + m0 + r) * O + c]) * sc + sh;
        s[r >> 4] += fmaxf(v, 0.f);
    }
    const int Cnew = O + F;
#pragma unroll
    for (int i = 0; i < NPG; ++i)
        xnew[(size_t)(nb0 + rg * NPG + i) * Cnew + c] = s[i] * (1.0f / 16.0f);
    for (int l = tid; l < 4 * F; l += 256) {
        int nd = l / F, cc = l - nd * F;
        xnew[(size_t)(nb0 + nd) * Cnew + O + cc] = xold[(size_t)(nb0 + nd) * F + cc];
    }
}

// ---------------- fallback: fused recompute stages (bf16 weights, single pass) -------
template<int O, int STAGE>
__global__ __launch_bounds__(256) void conv_stage_kernel(
    const float* __restrict__ T1, const float* __restrict__ T2, const int* __restrict__ idx,
    const short* __restrict__ W1, const float* __restrict__ bias1,
    const short* __restrict__ W2, const float* __restrict__ bias2,
    const float* __restrict__ gm0, const float* __restrict__ bt0,
    const float* __restrict__ gm1, const float* __restrict__ bt1,
    const float* __restrict__ gm2, const float* __restrict__ bt2,
    const float* __restrict__ st0, float* __restrict__ st1, float* __restrict__ st2,
    const float* __restrict__ xold, float* __restrict__ xnew, int F, float inv_n)
{
    constexpr int NCT = O / 16;
    constexpr int OSH = (O == 64) ? 6 : (O == 128 ? 7 : 8);
    constexpr int AP = O + 8;
    __shared__ __align__(16) short Am[64][AP];
    __shared__ __align__(16) short Wt[O][40];
    __shared__ float sc0[O], sh0[O], sc1[O], sh1[O], sc2[O], sh2[O];
    __shared__ float red[4 * O], redq[4 * O];
    __shared__ int gArr[64];
    const int tid = threadIdx.x;
    const int lane = tid & 63, wave = tid >> 6;
    const int l15 = lane & 15, quad = lane >> 4;
    const int e0 = blockIdx.x * 64;
    const int nb0 = e0 >> 4;

    if (tid < O) {
        {
            float mean = st0[tid] * inv_n;
            float var = fmaxf(st0[O + tid] * inv_n - mean * mean, 0.f);
            float s = rsqrtf(var + 1e-5f) * gm0[tid];
            sc0[tid] = s; sh0[tid] = bt0[tid] - mean * s;
        }
        if (STAGE >= 2) {
            float mean = st1[tid] * inv_n;
            float var = fmaxf(st1[O + tid] * inv_n - mean * mean, 0.f);
            float s = rsqrtf(var + 1e-5f) * gm1[tid];
            sc1[tid] = s; sh1[tid] = bt1[tid] - mean * s;
        }
        if (STAGE == 3) {
            float mean = st2[tid] * inv_n;
            float var = fmaxf(st2[O + tid] * inv_n - mean * mean, 0.f);
            float s = rsqrtf(var + 1e-5f) * gm2[tid];
            sc2[tid] = s; sh2[tid] = bt2[tid] - mean * s;
        }
    }
    if (tid < 64) {
        int e = e0 + tid;
        int nd = e >> 4;
        gArr[tid] = ((nd >> 7) << 7) + idx[e];
    }
    __syncthreads();

    for (int l = tid; l < 32 * O; l += 256) {
        int m = l >> (OSH - 1);
        int c = (l & (O / 2 - 1)) * 2;
        const float2 t1 = *(const float2*)&T1[(size_t)(nb0 + (m >> 4)) * O + c];
        const float2 t2 = *(const float2*)&T2[(size_t)gArr[m] * O + c];
        float v0 = fmaxf((t1.x + t2.x) * sc0[c] + sh0[c], 0.f);
        float v1 = fmaxf((t1.y + t2.y) * sc0[c + 1] + sh0[c + 1], 0.f);
        v2s pr; pr[0] = f2bs(v0); pr[1] = f2bs(v1);
        *(v2s*)&Am[m][c] = pr;
    }

    v4f acc[NCT];
    const int swc = tid >> 2;
    const int skk = (tid & 3) * 8;
    auto do_gemm = [&](const short* __restrict__ Wg) {
#pragma unroll
        for (int ct = 0; ct < NCT; ++ct)
#pragma unroll
            for (int r = 0; r < 4; ++r) acc[ct][r] = 0.f;
        for (int k0 = 0; k0 < O; k0 += 32) {
            __syncthreads();
#pragma unroll
            for (int c0 = 0; c0 < O; c0 += 64) {
                int c = c0 + swc;
                *(v8s*)&Wt[c][skk] = *(const v8s*)&Wg[(size_t)c * O + k0 + skk];
            }
            __syncthreads();
            v8s av = *(const v8s*)&Am[wave * 16 + l15][k0 + quad * 8];
#pragma unroll
            for (int ct = 0; ct < NCT; ++ct) {
                v8s bv = *(const v8s*)&Wt[ct * 16 + l15][quad * 8];
                acc[ct] = __builtin_amdgcn_mfma_f32_16x16x32_bf16(av, bv, acc[ct], 0, 0, 0);
            }
        }
    };

    do_gemm(W1);
#pragma unroll
    for (int ct = 0; ct < NCT; ++ct) {
        float bb = bias1[ct * 16 + l15];
#pragma unroll
        for (int r = 0; r < 4; ++r) acc[ct][r] += bb;
    }

    if (STAGE == 1) {
#pragma unroll
        for (int ct = 0; ct < NCT; ++ct) {
            int c = ct * 16 + l15;
            float s = 0.f, q = 0.f;
#pragma unroll
            for (int r = 0; r < 4; ++r) { float v = acc[ct][r]; s += v; q += v * v; }
            s += __shfl_down(s, 32); s += __shfl_down(s, 16);
            q += __shfl_down(q, 32); q += __shfl_down(q, 16);
            if (quad == 0) { red[wave * O + c] = s; redq[wave * O + c] = q; }
        }
        __syncthreads();
        if (tid < O) {
            float s = red[tid] + red[O + tid] + red[2 * O + tid] + red[3 * O + tid];
            float q = redq[tid] + redq[O + tid] + redq[2 * O + tid] + redq[3 * O + tid];
            atomicAdd(&st1[tid], s); atomicAdd(&st1[O + tid], q);
        }
        return;
    }

#pragma unroll
    for (int ct = 0; ct < NCT; ++ct) {
        int c = ct * 16 + l15;
        float sc = sc1[c], sh = sh1[c];
#pragma unroll
        for (int r = 0; r < 4; ++r) {
            float v = fmaxf(acc[ct][r] * sc + sh, 0.f);
            Am[wave * 16 + quad * 4 + r][c] = f2bs(v);
        }
    }

    do_gemm(W2);
#pragma unroll
    for (int ct = 0; ct < NCT; ++ct) {
        float bb = bias2[ct * 16 + l15];
#pragma unroll
        for (int r = 0; r < 4; ++r) acc[ct][r] += bb;
    }

    if (STAGE == 2) {
#pragma unroll
        for (int ct = 0; ct < NCT; ++ct) {
            int c = ct * 16 + l15;
            float s = 0.f, q = 0.f;
#pragma unroll
            for (int r = 0; r < 4; ++r) { float v = acc[ct][r]; s += v; q += v * v; }
            s += __shfl_down(s, 32); s += __shfl_down(s, 16);
            q += __shfl_down(q, 32); q += __shfl_down(q, 16);
            if (quad == 0) { red[wave * O + c] = s; redq[wave * O + c] = q; }
        }
        __syncthreads();
        if (tid < O) {
            float s = red[tid] + red[O + tid] + red[2 * O + tid] + red[3 * O + tid];
            float q = redq[tid] + redq[O + tid] + redq[2 * O + tid] + redq[3 * O + tid];
            atomicAdd(&st2[tid], s); atomicAdd(&st2[O + tid], q);
        }
        return;
    }

    const int Cnew = O + F;
#pragma unroll
    for (int ct = 0; ct < NCT; ++ct) {
        int c = ct * 16 + l15;
        float sc = sc2[c], sh = sh2[c];
        float s = 0.f;
#pragma unroll
        for (int r = 0; r < 4; ++r) s += fmaxf(acc[ct][r] * sc + sh, 0.f);
        s += __shfl_down(s, 32); s += __shfl_down(s, 16);
        if (quad == 0) xnew[(size_t)(nb0 + wave) * Cnew + c] = s * (1.0f / 16.0f);
    }
    for (int l = tid; l < 4 * F; l += 256) {
        int nd = l / F, c = l - nd * F;
        xnew[(size_t)(nb0 + nd) * Cnew + O + c] = xold[(size_t)(nb0 + nd) * F + c];
    }
}

// ---------------- global mean pool ----------------
__global__ __launch_bounds__(256) void pool_kernel(const float* __restrict__ x, float* __restrict__ pooled, int C) {
    int b = blockIdx.x, t = threadIdx.x;
    for (int c = t; c < C; c += 256) {
        float s = 0.f;
        for (int n = 0; n < NN; ++n) s += x[(size_t)(b * NN + n) * C + c];
        pooled[b * C + c] = s * (1.0f / NN);
    }
}

// ---------------- fc1 + fc2 ----------------
__global__ __launch_bounds__(256) void fc_kernel(const float* __restrict__ pooled,
                                                 const float* __restrict__ W1, const float* __restrict__ b1,
                                                 const float* __restrict__ W2, const float* __restrict__ b2,
                                                 float* __restrict__ out, int C) {
    __shared__ float px[451];
    __shared__ float h1[256];
    int b = blockIdx.x, t = threadIdx.x;
    for (int c = t; c < C; c += 256) px[c] = pooled[b * C + c];
    __syncthreads();
    float s = 0.f;
    for (int i = 0; i < C; ++i) s += px[i] * W1[(size_t)i * 256 + t];
    h1[t] = s + b1[t];
    __syncthreads();
    if (t < 5) {
        float s2 = 0.f;
        for (int j = 0; j < 256; ++j) s2 += h1[j] * W2[j * 5 + t];
        out[b * 5 + t] = s2 + b2[t];
    }
}

extern "C" void kernel_launch(void* const* d_in, const int* in_sizes, int n_in,
                              void* d_out, int out_size, void* d_ws, size_t ws_size,
                              hipStream_t stream) {
    const float* xin = (const float*)d_in[0];
    auto Wp = [&](int c, int l) { return (const float*)d_in[1 + c * 12 + l * 4 + 0]; };
    auto Bp = [&](int c, int l) { return (const float*)d_in[1 + c * 12 + l * 4 + 1]; };
    auto Gp = [&](int c, int l) { return (const float*)d_in[1 + c * 12 + l * 4 + 2]; };
    auto Ep = [&](int c, int l) { return (const float*)d_in[1 + c * 12 + l * 4 + 3]; };
    const float* fcW1 = (const float*)d_in[37];
    const float* fcb1 = (const float*)d_in[38];
    const float* fcW2 = (const float*)d_in[39];
    const float* fcb2 = (const float*)d_in[40];

    char* ws = (char*)d_ws;
    size_t off = 0;
    auto alloc = [&](size_t bytes) -> void* {
        void* p = ws + off;
        off += (bytes + 255) & ~(size_t)255;
        return p;
    };
    const int M = M_NODES;
    float* x1     = (float*)alloc((size_t)M * 67 * 4);
    float* x2     = (float*)alloc((size_t)M * 195 * 4);
    float* x3     = (float*)alloc((size_t)M * 451 * 4);
    float* T1     = (float*)alloc((size_t)M * 256 * 4);
    float* T2     = (float*)alloc((size_t)M * 256 * 4);
    int*   idxb   = (int*)alloc((size_t)M * KNN * 4);
    float* stats  = (float*)alloc(1536 * 4);
    float* pooled = (float*)alloc((size_t)NB * 451 * 4);
    short* W1b    = (short*)alloc(256 * 256 * 2);
    short* W2b    = (short*)alloc(256 * 256 * 2);
    float* d2buf  = (float*)alloc((size_t)M * NN * 4);
    float* sqbuf  = (float*)alloc((size_t)M * 4);
    size_t base_off = off;                                 // ~92 MiB
    short* hbuf   = (short*)alloc((size_t)NPOS * 256 * 2); // +134 MiB
    const bool big = (off <= ws_size);                     // materialize-h path available?
    (void)in_sizes; (void)n_in; (void)out_size; (void)base_off;

    float* st0 = stats, *st1 = stats + 512, *st2 = stats + 1024;
    const float inv_n = 1.0f / (float)NPOS;

    auto run_conv = [&](const float* xc, float* xn, int F, int D, int O, int c) {
        sq_kernel<<<M / 256, 256, 0, stream>>>(xc, F, D, sqbuf);
        dist_kernel<<<dim3(2, M / 64), 256, 0, stream>>>(xc, F, D, sqbuf, d2buf);
        knn_select_kernel<<<M / 4, 256, 0, stream>>>(d2buf, idxb);
        node_gemm_kernel<<<dim3(O / 64, M / 64), 256, 0, stream>>>(xc, F, O, Wp(c, 0), Bp(c, 0), T1, T2);
        wconv_kernel<<<O * O / 256, 256, 0, stream>>>(Wp(c, 1), W1b, O);
        wconv_kernel<<<O * O / 256, 256, 0, stream>>>(Wp(c, 2), W2b, O);
        zero_kernel<<<6, 256, 0, stream>>>(stats, 1536);
        const int grid = (int)(NPOS / 64);
        auto launch = [&](auto tag) {
            constexpr int OO = decltype(tag)::value;
            stats0_kernel<OO><<<(OO == 256 ? 1024 : 512), 256, 0, stream>>>(T1, T2, idxb, st0);
            if (big) {
                gemm1_kernel<OO><<<grid, 256, 0, stream>>>(T1, T2, idxb, W1b, Bp(c, 1),
                    Gp(c, 0), Ep(c, 0), st0, st1, hbuf, inv_n);
                gemm2_kernel<OO><<<grid, 256, 0, stream>>>(hbuf, W2b, Bp(c, 2),
                    Gp(c, 1), Ep(c, 1), st1, st2, inv_n);
                finish_kernel<OO><<<grid, 256, 0, stream>>>(hbuf, st2, Gp(c, 2), Ep(c, 2),
                    xc, xn, F, inv_n);
            } else {
                conv_stage_kernel<OO, 1><<<grid, 256, 0, stream>>>(T1, T2, idxb,
                    W1b, Bp(c, 1), W2b, Bp(c, 2), Gp(c, 0), Ep(c, 0), Gp(c, 1), Ep(c, 1),
                    Gp(c, 2), Ep(c, 2), st0, st1, st2, xc, xn, F, inv_n);
                conv_stage_kernel<OO, 2><<<grid, 256, 0, stream>>>(T1, T2, idxb,
                    W1b, Bp(c, 1), W2b, Bp(c, 2), Gp(c, 0), Ep(c, 0), Gp(c, 1), Ep(c, 1),
                    Gp(c, 2), Ep(c, 2), st0, st1, st2, xc, xn, F, inv_n);
                conv_stage_kernel<OO, 3><<<grid, 256, 0, stream>>>(T1, T2, idxb,
                    W1b, Bp(c, 1), W2b, Bp(c, 2), Gp(c, 0), Ep(c, 0), Gp(c, 1), Ep(c, 1),
                    Gp(c, 2), Ep(c, 2), st0, st1, st2, xc, xn, F, inv_n);
            }
        };
        if (O == 64)       launch(std::integral_constant<int, 64>{});
        else if (O == 128) launch(std::integral_constant<int, 128>{});
        else               launch(std::integral_constant<int, 256>{});
    };

    run_conv(xin, x1, 3, 2, 64, 0);     // -> x1: C=67
    run_conv(x1, x2, 67, 67, 128, 1);   // -> x2: C=195
    run_conv(x2, x3, 195, 195, 256, 2); // -> x3: C=451
    pool_kernel<<<NB, 256, 0, stream>>>(x3, pooled, 451);
    fc_kernel<<<NB, 256, 0, stream>>>(pooled, fcW1, fcb1, fcW2, fcb2, (float*)d_out, 451);
}

// Round 10
// 1709.830 us; speedup vs baseline: 4.8933x; 1.0188x over previous
//
#include <hip/hip_runtime.h>
#include <hip/hip_bf16.h>
#include <type_traits>

typedef __hip_bfloat16 bf16;
typedef short v8s __attribute__((ext_vector_type(8)));
typedef short v2s __attribute__((ext_vector_type(2)));
typedef float v4f __attribute__((ext_vector_type(4)));

__device__ __forceinline__ float b2f(bf16 v) { return __bfloat162float(v); }
__device__ __forceinline__ bf16  f2b(float v) { return __float2bfloat16(v); }
__device__ __forceinline__ short f2bs(float v) {
    bf16 b = f2b(v); short s; __builtin_memcpy(&s, &b, 2); return s;
}
__device__ __forceinline__ float bs2f(short s) {
    bf16 b; __builtin_memcpy(&b, &s, 2); return b2f(b);
}

#define NB 128
#define NN 128
#define KNN 16
#define M_NODES (NB * NN)          // 16384
#define NPOS ((long)M_NODES * KNN) // 262144 edge rows

// ---------------- zero a small float buffer ----------------
__global__ void zero_kernel(float* __restrict__ p, int n) {
    int i = blockIdx.x * blockDim.x + threadIdx.x;
    if (i < n) p[i] = 0.f;
}

// ---------------- weight precompute: transposed bf16 ----------------
__global__ __launch_bounds__(256) void wconv_kernel(const float* __restrict__ W,
        short* __restrict__ Wt, int O) {
    int d = blockIdx.x * 256 + threadIdx.x;      // d = c*O + k
    int c = d / O, k = d - c * O;
    Wt[d] = f2bs(W[(size_t)k * O + c]);
}

// ---------------- kNN part 1: per-node squared norm ----------------
__global__ __launch_bounds__(256) void sq_kernel(const float* __restrict__ x, int C, int D,
                                                 float* __restrict__ sq) {
    int n = blockIdx.x * 256 + threadIdx.x;
    if (n >= M_NODES) return;
    float s = 0.f;
    for (int d = 0; d < D; ++d) { float v = x[(size_t)n * C + d]; s += v * v; }
    sq[n] = s;
}

// ---------------- kNN part 2: d2 tile GEMM ----------------
__global__ __launch_bounds__(256) void dist_kernel(const float* __restrict__ x, int C, int D,
                                                   const float* __restrict__ sq,
                                                   float* __restrict__ d2) {
    __shared__ float As[16][65];
    __shared__ float Bs[16][65];
    const int tid = threadIdx.x;
    const int tx = tid & 15, ty = tid >> 4;
    const int m0 = blockIdx.y * 64;
    const int b  = m0 >> 7;
    const int c0 = blockIdx.x * 64;
    float acc[4][4];
#pragma unroll
    for (int r = 0; r < 4; ++r)
#pragma unroll
        for (int c = 0; c < 4; ++c) acc[r][c] = 0.f;
    for (int k0 = 0; k0 < D; k0 += 16) {
        for (int l = tid; l < 1024; l += 256) {
            int k = l & 15, m = l >> 4;
            int kk = k0 + k;
            As[k][m] = (kk < D) ? x[(size_t)(m0 + m) * C + kk] : 0.f;
            Bs[k][m] = (kk < D) ? x[(size_t)(b * NN + c0 + m) * C + kk] : 0.f;
        }
        __syncthreads();
        for (int k = 0; k < 16; ++k) {
            float av[4], bv[4];
#pragma unroll
            for (int r = 0; r < 4; ++r) av[r] = As[k][ty + 16 * r];
#pragma unroll
            for (int c = 0; c < 4; ++c) bv[c] = Bs[k][tx + 16 * c];
#pragma unroll
            for (int r = 0; r < 4; ++r)
#pragma unroll
                for (int c = 0; c < 4; ++c) acc[r][c] += av[r] * bv[c];
        }
        __syncthreads();
    }
#pragma unroll
    for (int r = 0; r < 4; ++r)
#pragma unroll
        for (int c = 0; c < 4; ++c) {
            int m = m0 + ty + 16 * r;
            int jl = c0 + tx + 16 * c;
            int jg = b * NN + jl;
            float v = sq[m] + sq[jg] - 2.0f * acc[r][c];
            if (m == jg) v += 1e9f;
            d2[(size_t)m * NN + jl] = v;
        }
}

// ---------------- kNN part 3: wave-per-node top-16 ----------------
__global__ __launch_bounds__(256) void knn_select_kernel(const float* __restrict__ d2,
                                                         int* __restrict__ idx) {
    const int node = blockIdx.x * 4 + (threadIdx.x >> 6);
    const int lane = threadIdx.x & 63;
    const float* row = d2 + (size_t)node * NN;
    float v0 = row[lane], v1 = row[lane + 64];
    int j0 = lane, j1 = lane + 64;
    int myIdx = 0;
#pragma unroll
    for (int k = 0; k < KNN; ++k) {
        float bv; int bj;
        if (v1 < v0 || (v1 == v0 && j1 < j0)) { bv = v1; bj = j1; }
        else                                 { bv = v0; bj = j0; }
#pragma unroll
        for (int off = 32; off; off >>= 1) {
            float ov = __shfl_xor(bv, off);
            int oj = __shfl_xor(bj, off);
            if (ov < bv || (ov == bv && oj < bj)) { bv = ov; bj = oj; }
        }
        if (bj == j0) v0 = 3.0e38f;
        if (bj == j1) v1 = 3.0e38f;
        if (lane == k) myIdx = bj;
    }
    if (lane < KNN) idx[(size_t)node * KNN + lane] = myIdx;
}

// ---------------- node GEMM: T1 = x@(Wt-Wb)+bias, T2 = x@Wb (f32) ----------------
__global__ __launch_bounds__(256) void node_gemm_kernel(const float* __restrict__ x, int F, int O,
                                                        const float* __restrict__ W, const float* __restrict__ bias,
                                                        float* __restrict__ T1, float* __restrict__ T2) {
    __shared__ float As[16][65];
    __shared__ float Bt[16][65];
    __shared__ float Bb[16][65];
    const int tid = threadIdx.x;
    const int tx = tid & 15, ty = tid >> 4;
    const int m0 = blockIdx.y * 64, c0 = blockIdx.x * 64;
    float aT[4][4], aB[4][4];
#pragma unroll
    for (int r = 0; r < 4; ++r)
#pragma unroll
        for (int c = 0; c < 4; ++c) { aT[r][c] = 0.f; aB[r][c] = 0.f; }
    for (int k0 = 0; k0 < F; k0 += 16) {
        for (int l = tid; l < 1024; l += 256) {
            int k = l & 15, m = l >> 4;
            int kk = k0 + k;
            As[k][m] = (kk < F) ? x[(size_t)(m0 + m) * F + kk] : 0.f;
        }
        for (int l = tid; l < 1024; l += 256) {
            int c = l & 63, k = l >> 6;
            int kk = k0 + k;
            Bt[k][c] = (kk < F) ? W[(size_t)kk * O + c0 + c] : 0.f;
            Bb[k][c] = (kk < F) ? W[(size_t)(F + kk) * O + c0 + c] : 0.f;
        }
        __syncthreads();
        for (int k = 0; k < 16; ++k) {
            float av[4], bt[4], bb[4];
#pragma unroll
            for (int r = 0; r < 4; ++r) av[r] = As[k][ty + 16 * r];
#pragma unroll
            for (int c = 0; c < 4; ++c) { bt[c] = Bt[k][tx + 16 * c]; bb[c] = Bb[k][tx + 16 * c]; }
#pragma unroll
            for (int r = 0; r < 4; ++r)
#pragma unroll
                for (int c = 0; c < 4; ++c) { aT[r][c] += av[r] * bt[c]; aB[r][c] += av[r] * bb[c]; }
        }
        __syncthreads();
    }
    float bc[4];
#pragma unroll
    for (int c = 0; c < 4; ++c) bc[c] = bias[c0 + tx + 16 * c];
#pragma unroll
    for (int r = 0; r < 4; ++r)
#pragma unroll
        for (int c = 0; c < 4; ++c) {
            size_t m = m0 + ty + 16 * r, cc = c0 + tx + 16 * c;
            T1[m * O + cc] = aT[r][c] - aB[r][c] + bc[c];
            T2[m * O + cc] = aB[r][c];
        }
}

// ---------------- stats of h0 = T1[n] + T2[nbr] (not materialized) ------
template<int O>
__global__ __launch_bounds__(256) void stats0_kernel(const float* __restrict__ T1,
        const float* __restrict__ T2, const int* __restrict__ idx, float* __restrict__ st0) {
    constexpr int OSH = (O == 64) ? 6 : (O == 128 ? 7 : 8);
    __shared__ float ls[256], lss[256];
    const int t = threadIdx.x;
    const long n = NPOS * O;
    float s = 0.f, ss = 0.f;
    for (long i = (long)blockIdx.x * 256 + t; i < n; i += (long)gridDim.x * 256) {
        int c = (int)(i & (O - 1));
        long e = i >> OSH;
        int nd = (int)(e >> 4);
        int j = idx[e];
        int g = ((nd >> 7) << 7) + j;
        float v = T1[(size_t)nd * O + c] + T2[(size_t)g * O + c];
        s += v; ss += v * v;
    }
    ls[t] = s; lss[t] = ss;
    __syncthreads();
    for (int off = 128; off >= O; off >>= 1) {
        if (t < off) { ls[t] += ls[t + off]; lss[t] += lss[t + off]; }
        __syncthreads();
    }
    if (t < O) { atomicAdd(&st0[t], ls[t]); atomicAdd(&st0[O + t], lss[t]); }
}

// ========================= column-owned MFMA GEMM kernels ==========================
// Block = 64 edge rows x O cols; wave w owns cols [w*O/4, (w+1)*O/4) for ALL 64 rows.
// B fragments load directly from transposed bf16 W in global (L2-resident) -> no
// B-staging LDS, no barriers inside the K-loop.

// ---------------- gemm1: A0-build -> h1 = A0@W1 + b1 -> h + st1 ----------------
template<int O>
__global__ __launch_bounds__(256, 4) void gemm1_kernel(
    const float* __restrict__ T1, const float* __restrict__ T2, const int* __restrict__ idx,
    const short* __restrict__ W1, const float* __restrict__ bias1,
    const float* __restrict__ gm0, const float* __restrict__ bt0,
    const float* __restrict__ st0, float* __restrict__ st1,
    short* __restrict__ h, float inv_n)
{
    constexpr int CPW = O / 64;            // col-tiles per wave (1/2/4)
    constexpr int OSH = (O == 64) ? 6 : (O == 128 ? 7 : 8);
    constexpr int AP = O + 8;
    __shared__ __align__(16) short Am[64][AP];
    __shared__ float sc0[O], sh0[O];
    __shared__ int gArr[64];
    const int tid = threadIdx.x;
    const int lane = tid & 63, wave = tid >> 6;
    const int l15 = lane & 15, quad = lane >> 4;
    const int e0 = blockIdx.x * 64;
    const int nb0 = e0 >> 4;

    if (tid < O) {
        float mean = st0[tid] * inv_n;
        float var = fmaxf(st0[O + tid] * inv_n - mean * mean, 0.f);
        float s = rsqrtf(var + 1e-5f) * gm0[tid];
        sc0[tid] = s; sh0[tid] = bt0[tid] - mean * s;
    }
    if (tid < 64) {
        int e = e0 + tid;
        int nd = e >> 4;
        gArr[tid] = ((nd >> 7) << 7) + idx[e];
    }
    __syncthreads();

    // A0 build
    for (int l = tid; l < 32 * O; l += 256) {
        int m = l >> (OSH - 1);
        int c = (l & (O / 2 - 1)) * 2;
        const float2 t1 = *(const float2*)&T1[(size_t)(nb0 + (m >> 4)) * O + c];
        const float2 t2 = *(const float2*)&T2[(size_t)gArr[m] * O + c];
        float v0 = fmaxf((t1.x + t2.x) * sc0[c] + sh0[c], 0.f);
        float v1 = fmaxf((t1.y + t2.y) * sc0[c + 1] + sh0[c + 1], 0.f);
        v2s pr; pr[0] = f2bs(v0); pr[1] = f2bs(v1);
        *(v2s*)&Am[m][c] = pr;
    }
    __syncthreads();

    v4f acc[4][CPW];
#pragma unroll
    for (int rt = 0; rt < 4; ++rt)
#pragma unroll
        for (int j = 0; j < CPW; ++j)
#pragma unroll
            for (int r = 0; r < 4; ++r) acc[rt][j][r] = 0.f;

    for (int k0 = 0; k0 < O; k0 += 32) {
        v8s av[4];
#pragma unroll
        for (int rt = 0; rt < 4; ++rt)
            av[rt] = *(const v8s*)&Am[rt * 16 + l15][k0 + quad * 8];
#pragma unroll
        for (int j = 0; j < CPW; ++j) {
            int c = (wave * CPW + j) * 16 + l15;
            v8s bv = *(const v8s*)&W1[(size_t)c * O + k0 + quad * 8];
#pragma unroll
            for (int rt = 0; rt < 4; ++rt)
                acc[rt][j] = __builtin_amdgcn_mfma_f32_16x16x32_bf16(av[rt], bv, acc[rt][j], 0, 0, 0);
        }
    }
#pragma unroll
    for (int j = 0; j < CPW; ++j) {
        float bb = bias1[(wave * CPW + j) * 16 + l15];
#pragma unroll
        for (int rt = 0; rt < 4; ++rt)
#pragma unroll
            for (int r = 0; r < 4; ++r) acc[rt][j][r] += bb;
    }
    // stats (column-owned -> in-wave reduce + direct atomics)
#pragma unroll
    for (int j = 0; j < CPW; ++j) {
        int c = (wave * CPW + j) * 16 + l15;
        float s = 0.f, q = 0.f;
#pragma unroll
        for (int rt = 0; rt < 4; ++rt)
#pragma unroll
            for (int r = 0; r < 4; ++r) { float v = acc[rt][j][r]; s += v; q += v * v; }
        s += __shfl_down(s, 32); s += __shfl_down(s, 16);
        q += __shfl_down(q, 32); q += __shfl_down(q, 16);
        if (quad == 0) { atomicAdd(&st1[c], s); atomicAdd(&st1[O + c], q); }
    }
    __syncthreads();   // all waves done reading Am
#pragma unroll
    for (int j = 0; j < CPW; ++j) {
        int c = (wave * CPW + j) * 16 + l15;
#pragma unroll
        for (int rt = 0; rt < 4; ++rt)
#pragma unroll
            for (int r = 0; r < 4; ++r)
                Am[rt * 16 + quad * 4 + r][c] = f2bs(acc[rt][j][r]);
    }
    __syncthreads();
    for (int g = tid; g < 8 * O; g += 256) {
        int row = g >> (OSH - 3);
        int c8 = (g & (O / 8 - 1)) * 8;
        *(v8s*)&h[(size_t)(e0 + row) * O + c8] = *(const v8s*)&Am[row][c8];
    }
}

// ---------------- gemm2: h -> bn1+relu -> h2 = A1@W2 + b2 -> h (in place) + st2 ------
template<int O>
__global__ __launch_bounds__(256, 4) void gemm2_kernel(
    short* __restrict__ h,
    const short* __restrict__ W2, const float* __restrict__ bias2,
    const float* __restrict__ gm1, const float* __restrict__ bt1,
    const float* __restrict__ st1, float* __restrict__ st2, float inv_n)
{
    constexpr int CPW = O / 64;
    constexpr int OSH = (O == 64) ? 6 : (O == 128 ? 7 : 8);
    constexpr int AP = O + 8;
    __shared__ __align__(16) short Am[64][AP];
    __shared__ float sc1[O], sh1[O];
    const int tid = threadIdx.x;
    const int lane = tid & 63, wave = tid >> 6;
    const int l15 = lane & 15, quad = lane >> 4;
    const int e0 = blockIdx.x * 64;

    if (tid < O) {
        float mean = st1[tid] * inv_n;
        float var = fmaxf(st1[O + tid] * inv_n - mean * mean, 0.f);
        float s = rsqrtf(var + 1e-5f) * gm1[tid];
        sc1[tid] = s; sh1[tid] = bt1[tid] - mean * s;
    }
    __syncthreads();

    for (int g = tid; g < 8 * O; g += 256) {
        int row = g >> (OSH - 3);
        int c8 = (g & (O / 8 - 1)) * 8;
        v8s hv = *(const v8s*)&h[(size_t)(e0 + row) * O + c8];
        v8s ov;
#pragma unroll
        for (int j = 0; j < 8; ++j) {
            float v = bs2f(hv[j]) * sc1[c8 + j] + sh1[c8 + j];
            ov[j] = f2bs(fmaxf(v, 0.f));
        }
        *(v8s*)&Am[row][c8] = ov;
    }
    __syncthreads();

    v4f acc[4][CPW];
#pragma unroll
    for (int rt = 0; rt < 4; ++rt)
#pragma unroll
        for (int j = 0; j < CPW; ++j)
#pragma unroll
            for (int r = 0; r < 4; ++r) acc[rt][j][r] = 0.f;

    for (int k0 = 0; k0 < O; k0 += 32) {
        v8s av[4];
#pragma unroll
        for (int rt = 0; rt < 4; ++rt)
            av[rt] = *(const v8s*)&Am[rt * 16 + l15][k0 + quad * 8];
#pragma unroll
        for (int j = 0; j < CPW; ++j) {
            int c = (wave * CPW + j) * 16 + l15;
            v8s bv = *(const v8s*)&W2[(size_t)c * O + k0 + quad * 8];
#pragma unroll
            for (int rt = 0; rt < 4; ++rt)
                acc[rt][j] = __builtin_amdgcn_mfma_f32_16x16x32_bf16(av[rt], bv, acc[rt][j], 0, 0, 0);
        }
    }
#pragma unroll
    for (int j = 0; j < CPW; ++j) {
        float bb = bias2[(wave * CPW + j) * 16 + l15];
#pragma unroll
        for (int rt = 0; rt < 4; ++rt)
#pragma unroll
            for (int r = 0; r < 4; ++r) acc[rt][j][r] += bb;
    }
#pragma unroll
    for (int j = 0; j < CPW; ++j) {
        int c = (wave * CPW + j) * 16 + l15;
        float s = 0.f, q = 0.f;
#pragma unroll
        for (int rt = 0; rt < 4; ++rt)
#pragma unroll
            for (int r = 0; r < 4; ++r) { float v = acc[rt][j][r]; s += v; q += v * v; }
        s += __shfl_down(s, 32); s += __shfl_down(s, 16);
        q += __shfl_down(q, 32); q += __shfl_down(q, 16);
        if (quad == 0) { atomicAdd(&st2[c], s); atomicAdd(&st2[O + c], q); }
    }
    __syncthreads();
#pragma unroll
    for (int j = 0; j < CPW; ++j) {
        int c = (wave * CPW + j) * 16 + l15;
#pragma unroll
        for (int rt = 0; rt < 4; ++rt)
#pragma unroll
            for (int r = 0; r < 4; ++r)
                Am[rt * 16 + quad * 4 + r][c] = f2bs(acc[rt][j][r]);
    }
    __syncthreads();
    for (int g = tid; g < 8 * O; g += 256) {
        int row = g >> (OSH - 3);
        int c8 = (g & (O / 8 - 1)) * 8;
        *(v8s*)&h[(size_t)(e0 + row) * O + c8] = *(const v8s*)&Am[row][c8];
    }
}

// ---------------- finish: stream h2, bn2+relu, k-mean, skip-concat ----------------
template<int O>
__global__ __launch_bounds__(256) void finish_kernel(
    const short* __restrict__ h,
    const float* __restrict__ st2, const float* __restrict__ gm2, const float* __restrict__ bt2,
    const float* __restrict__ xold, float* __restrict__ xnew, int F, float inv_n)
{
    constexpr int G = 256 / O;
    constexpr int RPG = 64 / G;
    constexpr int NPG = RPG / 16;
    const int tid = threadIdx.x;
    const int c = tid & (O - 1);
    const int rg = tid / O;
    const int e0 = blockIdx.x * 64;
    const int nb0 = e0 >> 4;
    float mean = st2[c] * inv_n;
    float var = fmaxf(st2[O + c] * inv_n - mean * mean, 0.f);
    float sc = rsqrtf(var + 1e-5f) * gm2[c];
    float sh = bt2[c] - mean * sc;
    float s[NPG];
#pragma unroll
    for (int i = 0; i < NPG; ++i) s[i] = 0.f;
    const int m0 = rg * RPG;
#pragma unroll
    for (int r = 0; r < RPG; ++r) {
        float v = bs2f(h[(size_t)(e0 + m0 + r) * O + c]) * sc + sh;
        s[r >> 4] += fmaxf(v, 0.f);
    }
    const int Cnew = O + F;
#pragma unroll
    for (int i = 0; i < NPG; ++i)
        xnew[(size_t)(nb0 + rg * NPG + i) * Cnew + c] = s[i] * (1.0f / 16.0f);
    for (int l = tid; l < 4 * F; l += 256) {
        int nd = l / F, cc = l - nd * F;
        xnew[(size_t)(nb0 + nd) * Cnew + O + cc] = xold[(size_t)(nb0 + nd) * F + cc];
    }
}

// ---------------- fallback: fused recompute stages (unused when ws fits h) ----------
template<int O, int STAGE>
__global__ __launch_bounds__(256) void conv_stage_kernel(
    const float* __restrict__ T1, const float* __restrict__ T2, const int* __restrict__ idx,
    const short* __restrict__ W1, const float* __restrict__ bias1,
    const short* __restrict__ W2, const float* __restrict__ bias2,
    const float* __restrict__ gm0, const float* __restrict__ bt0,
    const float* __restrict__ gm1, const float* __restrict__ bt1,
    const float* __restrict__ gm2, const float* __restrict__ bt2,
    const float* __restrict__ st0, float* __restrict__ st1, float* __restrict__ st2,
    const float* __restrict__ xold, float* __restrict__ xnew, int F, float inv_n)
{
    constexpr int CPW = O / 64;
    constexpr int OSH = (O == 64) ? 6 : (O == 128 ? 7 : 8);
    constexpr int AP = O + 8;
    __shared__ __align__(16) short Am[64][AP];
    __shared__ float sc0[O], sh0[O], sc1[O], sh1[O], sc2[O], sh2[O];
    __shared__ int gArr[64];
    const int tid = threadIdx.x;
    const int lane = tid & 63, wave = tid >> 6;
    const int l15 = lane & 15, quad = lane >> 4;
    const int e0 = blockIdx.x * 64;
    const int nb0 = e0 >> 4;

    if (tid < O) {
        {
            float mean = st0[tid] * inv_n;
            float var = fmaxf(st0[O + tid] * inv_n - mean * mean, 0.f);
            float s = rsqrtf(var + 1e-5f) * gm0[tid];
            sc0[tid] = s; sh0[tid] = bt0[tid] - mean * s;
        }
        if (STAGE >= 2) {
            float mean = st1[tid] * inv_n;
            float var = fmaxf(st1[O + tid] * inv_n - mean * mean, 0.f);
            float s = rsqrtf(var + 1e-5f) * gm1[tid];
            sc1[tid] = s; sh1[tid] = bt1[tid] - mean * s;
        }
        if (STAGE == 3) {
            float mean = st2[tid] * inv_n;
            float var = fmaxf(st2[O + tid] * inv_n - mean * mean, 0.f);
            float s = rsqrtf(var + 1e-5f) * gm2[tid];
            sc2[tid] = s; sh2[tid] = bt2[tid] - mean * s;
        }
    }
    if (tid < 64) {
        int e = e0 + tid;
        int nd = e >> 4;
        gArr[tid] = ((nd >> 7) << 7) + idx[e];
    }
    __syncthreads();

    for (int l = tid; l < 32 * O; l += 256) {
        int m = l >> (OSH - 1);
        int c = (l & (O / 2 - 1)) * 2;
        const float2 t1 = *(const float2*)&T1[(size_t)(nb0 + (m >> 4)) * O + c];
        const float2 t2 = *(const float2*)&T2[(size_t)gArr[m] * O + c];
        float v0 = fmaxf((t1.x + t2.x) * sc0[c] + sh0[c], 0.f);
        float v1 = fmaxf((t1.y + t2.y) * sc0[c + 1] + sh0[c + 1], 0.f);
        v2s pr; pr[0] = f2bs(v0); pr[1] = f2bs(v1);
        *(v2s*)&Am[m][c] = pr;
    }
    __syncthreads();

    v4f acc[4][CPW];
    auto do_gemm = [&](const short* __restrict__ Wg) {
#pragma unroll
        for (int rt = 0; rt < 4; ++rt)
#pragma unroll
            for (int j = 0; j < CPW; ++j)
#pragma unroll
                for (int r = 0; r < 4; ++r) acc[rt][j][r] = 0.f;
        for (int k0 = 0; k0 < O; k0 += 32) {
            v8s av[4];
#pragma unroll
            for (int rt = 0; rt < 4; ++rt)
                av[rt] = *(const v8s*)&Am[rt * 16 + l15][k0 + quad * 8];
#pragma unroll
            for (int j = 0; j < CPW; ++j) {
                int c = (wave * CPW + j) * 16 + l15;
                v8s bv = *(const v8s*)&Wg[(size_t)c * O + k0 + quad * 8];
#pragma unroll
                for (int rt = 0; rt < 4; ++rt)
                    acc[rt][j] = __builtin_amdgcn_mfma_f32_16x16x32_bf16(av[rt], bv, acc[rt][j], 0, 0, 0);
            }
        }
    };

    do_gemm(W1);
#pragma unroll
    for (int j = 0; j < CPW; ++j) {
        float bb = bias1[(wave * CPW + j) * 16 + l15];
#pragma unroll
        for (int rt = 0; rt < 4; ++rt)
#pragma unroll
            for (int r = 0; r < 4; ++r) acc[rt][j][r] += bb;
    }

    if (STAGE == 1) {
#pragma unroll
        for (int j = 0; j < CPW; ++j) {
            int c = (wave * CPW + j) * 16 + l15;
            float s = 0.f, q = 0.f;
#pragma unroll
            for (int rt = 0; rt < 4; ++rt)
#pragma unroll
                for (int r = 0; r < 4; ++r) { float v = acc[rt][j][r]; s += v; q += v * v; }
            s += __shfl_down(s, 32); s += __shfl_down(s, 16);
            q += __shfl_down(q, 32); q += __shfl_down(q, 16);
            if (quad == 0) { atomicAdd(&st1[c], s); atomicAdd(&st1[O + c], q); }
        }
        return;
    }

    __syncthreads();
#pragma unroll
    for (int j = 0; j < CPW; ++j) {
        int c = (wave * CPW + j) * 16 + l15;
        float sc = sc1[c], sh = sh1[c];
#pragma unroll
        for (int rt = 0; rt < 4; ++rt)
#pragma unroll
            for (int r = 0; r < 4; ++r) {
                float v = fmaxf(acc[rt][j][r] * sc + sh, 0.f);
                Am[rt * 16 + quad * 4 + r][c] = f2bs(v);
            }
    }
    __syncthreads();

    do_gemm(W2);
#pragma unroll
    for (int j = 0; j < CPW; ++j) {
        float bb = bias2[(wave * CPW + j) * 16 + l15];
#pragma unroll
        for (int rt = 0; rt < 4; ++rt)
#pragma unroll
            for (int r = 0; r < 4; ++r) acc[rt][j][r] += bb;
    }

    if (STAGE == 2) {
#pragma unroll
        for (int j = 0; j < CPW; ++j) {
            int c = (wave * CPW + j) * 16 + l15;
            float s = 0.f, q = 0.f;
#pragma unroll
            for (int rt = 0; rt < 4; ++rt)
#pragma unroll
                for (int r = 0; r < 4; ++r) { float v = acc[rt][j][r]; s += v; q += v * v; }
            s += __shfl_down(s, 32); s += __shfl_down(s, 16);
            q += __shfl_down(q, 32); q += __shfl_down(q, 16);
            if (quad == 0) { atomicAdd(&st2[c], s); atomicAdd(&st2[O + c], q); }
        }
        return;
    }

    // STAGE3: bn2+relu, per-node k-mean (rows of node nd live across quads/r)
    const int Cnew = O + F;
#pragma unroll
    for (int j = 0; j < CPW; ++j) {
        int c = (wave * CPW + j) * 16 + l15;
        float sc = sc2[c], sh = sh2[c];
        float s[4];
#pragma unroll
        for (int rt = 0; rt < 4; ++rt) {
            s[rt] = 0.f;
#pragma unroll
            for (int r = 0; r < 4; ++r) s[rt] += fmaxf(acc[rt][j][r] * sc + sh, 0.f);
            s[rt] += __shfl_down(s[rt], 32); s[rt] += __shfl_down(s[rt], 16);
            if (quad == 0) xnew[(size_t)(nb0 + rt) * Cnew + c] = s[rt] * (1.0f / 16.0f);
        }
    }
    for (int l = tid; l < 4 * F; l += 256) {
        int nd = l / F, c = l - nd * F;
        xnew[(size_t)(nb0 + nd) * Cnew + O + c] = xold[(size_t)(nb0 + nd) * F + c];
    }
}

// ---------------- global mean pool ----------------
__global__ __launch_bounds__(256) void pool_kernel(const float* __restrict__ x, float* __restrict__ pooled, int C) {
    int b = blockIdx.x, t = threadIdx.x;
    for (int c = t; c < C; c += 256) {
        float s = 0.f;
        for (int n = 0; n < NN; ++n) s += x[(size_t)(b * NN + n) * C + c];
        pooled[b * C + c] = s * (1.0f / NN);
    }
}

// ---------------- fc1 + fc2 ----------------
__global__ __launch_bounds__(256) void fc_kernel(const float* __restrict__ pooled,
                                                 const float* __restrict__ W1, const float* __restrict__ b1,
                                                 const float* __restrict__ W2, const float* __restrict__ b2,
                                                 float* __restrict__ out, int C) {
    __shared__ float px[451];
    __shared__ float h1[256];
    int b = blockIdx.x, t = threadIdx.x;
    for (int c = t; c < C; c += 256) px[c] = pooled[b * C + c];
    __syncthreads();
    float s = 0.f;
    for (int i = 0; i < C; ++i) s += px[i] * W1[(size_t)i * 256 + t];
    h1[t] = s + b1[t];
    __syncthreads();
    if (t < 5) {
        float s2 = 0.f;
        for (int j = 0; j < 256; ++j) s2 += h1[j] * W2[j * 5 + t];
        out[b * 5 + t] = s2 + b2[t];
    }
}

extern "C" void kernel_launch(void* const* d_in, const int* in_sizes, int n_in,
                              void* d_out, int out_size, void* d_ws, size_t ws_size,
                              hipStream_t stream) {
    const float* xin = (const float*)d_in[0];
    auto Wp = [&](int c, int l) { return (const float*)d_in[1 + c * 12 + l * 4 + 0]; };
    auto Bp = [&](int c, int l) { return (const float*)d_in[1 + c * 12 + l * 4 + 1]; };
    auto Gp = [&](int c, int l) { return (const float*)d_in[1 + c * 12 + l * 4 + 2]; };
    auto Ep = [&](int c, int l) { return (const float*)d_in[1 + c * 12 + l * 4 + 3]; };
    const float* fcW1 = (const float*)d_in[37];
    const float* fcb1 = (const float*)d_in[38];
    const float* fcW2 = (const float*)d_in[39];
    const float* fcb2 = (const float*)d_in[40];

    char* ws = (char*)d_ws;
    size_t off = 0;
    auto alloc = [&](size_t bytes) -> void* {
        void* p = ws + off;
        off += (bytes + 255) & ~(size_t)255;
        return p;
    };
    const int M = M_NODES;
    float* x1     = (float*)alloc((size_t)M * 67 * 4);
    float* x2     = (float*)alloc((size_t)M * 195 * 4);
    float* x3     = (float*)alloc((size_t)M * 451 * 4);
    float* T1     = (float*)alloc((size_t)M * 256 * 4);
    float* T2     = (float*)alloc((size_t)M * 256 * 4);
    int*   idxb   = (int*)alloc((size_t)M * KNN * 4);
    float* stats  = (float*)alloc(1536 * 4);
    float* pooled = (float*)alloc((size_t)NB * 451 * 4);
    short* W1b    = (short*)alloc(256 * 256 * 2);
    short* W2b    = (short*)alloc(256 * 256 * 2);
    float* d2buf  = (float*)alloc((size_t)M * NN * 4);
    float* sqbuf  = (float*)alloc((size_t)M * 4);
    short* hbuf   = (short*)alloc((size_t)NPOS * 256 * 2); // +134 MiB
    const bool big = (off <= ws_size);
    (void)in_sizes; (void)n_in; (void)out_size;

    float* st0 = stats, *st1 = stats + 512, *st2 = stats + 1024;
    const float inv_n = 1.0f / (float)NPOS;

    auto run_conv = [&](const float* xc, float* xn, int F, int D, int O, int c) {
        sq_kernel<<<M / 256, 256, 0, stream>>>(xc, F, D, sqbuf);
        dist_kernel<<<dim3(2, M / 64), 256, 0, stream>>>(xc, F, D, sqbuf, d2buf);
        knn_select_kernel<<<M / 4, 256, 0, stream>>>(d2buf, idxb);
        node_gemm_kernel<<<dim3(O / 64, M / 64), 256, 0, stream>>>(xc, F, O, Wp(c, 0), Bp(c, 0), T1, T2);
        wconv_kernel<<<O * O / 256, 256, 0, stream>>>(Wp(c, 1), W1b, O);
        wconv_kernel<<<O * O / 256, 256, 0, stream>>>(Wp(c, 2), W2b, O);
        zero_kernel<<<6, 256, 0, stream>>>(stats, 1536);
        const int grid = (int)(NPOS / 64);
        auto launch = [&](auto tag) {
            constexpr int OO = decltype(tag)::value;
            stats0_kernel<OO><<<(OO == 256 ? 1024 : 512), 256, 0, stream>>>(T1, T2, idxb, st0);
            if (big) {
                gemm1_kernel<OO><<<grid, 256, 0, stream>>>(T1, T2, idxb, W1b, Bp(c, 1),
                    Gp(c, 0), Ep(c, 0), st0, st1, hbuf, inv_n);
                gemm2_kernel<OO><<<grid, 256, 0, stream>>>(hbuf, W2b, Bp(c, 2),
                    Gp(c, 1), Ep(c, 1), st1, st2, inv_n);
                finish_kernel<OO><<<grid, 256, 0, stream>>>(hbuf, st2, Gp(c, 2), Ep(c, 2),
                    xc, xn, F, inv_n);
            } else {
                conv_stage_kernel<OO, 1><<<grid, 256, 0, stream>>>(T1, T2, idxb,
                    W1b, Bp(c, 1), W2b, Bp(c, 2), Gp(c, 0), Ep(c, 0), Gp(c, 1), Ep(c, 1),
                    Gp(c, 2), Ep(c, 2), st0, st1, st2, xc, xn, F, inv_n);
                conv_stage_kernel<OO, 2><<<grid, 256, 0, stream>>>(T1, T2, idxb,
                    W1b, Bp(c, 1), W2b, Bp(c, 2), Gp(c, 0), Ep(c, 0), Gp(c, 1), Ep(c, 1),
                    Gp(c, 2), Ep(c, 2), st0, st1, st2, xc, xn, F, inv_n);
                conv_stage_kernel<OO, 3><<<grid, 256, 0, stream>>>(T1, T2, idxb,
                    W1b, Bp(c, 1), W2b, Bp(c, 2), Gp(c, 0), Ep(c, 0), Gp(c, 1), Ep(c, 1),
                    Gp(c, 2), Ep(c, 2), st0, st1, st2, xc, xn, F, inv_n);
            }
        };
        if (O == 64)       launch(std::integral_constant<int, 64>{});
        else if (O == 128) launch(std::integral_constant<int, 128>{});
        else               launch(std::integral_constant<int, 256>{});
    };

    run_conv(xin, x1, 3, 2, 64, 0);     // -> x1: C=67
    run_conv(x1, x2, 67, 67, 128, 1);   // -> x2: C=195
    run_conv(x2, x3, 195, 195, 256, 2); // -> x3: C=451
    pool_kernel<<<NB, 256, 0, stream>>>(x3, pooled, 451);
    fc_kernel<<<NB, 256, 0, stream>>>(pooled, fcW1, fcb1, fcW2, fcb2, (float*)d_out, 451);
}

// Round 11
// 1684.030 us; speedup vs baseline: 4.9682x; 1.0153x over previous
//
#include <hip/hip_runtime.h>
#include <hip/hip_bf16.h>
#include <type_traits>

typedef __hip_bfloat16 bf16;
typedef short v8s __attribute__((ext_vector_type(8)));
typedef short v2s __attribute__((ext_vector_type(2)));
typedef float v4f __attribute__((ext_vector_type(4)));

__device__ __forceinline__ float b2f(bf16 v) { return __bfloat162float(v); }
__device__ __forceinline__ bf16  f2b(float v) { return __float2bfloat16(v); }
__device__ __forceinline__ short f2bs(float v) {
    bf16 b = f2b(v); short s; __builtin_memcpy(&s, &b, 2); return s;
}
__device__ __forceinline__ float bs2f(short s) {
    bf16 b; __builtin_memcpy(&b, &s, 2); return b2f(b);
}

#define NB 128
#define NN 128
#define KNN 16
#define M_NODES (NB * NN)          // 16384
#define NPOS ((long)M_NODES * KNN) // 262144 edge rows

// ---------------- zero a small float buffer ----------------
__global__ void zero_kernel(float* __restrict__ p, int n) {
    int i = blockIdx.x * blockDim.x + threadIdx.x;
    if (i < n) p[i] = 0.f;
}

// ---------------- edge-layer weight precompute: transposed bf16 ----------------
__global__ __launch_bounds__(256) void wconv_kernel(const float* __restrict__ W,
        short* __restrict__ Wt, int O) {
    int d = blockIdx.x * 256 + threadIdx.x;      // d = c*O + k
    int c = d / O, k = d - c * O;
    Wt[d] = f2bs(W[(size_t)k * O + c]);
}

// ---------------- layer-0 weight precompute: Wd = bf16(Wt-Wb), Wb, transposed [O,Fpad] --
__global__ __launch_bounds__(256) void wconv0_kernel(const float* __restrict__ W,
        short* __restrict__ Wd, short* __restrict__ Wb, int F, int Fpad, int O) {
    int d = blockIdx.x * 256 + threadIdx.x;      // d = c*Fpad + k
    if (d >= O * Fpad) return;
    int c = d / Fpad, k = d - c * Fpad;
    if (k < F) {
        float wt = W[(size_t)k * O + c];
        float wb = W[(size_t)(F + k) * O + c];
        Wd[d] = f2bs(wt - wb);
        Wb[d] = f2bs(wb);
    } else { Wd[d] = 0; Wb[d] = 0; }
}

// ---------------- kNN part 1: per-node squared norm ----------------
__global__ __launch_bounds__(256) void sq_kernel(const float* __restrict__ x, int C, int D,
                                                 float* __restrict__ sq) {
    int n = blockIdx.x * 256 + threadIdx.x;
    if (n >= M_NODES) return;
    float s = 0.f;
    for (int d = 0; d < D; ++d) { float v = x[(size_t)n * C + d]; s += v * v; }
    sq[n] = s;
}

// ---------------- kNN part 2: d2 tile GEMM (f32 exact -> kNN selection stable) --------
__global__ __launch_bounds__(256) void dist_kernel(const float* __restrict__ x, int C, int D,
                                                   const float* __restrict__ sq,
                                                   float* __restrict__ d2) {
    __shared__ float As[16][65];
    __shared__ float Bs[16][65];
    const int tid = threadIdx.x;
    const int tx = tid & 15, ty = tid >> 4;
    const int m0 = blockIdx.y * 64;
    const int b  = m0 >> 7;
    const int c0 = blockIdx.x * 64;
    float acc[4][4];
#pragma unroll
    for (int r = 0; r < 4; ++r)
#pragma unroll
        for (int c = 0; c < 4; ++c) acc[r][c] = 0.f;
    for (int k0 = 0; k0 < D; k0 += 16) {
        for (int l = tid; l < 1024; l += 256) {
            int k = l & 15, m = l >> 4;
            int kk = k0 + k;
            As[k][m] = (kk < D) ? x[(size_t)(m0 + m) * C + kk] : 0.f;
            Bs[k][m] = (kk < D) ? x[(size_t)(b * NN + c0 + m) * C + kk] : 0.f;
        }
        __syncthreads();
        for (int k = 0; k < 16; ++k) {
            float av[4], bv[4];
#pragma unroll
            for (int r = 0; r < 4; ++r) av[r] = As[k][ty + 16 * r];
#pragma unroll
            for (int c = 0; c < 4; ++c) bv[c] = Bs[k][tx + 16 * c];
#pragma unroll
            for (int r = 0; r < 4; ++r)
#pragma unroll
                for (int c = 0; c < 4; ++c) acc[r][c] += av[r] * bv[c];
        }
        __syncthreads();
    }
#pragma unroll
    for (int r = 0; r < 4; ++r)
#pragma unroll
        for (int c = 0; c < 4; ++c) {
            int m = m0 + ty + 16 * r;
            int jl = c0 + tx + 16 * c;
            int jg = b * NN + jl;
            float v = sq[m] + sq[jg] - 2.0f * acc[r][c];
            if (m == jg) v += 1e9f;
            d2[(size_t)m * NN + jl] = v;
        }
}

// ---------------- kNN part 3: wave-per-node top-16 ----------------
__global__ __launch_bounds__(256) void knn_select_kernel(const float* __restrict__ d2,
                                                         int* __restrict__ idx) {
    const int node = blockIdx.x * 4 + (threadIdx.x >> 6);
    const int lane = threadIdx.x & 63;
    const float* row = d2 + (size_t)node * NN;
    float v0 = row[lane], v1 = row[lane + 64];
    int j0 = lane, j1 = lane + 64;
    int myIdx = 0;
#pragma unroll
    for (int k = 0; k < KNN; ++k) {
        float bv; int bj;
        if (v1 < v0 || (v1 == v0 && j1 < j0)) { bv = v1; bj = j1; }
        else                                 { bv = v0; bj = j0; }
#pragma unroll
        for (int off = 32; off; off >>= 1) {
            float ov = __shfl_xor(bv, off);
            int oj = __shfl_xor(bj, off);
            if (ov < bv || (ov == bv && oj < bj)) { bv = ov; bj = oj; }
        }
        if (bj == j0) v0 = 3.0e38f;
        if (bj == j1) v1 = 3.0e38f;
        if (lane == k) myIdx = bj;
    }
    if (lane < KNN) idx[(size_t)node * KNN + lane] = myIdx;
}

// ---------------- MFMA node GEMM: T1 = x@Wd + bias, T2 = x@Wb (f32 out) ----------------
// Block = 64 node rows x O cols; A staged once in LDS (bf16); two K-passes (Wd, Wb).
template<int O>
__global__ __launch_bounds__(256, 2) void node_gemm_mfma(
    const float* __restrict__ x, int F, int Fpad,
    const short* __restrict__ Wd, const short* __restrict__ Wb,
    const float* __restrict__ bias,
    float* __restrict__ T1, float* __restrict__ T2)
{
    constexpr int CPW = O / 64;
    __shared__ __align__(16) short Am[64][232];   // Fpad <= 224, +8 pad
    const int tid = threadIdx.x;
    const int lane = tid & 63, wave = tid >> 6;
    const int l15 = lane & 15, quad = lane >> 4;
    const int m0 = blockIdx.x * 64;
    for (int l = tid; l < 64 * Fpad; l += 256) {
        int m = l / Fpad, k = l - m * Fpad;
        Am[m][k] = (k < F) ? f2bs(x[(size_t)(m0 + m) * F + k]) : (short)0;
    }
    __syncthreads();
#pragma unroll
    for (int p = 0; p < 2; ++p) {
        const short* __restrict__ Wg = p ? Wb : Wd;
        float* __restrict__ T = p ? T2 : T1;
        v4f acc[4][CPW];
#pragma unroll
        for (int rt = 0; rt < 4; ++rt)
#pragma unroll
            for (int j = 0; j < CPW; ++j)
#pragma unroll
                for (int r = 0; r < 4; ++r) acc[rt][j][r] = 0.f;
        for (int k0 = 0; k0 < Fpad; k0 += 32) {
            v8s av[4];
#pragma unroll
            for (int rt = 0; rt < 4; ++rt)
                av[rt] = *(const v8s*)&Am[rt * 16 + l15][k0 + quad * 8];
#pragma unroll
            for (int j = 0; j < CPW; ++j) {
                int c = (wave * CPW + j) * 16 + l15;
                v8s bv = *(const v8s*)&Wg[(size_t)c * Fpad + k0 + quad * 8];
#pragma unroll
                for (int rt = 0; rt < 4; ++rt)
                    acc[rt][j] = __builtin_amdgcn_mfma_f32_16x16x32_bf16(av[rt], bv, acc[rt][j], 0, 0, 0);
            }
        }
#pragma unroll
        for (int j = 0; j < CPW; ++j) {
            int c = (wave * CPW + j) * 16 + l15;
            float bb = p ? 0.f : bias[c];
#pragma unroll
            for (int rt = 0; rt < 4; ++rt)
#pragma unroll
                for (int r = 0; r < 4; ++r)
                    T[(size_t)(m0 + rt * 16 + quad * 4 + r) * O + c] = acc[rt][j][r] + bb;
        }
    }
}

// ---------------- stats of h0 = T1[n] + T2[nbr] (not materialized) ------
template<int O>
__global__ __launch_bounds__(256) void stats0_kernel(const float* __restrict__ T1,
        const float* __restrict__ T2, const int* __restrict__ idx, float* __restrict__ st0) {
    constexpr int OSH = (O == 64) ? 6 : (O == 128 ? 7 : 8);
    __shared__ float ls[256], lss[256];
    const int t = threadIdx.x;
    const long n = NPOS * O;
    float s = 0.f, ss = 0.f;
    for (long i = (long)blockIdx.x * 256 + t; i < n; i += (long)gridDim.x * 256) {
        int c = (int)(i & (O - 1));
        long e = i >> OSH;
        int nd = (int)(e >> 4);
        int j = idx[e];
        int g = ((nd >> 7) << 7) + j;
        float v = T1[(size_t)nd * O + c] + T2[(size_t)g * O + c];
        s += v; ss += v * v;
    }
    ls[t] = s; lss[t] = ss;
    __syncthreads();
    for (int off = 128; off >= O; off >>= 1) {
        if (t < off) { ls[t] += ls[t + off]; lss[t] += lss[t + off]; }
        __syncthreads();
    }
    if (t < O) { atomicAdd(&st0[t], ls[t]); atomicAdd(&st0[O + t], lss[t]); }
}

// ========================= column-owned MFMA GEMM kernels ==========================
// Wave w owns cols [w*O/4,(w+1)*O/4) for all 64 rows. B fragments load directly from
// transposed bf16 W in global (L2-resident); next K-step's B explicitly prefetched.

// ---------------- gemm1: A0-build -> h1 = A0@W1 + b1 -> h + st1 ----------------
template<int O>
__global__ __launch_bounds__(256, 4) void gemm1_kernel(
    const float* __restrict__ T1, const float* __restrict__ T2, const int* __restrict__ idx,
    const short* __restrict__ W1, const float* __restrict__ bias1,
    const float* __restrict__ gm0, const float* __restrict__ bt0,
    const float* __restrict__ st0, float* __restrict__ st1,
    short* __restrict__ h, float inv_n)
{
    constexpr int CPW = O / 64;
    constexpr int OSH = (O == 64) ? 6 : (O == 128 ? 7 : 8);
    constexpr int AP = O + 8;
    __shared__ __align__(16) short Am[64][AP];
    __shared__ float sc0[O], sh0[O];
    __shared__ int gArr[64];
    const int tid = threadIdx.x;
    const int lane = tid & 63, wave = tid >> 6;
    const int l15 = lane & 15, quad = lane >> 4;
    const int e0 = blockIdx.x * 64;
    const int nb0 = e0 >> 4;

    if (tid < O) {
        float mean = st0[tid] * inv_n;
        float var = fmaxf(st0[O + tid] * inv_n - mean * mean, 0.f);
        float s = rsqrtf(var + 1e-5f) * gm0[tid];
        sc0[tid] = s; sh0[tid] = bt0[tid] - mean * s;
    }
    if (tid < 64) {
        int e = e0 + tid;
        int nd = e >> 4;
        gArr[tid] = ((nd >> 7) << 7) + idx[e];
    }
    __syncthreads();

    for (int l = tid; l < 32 * O; l += 256) {
        int m = l >> (OSH - 1);
        int c = (l & (O / 2 - 1)) * 2;
        const float2 t1 = *(const float2*)&T1[(size_t)(nb0 + (m >> 4)) * O + c];
        const float2 t2 = *(const float2*)&T2[(size_t)gArr[m] * O + c];
        float v0 = fmaxf((t1.x + t2.x) * sc0[c] + sh0[c], 0.f);
        float v1 = fmaxf((t1.y + t2.y) * sc0[c + 1] + sh0[c + 1], 0.f);
        v2s pr; pr[0] = f2bs(v0); pr[1] = f2bs(v1);
        *(v2s*)&Am[m][c] = pr;
    }
    __syncthreads();

    v4f acc[4][CPW];
#pragma unroll
    for (int rt = 0; rt < 4; ++rt)
#pragma unroll
        for (int j = 0; j < CPW; ++j)
#pragma unroll
            for (int r = 0; r < 4; ++r) acc[rt][j][r] = 0.f;

    v8s bvc[CPW];
#pragma unroll
    for (int j = 0; j < CPW; ++j) {
        int c = (wave * CPW + j) * 16 + l15;
        bvc[j] = *(const v8s*)&W1[(size_t)c * O + quad * 8];
    }
#pragma unroll
    for (int k0 = 0; k0 < O; k0 += 32) {
        v8s bvn[CPW];
        if (k0 + 32 < O) {
#pragma unroll
            for (int j = 0; j < CPW; ++j) {
                int c = (wave * CPW + j) * 16 + l15;
                bvn[j] = *(const v8s*)&W1[(size_t)c * O + k0 + 32 + quad * 8];
            }
        }
        v8s av[4];
#pragma unroll
        for (int rt = 0; rt < 4; ++rt)
            av[rt] = *(const v8s*)&Am[rt * 16 + l15][k0 + quad * 8];
#pragma unroll
        for (int j = 0; j < CPW; ++j)
#pragma unroll
            for (int rt = 0; rt < 4; ++rt)
                acc[rt][j] = __builtin_amdgcn_mfma_f32_16x16x32_bf16(av[rt], bvc[j], acc[rt][j], 0, 0, 0);
        if (k0 + 32 < O) {
#pragma unroll
            for (int j = 0; j < CPW; ++j) bvc[j] = bvn[j];
        }
    }
#pragma unroll
    for (int j = 0; j < CPW; ++j) {
        float bb = bias1[(wave * CPW + j) * 16 + l15];
#pragma unroll
        for (int rt = 0; rt < 4; ++rt)
#pragma unroll
            for (int r = 0; r < 4; ++r) acc[rt][j][r] += bb;
    }
#pragma unroll
    for (int j = 0; j < CPW; ++j) {
        int c = (wave * CPW + j) * 16 + l15;
        float s = 0.f, q = 0.f;
#pragma unroll
        for (int rt = 0; rt < 4; ++rt)
#pragma unroll
            for (int r = 0; r < 4; ++r) { float v = acc[rt][j][r]; s += v; q += v * v; }
        s += __shfl_down(s, 32); s += __shfl_down(s, 16);
        q += __shfl_down(q, 32); q += __shfl_down(q, 16);
        if (quad == 0) { atomicAdd(&st1[c], s); atomicAdd(&st1[O + c], q); }
    }
    __syncthreads();
#pragma unroll
    for (int j = 0; j < CPW; ++j) {
        int c = (wave * CPW + j) * 16 + l15;
#pragma unroll
        for (int rt = 0; rt < 4; ++rt)
#pragma unroll
            for (int r = 0; r < 4; ++r)
                Am[rt * 16 + quad * 4 + r][c] = f2bs(acc[rt][j][r]);
    }
    __syncthreads();
    for (int g = tid; g < 8 * O; g += 256) {
        int row = g >> (OSH - 3);
        int c8 = (g & (O / 8 - 1)) * 8;
        *(v8s*)&h[(size_t)(e0 + row) * O + c8] = *(const v8s*)&Am[row][c8];
    }
}

// ---------------- gemm2: h -> bn1+relu -> h2 = A1@W2 + b2 -> h (in place) + st2 ------
template<int O>
__global__ __launch_bounds__(256, 4) void gemm2_kernel(
    short* __restrict__ h,
    const short* __restrict__ W2, const float* __restrict__ bias2,
    const float* __restrict__ gm1, const float* __restrict__ bt1,
    const float* __restrict__ st1, float* __restrict__ st2, float inv_n)
{
    constexpr int CPW = O / 64;
    constexpr int OSH = (O == 64) ? 6 : (O == 128 ? 7 : 8);
    constexpr int AP = O + 8;
    __shared__ __align__(16) short Am[64][AP];
    __shared__ float sc1[O], sh1[O];
    const int tid = threadIdx.x;
    const int lane = tid & 63, wave = tid >> 6;
    const int l15 = lane & 15, quad = lane >> 4;
    const int e0 = blockIdx.x * 64;

    if (tid < O) {
        float mean = st1[tid] * inv_n;
        float var = fmaxf(st1[O + tid] * inv_n - mean * mean, 0.f);
        float s = rsqrtf(var + 1e-5f) * gm1[tid];
        sc1[tid] = s; sh1[tid] = bt1[tid] - mean * s;
    }
    __syncthreads();

    for (int g = tid; g < 8 * O; g += 256) {
        int row = g >> (OSH - 3);
        int c8 = (g & (O / 8 - 1)) * 8;
        v8s hv = *(const v8s*)&h[(size_t)(e0 + row) * O + c8];
        v8s ov;
#pragma unroll
        for (int j = 0; j < 8; ++j) {
            float v = bs2f(hv[j]) * sc1[c8 + j] + sh1[c8 + j];
            ov[j] = f2bs(fmaxf(v, 0.f));
        }
        *(v8s*)&Am[row][c8] = ov;
    }
    __syncthreads();

    v4f acc[4][CPW];
#pragma unroll
    for (int rt = 0; rt < 4; ++rt)
#pragma unroll
        for (int j = 0; j < CPW; ++j)
#pragma unroll
            for (int r = 0; r < 4; ++r) acc[rt][j][r] = 0.f;

    v8s bvc[CPW];
#pragma unroll
    for (int j = 0; j < CPW; ++j) {
        int c = (wave * CPW + j) * 16 + l15;
        bvc[j] = *(const v8s*)&W2[(size_t)c * O + quad * 8];
    }
#pragma unroll
    for (int k0 = 0; k0 < O; k0 += 32) {
        v8s bvn[CPW];
        if (k0 + 32 < O) {
#pragma unroll
            for (int j = 0; j < CPW; ++j) {
                int c = (wave * CPW + j) * 16 + l15;
                bvn[j] = *(const v8s*)&W2[(size_t)c * O + k0 + 32 + quad * 8];
            }
        }
        v8s av[4];
#pragma unroll
        for (int rt = 0; rt < 4; ++rt)
            av[rt] = *(const v8s*)&Am[rt * 16 + l15][k0 + quad * 8];
#pragma unroll
        for (int j = 0; j < CPW; ++j)
#pragma unroll
            for (int rt = 0; rt < 4; ++rt)
                acc[rt][j] = __builtin_amdgcn_mfma_f32_16x16x32_bf16(av[rt], bvc[j], acc[rt][j], 0, 0, 0);
        if (k0 + 32 < O) {
#pragma unroll
            for (int j = 0; j < CPW; ++j) bvc[j] = bvn[j];
        }
    }
#pragma unroll
    for (int j = 0; j < CPW; ++j) {
        float bb = bias2[(wave * CPW + j) * 16 + l15];
#pragma unroll
        for (int rt = 0; rt < 4; ++rt)
#pragma unroll
            for (int r = 0; r < 4; ++r) acc[rt][j][r] += bb;
    }
#pragma unroll
    for (int j = 0; j < CPW; ++j) {
        int c = (wave * CPW + j) * 16 + l15;
        float s = 0.f, q = 0.f;
#pragma unroll
        for (int rt = 0; rt < 4; ++rt)
#pragma unroll
            for (int r = 0; r < 4; ++r) { float v = acc[rt][j][r]; s += v; q += v * v; }
        s += __shfl_down(s, 32); s += __shfl_down(s, 16);
        q += __shfl_down(q, 32); q += __shfl_down(q, 16);
        if (quad == 0) { atomicAdd(&st2[c], s); atomicAdd(&st2[O + c], q); }
    }
    __syncthreads();
#pragma unroll
    for (int j = 0; j < CPW; ++j) {
        int c = (wave * CPW + j) * 16 + l15;
#pragma unroll
        for (int rt = 0; rt < 4; ++rt)
#pragma unroll
            for (int r = 0; r < 4; ++r)
                Am[rt * 16 + quad * 4 + r][c] = f2bs(acc[rt][j][r]);
    }
    __syncthreads();
    for (int g = tid; g < 8 * O; g += 256) {
        int row = g >> (OSH - 3);
        int c8 = (g & (O / 8 - 1)) * 8;
        *(v8s*)&h[(size_t)(e0 + row) * O + c8] = *(const v8s*)&Am[row][c8];
    }
}

// ---------------- finish: stream h2, bn2+relu, k-mean, skip-concat ----------------
template<int O>
__global__ __launch_bounds__(256) void finish_kernel(
    const short* __restrict__ h,
    const float* __restrict__ st2, const float* __restrict__ gm2, const float* __restrict__ bt2,
    const float* __restrict__ xold, float* __restrict__ xnew, int F, float inv_n)
{
    constexpr int G = 256 / O;
    constexpr int RPG = 64 / G;
    constexpr int NPG = RPG / 16;
    const int tid = threadIdx.x;
    const int c = tid & (O - 1);
    const int rg = tid / O;
    const int e0 = blockIdx.x * 64;
    const int nb0 = e0 >> 4;
    float mean = st2[c] * inv_n;
    float var = fmaxf(st2[O + c] * inv_n - mean * mean, 0.f);
    float sc = rsqrtf(var + 1e-5f) * gm2[c];
    float sh = bt2[c] - mean * sc;
    float s[NPG];
#pragma unroll
    for (int i = 0; i < NPG; ++i) s[i] = 0.f;
    const int m0 = rg * RPG;
#pragma unroll
    for (int r = 0; r < RPG; ++r) {
        float v = bs2f(h[(size_t)(e0 + m0 + r) * O + c]) * sc + sh;
        s[r >> 4] += fmaxf(v, 0.f);
    }
    const int Cnew = O + F;
#pragma unroll
    for (int i = 0; i < NPG; ++i)
        xnew[(size_t)(nb0 + rg * NPG + i) * Cnew + c] = s[i] * (1.0f / 16.0f);
    for (int l = tid; l < 4 * F; l += 256) {
        int nd = l / F, cc = l - nd * F;
        xnew[(size_t)(nb0 + nd) * Cnew + O + cc] = xold[(size_t)(nb0 + nd) * F + cc];
    }
}

// ---------------- global mean pool ----------------
__global__ __launch_bounds__(256) void pool_kernel(const float* __restrict__ x, float* __restrict__ pooled, int C) {
    int b = blockIdx.x, t = threadIdx.x;
    for (int c = t; c < C; c += 256) {
        float s = 0.f;
        for (int n = 0; n < NN; ++n) s += x[(size_t)(b * NN + n) * C + c];
        pooled[b * C + c] = s * (1.0f / NN);
    }
}

// ---------------- fc1 + fc2 ----------------
__global__ __launch_bounds__(256) void fc_kernel(const float* __restrict__ pooled,
                                                 const float* __restrict__ W1, const float* __restrict__ b1,
                                                 const float* __restrict__ W2, const float* __restrict__ b2,
                                                 float* __restrict__ out, int C) {
    __shared__ float px[451];
    __shared__ float h1[256];
    int b = blockIdx.x, t = threadIdx.x;
    for (int c = t; c < C; c += 256) px[c] = pooled[b * C + c];
    __syncthreads();
    float s = 0.f;
    for (int i = 0; i < C; ++i) s += px[i] * W1[(size_t)i * 256 + t];
    h1[t] = s + b1[t];
    __syncthreads();
    if (t < 5) {
        float s2 = 0.f;
        for (int j = 0; j < 256; ++j) s2 += h1[j] * W2[j * 5 + t];
        out[b * 5 + t] = s2 + b2[t];
    }
}

extern "C" void kernel_launch(void* const* d_in, const int* in_sizes, int n_in,
                              void* d_out, int out_size, void* d_ws, size_t ws_size,
                              hipStream_t stream) {
    const float* xin = (const float*)d_in[0];
    auto Wp = [&](int c, int l) { return (const float*)d_in[1 + c * 12 + l * 4 + 0]; };
    auto Bp = [&](int c, int l) { return (const float*)d_in[1 + c * 12 + l * 4 + 1]; };
    auto Gp = [&](int c, int l) { return (const float*)d_in[1 + c * 12 + l * 4 + 2]; };
    auto Ep = [&](int c, int l) { return (const float*)d_in[1 + c * 12 + l * 4 + 3]; };
    const float* fcW1 = (const float*)d_in[37];
    const float* fcb1 = (const float*)d_in[38];
    const float* fcW2 = (const float*)d_in[39];
    const float* fcb2 = (const float*)d_in[40];

    char* ws = (char*)d_ws;
    size_t off = 0;
    auto alloc = [&](size_t bytes) -> void* {
        void* p = ws + off;
        off += (bytes + 255) & ~(size_t)255;
        return p;
    };
    const int M = M_NODES;
    float* x1     = (float*)alloc((size_t)M * 67 * 4);
    float* x2     = (float*)alloc((size_t)M * 195 * 4);
    float* x3     = (float*)alloc((size_t)M * 451 * 4);
    float* T1     = (float*)alloc((size_t)M * 256 * 4);
    float* T2     = (float*)alloc((size_t)M * 256 * 4);
    int*   idxb   = (int*)alloc((size_t)M * KNN * 4);
    float* stats  = (float*)alloc(1536 * 4);
    float* pooled = (float*)alloc((size_t)NB * 451 * 4);
    short* W1b    = (short*)alloc(256 * 256 * 2);
    short* W2b    = (short*)alloc(256 * 256 * 2);
    short* W0d    = (short*)alloc(256 * 224 * 2);
    short* W0b    = (short*)alloc(256 * 224 * 2);
    float* d2buf  = (float*)alloc((size_t)M * NN * 4);
    float* sqbuf  = (float*)alloc((size_t)M * 4);
    short* hbuf   = (short*)alloc((size_t)NPOS * 256 * 2); // 134 MiB (ws verified to fit in R9/R10)
    (void)in_sizes; (void)n_in; (void)out_size; (void)ws_size;

    float* st0 = stats, *st1 = stats + 512, *st2 = stats + 1024;
    const float inv_n = 1.0f / (float)NPOS;

    auto run_conv = [&](const float* xc, float* xn, int F, int D, int O, int c) {
        const int Fpad = (F + 31) & ~31;
        sq_kernel<<<M / 256, 256, 0, stream>>>(xc, F, D, sqbuf);
        dist_kernel<<<dim3(2, M / 64), 256, 0, stream>>>(xc, F, D, sqbuf, d2buf);
        knn_select_kernel<<<M / 4, 256, 0, stream>>>(d2buf, idxb);
        wconv0_kernel<<<(O * Fpad + 255) / 256, 256, 0, stream>>>(Wp(c, 0), W0d, W0b, F, Fpad, O);
        wconv_kernel<<<O * O / 256, 256, 0, stream>>>(Wp(c, 1), W1b, O);
        wconv_kernel<<<O * O / 256, 256, 0, stream>>>(Wp(c, 2), W2b, O);
        zero_kernel<<<6, 256, 0, stream>>>(stats, 1536);
        const int grid = (int)(NPOS / 64);
        auto launch = [&](auto tag) {
            constexpr int OO = decltype(tag)::value;
            node_gemm_mfma<OO><<<M / 64, 256, 0, stream>>>(xc, F, Fpad, W0d, W0b, Bp(c, 0), T1, T2);
            stats0_kernel<OO><<<(OO == 256 ? 1024 : 512), 256, 0, stream>>>(T1, T2, idxb, st0);
            gemm1_kernel<OO><<<grid, 256, 0, stream>>>(T1, T2, idxb, W1b, Bp(c, 1),
                Gp(c, 0), Ep(c, 0), st0, st1, hbuf, inv_n);
            gemm2_kernel<OO><<<grid, 256, 0, stream>>>(hbuf, W2b, Bp(c, 2),
                Gp(c, 1), Ep(c, 1), st1, st2, inv_n);
            finish_kernel<OO><<<grid, 256, 0, stream>>>(hbuf, st2, Gp(c, 2), Ep(c, 2),
                xc, xn, F, inv_n);
        };
        if (O == 64)       launch(std::integral_constant<int, 64>{});
        else if (O == 128) launch(std::integral_constant<int, 128>{});
        else               launch(std::integral_constant<int, 256>{});
    };

    run_conv(xin, x1, 3, 2, 64, 0);     // -> x1: C=67
    run_conv(x1, x2, 67, 67, 128, 1);   // -> x2: C=195
    run_conv(x2, x3, 195, 195, 256, 2); // -> x3: C=451
    pool_kernel<<<NB, 256, 0, stream>>>(x3, pooled, 451);
    fc_kernel<<<NB, 256, 0, stream>>>(pooled, fcW1, fcb1, fcW2, fcb2, (float*)d_out, 451);
}

// Round 12
// 1266.496 us; speedup vs baseline: 6.6061x; 1.3297x over previous
//
#include <hip/hip_runtime.h>
#include <hip/hip_bf16.h>
#include <type_traits>

typedef __hip_bfloat16 bf16;
typedef short v8s __attribute__((ext_vector_type(8)));
typedef short v2s __attribute__((ext_vector_type(2)));
typedef float v4f __attribute__((ext_vector_type(4)));

__device__ __forceinline__ float b2f(bf16 v) { return __bfloat162float(v); }
__device__ __forceinline__ bf16  f2b(float v) { return __float2bfloat16(v); }
__device__ __forceinline__ short f2bs(float v) {
    bf16 b = f2b(v); short s; __builtin_memcpy(&s, &b, 2); return s;
}
__device__ __forceinline__ float bs2f(short s) {
    bf16 b; __builtin_memcpy(&b, &s, 2); return b2f(b);
}

#define NB 128
#define NN 128
#define KNN 16
#define M_NODES (NB * NN)          // 16384
#define NPOS ((long)M_NODES * KNN) // 262144 edge rows
#define NREP 16                    // stats replicas (atomic decontention)
// replica layout: 512 floats each -> sum at [c], sumsq at [256+c]

__device__ __forceinline__ void fold_stats(const float* __restrict__ st, int c,
                                           float& sum, float& sq) {
    sum = 0.f; sq = 0.f;
#pragma unroll
    for (int r = 0; r < NREP; ++r) { sum += st[r * 512 + c]; sq += st[r * 512 + 256 + c]; }
}

// ---------------- zero a small float buffer ----------------
__global__ void zero_kernel(float* __restrict__ p, int n) {
    int i = blockIdx.x * blockDim.x + threadIdx.x;
    if (i < n) p[i] = 0.f;
}

// ---------------- edge-layer weight precompute: transposed bf16 ----------------
__global__ __launch_bounds__(256) void wconv_kernel(const float* __restrict__ W,
        short* __restrict__ Wt, int O) {
    int d = blockIdx.x * 256 + threadIdx.x;      // d = c*O + k
    int c = d / O, k = d - c * O;
    Wt[d] = f2bs(W[(size_t)k * O + c]);
}

// ---------------- layer-0 weight precompute: Wd = bf16(Wt-Wb), Wb, transposed [O,Fpad] --
__global__ __launch_bounds__(256) void wconv0_kernel(const float* __restrict__ W,
        short* __restrict__ Wd, short* __restrict__ Wb, int F, int Fpad, int O) {
    int d = blockIdx.x * 256 + threadIdx.x;      // d = c*Fpad + k
    if (d >= O * Fpad) return;
    int c = d / Fpad, k = d - c * Fpad;
    if (k < F) {
        float wt = W[(size_t)k * O + c];
        float wb = W[(size_t)(F + k) * O + c];
        Wd[d] = f2bs(wt - wb);
        Wb[d] = f2bs(wb);
    } else { Wd[d] = 0; Wb[d] = 0; }
}

// ---------------- kNN part 1: per-node squared norm ----------------
__global__ __launch_bounds__(256) void sq_kernel(const float* __restrict__ x, int C, int D,
                                                 float* __restrict__ sq) {
    int n = blockIdx.x * 256 + threadIdx.x;
    if (n >= M_NODES) return;
    float s = 0.f;
    for (int d = 0; d < D; ++d) { float v = x[(size_t)n * C + d]; s += v * v; }
    sq[n] = s;
}

// ---------------- kNN part 2: d2 tile GEMM (f32 exact) ----------------
__global__ __launch_bounds__(256) void dist_kernel(const float* __restrict__ x, int C, int D,
                                                   const float* __restrict__ sq,
                                                   float* __restrict__ d2) {
    __shared__ float As[16][65];
    __shared__ float Bs[16][65];
    const int tid = threadIdx.x;
    const int tx = tid & 15, ty = tid >> 4;
    const int m0 = blockIdx.y * 64;
    const int b  = m0 >> 7;
    const int c0 = blockIdx.x * 64;
    float acc[4][4];
#pragma unroll
    for (int r = 0; r < 4; ++r)
#pragma unroll
        for (int c = 0; c < 4; ++c) acc[r][c] = 0.f;
    for (int k0 = 0; k0 < D; k0 += 16) {
        for (int l = tid; l < 1024; l += 256) {
            int k = l & 15, m = l >> 4;
            int kk = k0 + k;
            As[k][m] = (kk < D) ? x[(size_t)(m0 + m) * C + kk] : 0.f;
            Bs[k][m] = (kk < D) ? x[(size_t)(b * NN + c0 + m) * C + kk] : 0.f;
        }
        __syncthreads();
        for (int k = 0; k < 16; ++k) {
            float av[4], bv[4];
#pragma unroll
            for (int r = 0; r < 4; ++r) av[r] = As[k][ty + 16 * r];
#pragma unroll
            for (int c = 0; c < 4; ++c) bv[c] = Bs[k][tx + 16 * c];
#pragma unroll
            for (int r = 0; r < 4; ++r)
#pragma unroll
                for (int c = 0; c < 4; ++c) acc[r][c] += av[r] * bv[c];
        }
        __syncthreads();
    }
#pragma unroll
    for (int r = 0; r < 4; ++r)
#pragma unroll
        for (int c = 0; c < 4; ++c) {
            int m = m0 + ty + 16 * r;
            int jl = c0 + tx + 16 * c;
            int jg = b * NN + jl;
            float v = sq[m] + sq[jg] - 2.0f * acc[r][c];
            if (m == jg) v += 1e9f;
            d2[(size_t)m * NN + jl] = v;
        }
}

// ---------------- kNN part 3: wave-per-node top-16 ----------------
__global__ __launch_bounds__(256) void knn_select_kernel(const float* __restrict__ d2,
                                                         int* __restrict__ idx) {
    const int node = blockIdx.x * 4 + (threadIdx.x >> 6);
    const int lane = threadIdx.x & 63;
    const float* row = d2 + (size_t)node * NN;
    float v0 = row[lane], v1 = row[lane + 64];
    int j0 = lane, j1 = lane + 64;
    int myIdx = 0;
#pragma unroll
    for (int k = 0; k < KNN; ++k) {
        float bv; int bj;
        if (v1 < v0 || (v1 == v0 && j1 < j0)) { bv = v1; bj = j1; }
        else                                 { bv = v0; bj = j0; }
#pragma unroll
        for (int off = 32; off; off >>= 1) {
            float ov = __shfl_xor(bv, off);
            int oj = __shfl_xor(bj, off);
            if (ov < bv || (ov == bv && oj < bj)) { bv = ov; bj = oj; }
        }
        if (bj == j0) v0 = 3.0e38f;
        if (bj == j1) v1 = 3.0e38f;
        if (lane == k) myIdx = bj;
    }
    if (lane < KNN) idx[(size_t)node * KNN + lane] = myIdx;
}

// ---------------- MFMA node GEMM: T1 = x@Wd + bias, T2 = x@Wb (f32 out) ----------------
template<int O>
__global__ __launch_bounds__(256, 2) void node_gemm_mfma(
    const float* __restrict__ x, int F, int Fpad,
    const short* __restrict__ Wd, const short* __restrict__ Wb,
    const float* __restrict__ bias,
    float* __restrict__ T1, float* __restrict__ T2)
{
    constexpr int CPW = O / 64;
    __shared__ __align__(16) short Am[64][232];   // Fpad <= 224, +8 pad
    const int tid = threadIdx.x;
    const int lane = tid & 63, wave = tid >> 6;
    const int l15 = lane & 15, quad = lane >> 4;
    const int m0 = blockIdx.x * 64;
    for (int l = tid; l < 64 * Fpad; l += 256) {
        int m = l / Fpad, k = l - m * Fpad;
        Am[m][k] = (k < F) ? f2bs(x[(size_t)(m0 + m) * F + k]) : (short)0;
    }
    __syncthreads();
#pragma unroll
    for (int p = 0; p < 2; ++p) {
        const short* __restrict__ Wg = p ? Wb : Wd;
        float* __restrict__ T = p ? T2 : T1;
        v4f acc[4][CPW];
#pragma unroll
        for (int rt = 0; rt < 4; ++rt)
#pragma unroll
            for (int j = 0; j < CPW; ++j)
#pragma unroll
                for (int r = 0; r < 4; ++r) acc[rt][j][r] = 0.f;
        for (int k0 = 0; k0 < Fpad; k0 += 32) {
            v8s av[4];
#pragma unroll
            for (int rt = 0; rt < 4; ++rt)
                av[rt] = *(const v8s*)&Am[rt * 16 + l15][k0 + quad * 8];
#pragma unroll
            for (int j = 0; j < CPW; ++j) {
                int c = (wave * CPW + j) * 16 + l15;
                v8s bv = *(const v8s*)&Wg[(size_t)c * Fpad + k0 + quad * 8];
#pragma unroll
                for (int rt = 0; rt < 4; ++rt)
                    acc[rt][j] = __builtin_amdgcn_mfma_f32_16x16x32_bf16(av[rt], bv, acc[rt][j], 0, 0, 0);
            }
        }
#pragma unroll
        for (int j = 0; j < CPW; ++j) {
            int c = (wave * CPW + j) * 16 + l15;
            float bb = p ? 0.f : bias[c];
#pragma unroll
            for (int rt = 0; rt < 4; ++rt)
#pragma unroll
                for (int r = 0; r < 4; ++r)
                    T[(size_t)(m0 + rt * 16 + quad * 4 + r) * O + c] = acc[rt][j][r] + bb;
        }
    }
}

// ---------------- stats of h0 = T1[n] + T2[nbr] (not materialized) ------
template<int O>
__global__ __launch_bounds__(256) void stats0_kernel(const float* __restrict__ T1,
        const float* __restrict__ T2, const int* __restrict__ idx, float* __restrict__ st0) {
    constexpr int OSH = (O == 64) ? 6 : (O == 128 ? 7 : 8);
    __shared__ float ls[256], lss[256];
    const int t = threadIdx.x;
    const long n = NPOS * O;
    float s = 0.f, ss = 0.f;
    for (long i = (long)blockIdx.x * 256 + t; i < n; i += (long)gridDim.x * 256) {
        int c = (int)(i & (O - 1));
        long e = i >> OSH;
        int nd = (int)(e >> 4);
        int j = idx[e];
        int g = ((nd >> 7) << 7) + j;
        float v = T1[(size_t)nd * O + c] + T2[(size_t)g * O + c];
        s += v; ss += v * v;
    }
    ls[t] = s; lss[t] = ss;
    __syncthreads();
    for (int off = 128; off >= O; off >>= 1) {
        if (t < off) { ls[t] += ls[t + off]; lss[t] += lss[t + off]; }
        __syncthreads();
    }
    const int rep = blockIdx.x & (NREP - 1);
    if (t < O) {
        atomicAdd(&st0[rep * 512 + t], ls[t]);
        atomicAdd(&st0[rep * 512 + 256 + t], lss[t]);
    }
}

// ========================= column-owned MFMA GEMM kernels ==========================

// ---------------- gemm1: A0-build -> h1 = A0@W1 + b1 -> h + st1 ----------------
template<int O>
__global__ __launch_bounds__(256, 4) void gemm1_kernel(
    const float* __restrict__ T1, const float* __restrict__ T2, const int* __restrict__ idx,
    const short* __restrict__ W1, const float* __restrict__ bias1,
    const float* __restrict__ gm0, const float* __restrict__ bt0,
    const float* __restrict__ st0, float* __restrict__ st1,
    short* __restrict__ h, float inv_n)
{
    constexpr int CPW = O / 64;
    constexpr int OSH = (O == 64) ? 6 : (O == 128 ? 7 : 8);
    constexpr int AP = O + 8;
    __shared__ __align__(16) short Am[64][AP];
    __shared__ float T1s[4 * O];              // 4 node rows staged once (kills 16x reuse)
    __shared__ float sc0[O], sh0[O];
    __shared__ int gArr[64];
    const int tid = threadIdx.x;
    const int lane = tid & 63, wave = tid >> 6;
    const int l15 = lane & 15, quad = lane >> 4;
    const int e0 = blockIdx.x * 64;
    const int nb0 = e0 >> 4;
    const int rep = blockIdx.x & (NREP - 1);

    if (tid < O) {
        float sum, sq;
        fold_stats(st0, tid, sum, sq);
        float mean = sum * inv_n;
        float var = fmaxf(sq * inv_n - mean * mean, 0.f);
        float s = rsqrtf(var + 1e-5f) * gm0[tid];
        sc0[tid] = s; sh0[tid] = bt0[tid] - mean * s;
    }
    for (int l = tid; l < 4 * O; l += 256)
        T1s[l] = T1[(size_t)(nb0 + (l >> OSH)) * O + (l & (O - 1))];
    if (tid < 64) {
        int e = e0 + tid;
        int nd = e >> 4;
        gArr[tid] = ((nd >> 7) << 7) + idx[e];
    }
    __syncthreads();

    for (int l = tid; l < 32 * O; l += 256) {
        int m = l >> (OSH - 1);
        int c = (l & (O / 2 - 1)) * 2;
        const float2 t2 = *(const float2*)&T2[(size_t)gArr[m] * O + c];
        const int tb = (m >> 4) * O + c;
        float v0 = fmaxf((T1s[tb] + t2.x) * sc0[c] + sh0[c], 0.f);
        float v1 = fmaxf((T1s[tb + 1] + t2.y) * sc0[c + 1] + sh0[c + 1], 0.f);
        v2s pr; pr[0] = f2bs(v0); pr[1] = f2bs(v1);
        *(v2s*)&Am[m][c] = pr;
    }
    __syncthreads();

    v4f acc[4][CPW];
#pragma unroll
    for (int rt = 0; rt < 4; ++rt)
#pragma unroll
        for (int j = 0; j < CPW; ++j)
#pragma unroll
            for (int r = 0; r < 4; ++r) acc[rt][j][r] = 0.f;

    v8s bvc[CPW];
#pragma unroll
    for (int j = 0; j < CPW; ++j) {
        int c = (wave * CPW + j) * 16 + l15;
        bvc[j] = *(const v8s*)&W1[(size_t)c * O + quad * 8];
    }
#pragma unroll
    for (int k0 = 0; k0 < O; k0 += 32) {
        v8s bvn[CPW];
        if (k0 + 32 < O) {
#pragma unroll
            for (int j = 0; j < CPW; ++j) {
                int c = (wave * CPW + j) * 16 + l15;
                bvn[j] = *(const v8s*)&W1[(size_t)c * O + k0 + 32 + quad * 8];
            }
        }
        v8s av[4];
#pragma unroll
        for (int rt = 0; rt < 4; ++rt)
            av[rt] = *(const v8s*)&Am[rt * 16 + l15][k0 + quad * 8];
#pragma unroll
        for (int j = 0; j < CPW; ++j)
#pragma unroll
            for (int rt = 0; rt < 4; ++rt)
                acc[rt][j] = __builtin_amdgcn_mfma_f32_16x16x32_bf16(av[rt], bvc[j], acc[rt][j], 0, 0, 0);
        if (k0 + 32 < O) {
#pragma unroll
            for (int j = 0; j < CPW; ++j) bvc[j] = bvn[j];
        }
    }
#pragma unroll
    for (int j = 0; j < CPW; ++j) {
        float bb = bias1[(wave * CPW + j) * 16 + l15];
#pragma unroll
        for (int rt = 0; rt < 4; ++rt)
#pragma unroll
            for (int r = 0; r < 4; ++r) acc[rt][j][r] += bb;
    }
#pragma unroll
    for (int j = 0; j < CPW; ++j) {
        int c = (wave * CPW + j) * 16 + l15;
        float s = 0.f, q = 0.f;
#pragma unroll
        for (int rt = 0; rt < 4; ++rt)
#pragma unroll
            for (int r = 0; r < 4; ++r) { float v = acc[rt][j][r]; s += v; q += v * v; }
        s += __shfl_down(s, 32); s += __shfl_down(s, 16);
        q += __shfl_down(q, 32); q += __shfl_down(q, 16);
        if (quad == 0) { atomicAdd(&st1[rep * 512 + c], s); atomicAdd(&st1[rep * 512 + 256 + c], q); }
    }
    __syncthreads();
#pragma unroll
    for (int j = 0; j < CPW; ++j) {
        int c = (wave * CPW + j) * 16 + l15;
#pragma unroll
        for (int rt = 0; rt < 4; ++rt)
#pragma unroll
            for (int r = 0; r < 4; ++r)
                Am[rt * 16 + quad * 4 + r][c] = f2bs(acc[rt][j][r]);
    }
    __syncthreads();
    for (int g = tid; g < 8 * O; g += 256) {
        int row = g >> (OSH - 3);
        int c8 = (g & (O / 8 - 1)) * 8;
        *(v8s*)&h[(size_t)(e0 + row) * O + c8] = *(const v8s*)&Am[row][c8];
    }
}

// ---------------- gemm2: h -> bn1+relu -> h2 = A1@W2 + b2 -> h (in place) + st2 ------
template<int O>
__global__ __launch_bounds__(256, 4) void gemm2_kernel(
    short* __restrict__ h,
    const short* __restrict__ W2, const float* __restrict__ bias2,
    const float* __restrict__ gm1, const float* __restrict__ bt1,
    const float* __restrict__ st1, float* __restrict__ st2, float inv_n)
{
    constexpr int CPW = O / 64;
    constexpr int OSH = (O == 64) ? 6 : (O == 128 ? 7 : 8);
    constexpr int AP = O + 8;
    __shared__ __align__(16) short Am[64][AP];
    __shared__ float sc1[O], sh1[O];
    const int tid = threadIdx.x;
    const int lane = tid & 63, wave = tid >> 6;
    const int l15 = lane & 15, quad = lane >> 4;
    const int e0 = blockIdx.x * 64;
    const int rep = blockIdx.x & (NREP - 1);

    if (tid < O) {
        float sum, sq;
        fold_stats(st1, tid, sum, sq);
        float mean = sum * inv_n;
        float var = fmaxf(sq * inv_n - mean * mean, 0.f);
        float s = rsqrtf(var + 1e-5f) * gm1[tid];
        sc1[tid] = s; sh1[tid] = bt1[tid] - mean * s;
    }
    __syncthreads();

    for (int g = tid; g < 8 * O; g += 256) {
        int row = g >> (OSH - 3);
        int c8 = (g & (O / 8 - 1)) * 8;
        v8s hv = *(const v8s*)&h[(size_t)(e0 + row) * O + c8];
        v8s ov;
#pragma unroll
        for (int j = 0; j < 8; ++j) {
            float v = bs2f(hv[j]) * sc1[c8 + j] + sh1[c8 + j];
            ov[j] = f2bs(fmaxf(v, 0.f));
        }
        *(v8s*)&Am[row][c8] = ov;
    }
    __syncthreads();

    v4f acc[4][CPW];
#pragma unroll
    for (int rt = 0; rt < 4; ++rt)
#pragma unroll
        for (int j = 0; j < CPW; ++j)
#pragma unroll
            for (int r = 0; r < 4; ++r) acc[rt][j][r] = 0.f;

    v8s bvc[CPW];
#pragma unroll
    for (int j = 0; j < CPW; ++j) {
        int c = (wave * CPW + j) * 16 + l15;
        bvc[j] = *(const v8s*)&W2[(size_t)c * O + quad * 8];
    }
#pragma unroll
    for (int k0 = 0; k0 < O; k0 += 32) {
        v8s bvn[CPW];
        if (k0 + 32 < O) {
#pragma unroll
            for (int j = 0; j < CPW; ++j) {
                int c = (wave * CPW + j) * 16 + l15;
                bvn[j] = *(const v8s*)&W2[(size_t)c * O + k0 + 32 + quad * 8];
            }
        }
        v8s av[4];
#pragma unroll
        for (int rt = 0; rt < 4; ++rt)
            av[rt] = *(const v8s*)&Am[rt * 16 + l15][k0 + quad * 8];
#pragma unroll
        for (int j = 0; j < CPW; ++j)
#pragma unroll
            for (int rt = 0; rt < 4; ++rt)
                acc[rt][j] = __builtin_amdgcn_mfma_f32_16x16x32_bf16(av[rt], bvc[j], acc[rt][j], 0, 0, 0);
        if (k0 + 32 < O) {
#pragma unroll
            for (int j = 0; j < CPW; ++j) bvc[j] = bvn[j];
        }
    }
#pragma unroll
    for (int j = 0; j < CPW; ++j) {
        float bb = bias2[(wave * CPW + j) * 16 + l15];
#pragma unroll
        for (int rt = 0; rt < 4; ++rt)
#pragma unroll
            for (int r = 0; r < 4; ++r) acc[rt][j][r] += bb;
    }
#pragma unroll
    for (int j = 0; j < CPW; ++j) {
        int c = (wave * CPW + j) * 16 + l15;
        float s = 0.f, q = 0.f;
#pragma unroll
        for (int rt = 0; rt < 4; ++rt)
#pragma unroll
            for (int r = 0; r < 4; ++r) { float v = acc[rt][j][r]; s += v; q += v * v; }
        s += __shfl_down(s, 32); s += __shfl_down(s, 16);
        q += __shfl_down(q, 32); q += __shfl_down(q, 16);
        if (quad == 0) { atomicAdd(&st2[rep * 512 + c], s); atomicAdd(&st2[rep * 512 + 256 + c], q); }
    }
    __syncthreads();
#pragma unroll
    for (int j = 0; j < CPW; ++j) {
        int c = (wave * CPW + j) * 16 + l15;
#pragma unroll
        for (int rt = 0; rt < 4; ++rt)
#pragma unroll
            for (int r = 0; r < 4; ++r)
                Am[rt * 16 + quad * 4 + r][c] = f2bs(acc[rt][j][r]);
    }
    __syncthreads();
    for (int g = tid; g < 8 * O; g += 256) {
        int row = g >> (OSH - 3);
        int c8 = (g & (O / 8 - 1)) * 8;
        *(v8s*)&h[(size_t)(e0 + row) * O + c8] = *(const v8s*)&Am[row][c8];
    }
}

// ---------------- finish: stream h2, bn2+relu, k-mean, skip-concat ----------------
template<int O>
__global__ __launch_bounds__(256) void finish_kernel(
    const short* __restrict__ h,
    const float* __restrict__ st2, const float* __restrict__ gm2, const float* __restrict__ bt2,
    const float* __restrict__ xold, float* __restrict__ xnew, int F, float inv_n)
{
    constexpr int G = 256 / O;
    constexpr int RPG = 64 / G;
    constexpr int NPG = RPG / 16;
    const int tid = threadIdx.x;
    const int c = tid & (O - 1);
    const int rg = tid / O;
    const int e0 = blockIdx.x * 64;
    const int nb0 = e0 >> 4;
    float sum, sq;
    fold_stats(st2, c, sum, sq);
    float mean = sum * inv_n;
    float var = fmaxf(sq * inv_n - mean * mean, 0.f);
    float sc = rsqrtf(var + 1e-5f) * gm2[c];
    float sh = bt2[c] - mean * sc;
    float s[NPG];
#pragma unroll
    for (int i = 0; i < NPG; ++i) s[i] = 0.f;
    const int m0 = rg * RPG;
#pragma unroll
    for (int r = 0; r < RPG; ++r) {
        float v = bs2f(h[(size_t)(e0 + m0 + r) * O + c]) * sc + sh;
        s[r >> 4] += fmaxf(v, 0.f);
    }
    const int Cnew = O + F;
#pragma unroll
    for (int i = 0; i < NPG; ++i)
        xnew[(size_t)(nb0 + rg * NPG + i) * Cnew + c] = s[i] * (1.0f / 16.0f);
    for (int l = tid; l < 4 * F; l += 256) {
        int nd = l / F, cc = l - nd * F;
        xnew[(size_t)(nb0 + nd) * Cnew + O + cc] = xold[(size_t)(nb0 + nd) * F + cc];
    }
}

// ---------------- global mean pool ----------------
__global__ __launch_bounds__(256) void pool_kernel(const float* __restrict__ x, float* __restrict__ pooled, int C) {
    int b = blockIdx.x, t = threadIdx.x;
    for (int c = t; c < C; c += 256) {
        float s = 0.f;
        for (int n = 0; n < NN; ++n) s += x[(size_t)(b * NN + n) * C + c];
        pooled[b * C + c] = s * (1.0f / NN);
    }
}

// ---------------- fc1 + fc2 ----------------
__global__ __launch_bounds__(256) void fc_kernel(const float* __restrict__ pooled,
                                                 const float* __restrict__ W1, const float* __restrict__ b1,
                                                 const float* __restrict__ W2, const float* __restrict__ b2,
                                                 float* __restrict__ out, int C) {
    __shared__ float px[451];
    __shared__ float h1[256];
    int b = blockIdx.x, t = threadIdx.x;
    for (int c = t; c < C; c += 256) px[c] = pooled[b * C + c];
    __syncthreads();
    float s = 0.f;
    for (int i = 0; i < C; ++i) s += px[i] * W1[(size_t)i * 256 + t];
    h1[t] = s + b1[t];
    __syncthreads();
    if (t < 5) {
        float s2 = 0.f;
        for (int j = 0; j < 256; ++j) s2 += h1[j] * W2[j * 5 + t];
        out[b * 5 + t] = s2 + b2[t];
    }
}

extern "C" void kernel_launch(void* const* d_in, const int* in_sizes, int n_in,
                              void* d_out, int out_size, void* d_ws, size_t ws_size,
                              hipStream_t stream) {
    const float* xin = (const float*)d_in[0];
    auto Wp = [&](int c, int l) { return (const float*)d_in[1 + c * 12 + l * 4 + 0]; };
    auto Bp = [&](int c, int l) { return (const float*)d_in[1 + c * 12 + l * 4 + 1]; };
    auto Gp = [&](int c, int l) { return (const float*)d_in[1 + c * 12 + l * 4 + 2]; };
    auto Ep = [&](int c, int l) { return (const float*)d_in[1 + c * 12 + l * 4 + 3]; };
    const float* fcW1 = (const float*)d_in[37];
    const float* fcb1 = (const float*)d_in[38];
    const float* fcW2 = (const float*)d_in[39];
    const float* fcb2 = (const float*)d_in[40];

    char* ws = (char*)d_ws;
    size_t off = 0;
    auto alloc = [&](size_t bytes) -> void* {
        void* p = ws + off;
        off += (bytes + 255) & ~(size_t)255;
        return p;
    };
    const int M = M_NODES;
    float* x1     = (float*)alloc((size_t)M * 67 * 4);
    float* x2     = (float*)alloc((size_t)M * 195 * 4);
    float* x3     = (float*)alloc((size_t)M * 451 * 4);
    float* T1     = (float*)alloc((size_t)M * 256 * 4);
    float* T2     = (float*)alloc((size_t)M * 256 * 4);
    int*   idxb   = (int*)alloc((size_t)M * KNN * 4);
    float* stats  = (float*)alloc((size_t)3 * NREP * 512 * 4);   // st0/st1/st2 x 16 replicas
    float* pooled = (float*)alloc((size_t)NB * 451 * 4);
    short* W1b    = (short*)alloc(256 * 256 * 2);
    short* W2b    = (short*)alloc(256 * 256 * 2);
    short* W0d    = (short*)alloc(256 * 224 * 2);
    short* W0b    = (short*)alloc(256 * 224 * 2);
    float* d2buf  = (float*)alloc((size_t)M * NN * 4);
    float* sqbuf  = (float*)alloc((size_t)M * 4);
    short* hbuf   = (short*)alloc((size_t)NPOS * 256 * 2); // 134 MiB (ws verified to fit)
    (void)in_sizes; (void)n_in; (void)out_size; (void)ws_size;

    float* st0 = stats;
    float* st1 = stats + NREP * 512;
    float* st2 = stats + 2 * NREP * 512;
    const float inv_n = 1.0f / (float)NPOS;

    auto run_conv = [&](const float* xc, float* xn, int F, int D, int O, int c) {
        const int Fpad = (F + 31) & ~31;
        sq_kernel<<<M / 256, 256, 0, stream>>>(xc, F, D, sqbuf);
        dist_kernel<<<dim3(2, M / 64), 256, 0, stream>>>(xc, F, D, sqbuf, d2buf);
        knn_select_kernel<<<M / 4, 256, 0, stream>>>(d2buf, idxb);
        wconv0_kernel<<<(O * Fpad + 255) / 256, 256, 0, stream>>>(Wp(c, 0), W0d, W0b, F, Fpad, O);
        wconv_kernel<<<O * O / 256, 256, 0, stream>>>(Wp(c, 1), W1b, O);
        wconv_kernel<<<O * O / 256, 256, 0, stream>>>(Wp(c, 2), W2b, O);
        zero_kernel<<<3 * NREP * 2, 256, 0, stream>>>(stats, 3 * NREP * 512);
        const int grid = (int)(NPOS / 64);
        auto launch = [&](auto tag) {
            constexpr int OO = decltype(tag)::value;
            node_gemm_mfma<OO><<<M / 64, 256, 0, stream>>>(xc, F, Fpad, W0d, W0b, Bp(c, 0), T1, T2);
            stats0_kernel<OO><<<(OO == 256 ? 1024 : 512), 256, 0, stream>>>(T1, T2, idxb, st0);
            gemm1_kernel<OO><<<grid, 256, 0, stream>>>(T1, T2, idxb, W1b, Bp(c, 1),
                Gp(c, 0), Ep(c, 0), st0, st1, hbuf, inv_n);
            gemm2_kernel<OO><<<grid, 256, 0, stream>>>(hbuf, W2b, Bp(c, 2),
                Gp(c, 1), Ep(c, 1), st1, st2, inv_n);
            finish_kernel<OO><<<grid, 256, 0, stream>>>(hbuf, st2, Gp(c, 2), Ep(c, 2),
                xc, xn, F, inv_n);
        };
        if (O == 64)       launch(std::integral_constant<int, 64>{});
        else if (O == 128) launch(std::integral_constant<int, 128>{});
        else               launch(std::integral_constant<int, 256>{});
    };

    run_conv(xin, x1, 3, 2, 64, 0);     // -> x1: C=67
    run_conv(x1, x2, 67, 67, 128, 1);   // -> x2: C=195
    run_conv(x2, x3, 195, 195, 256, 2); // -> x3: C=451
    pool_kernel<<<NB, 256, 0, stream>>>(x3, pooled, 451);
    fc_kernel<<<NB, 256, 0, stream>>>(pooled, fcW1, fcb1, fcW2, fcb2, (float*)d_out, 451);
}

// Round 13
// 1025.871 us; speedup vs baseline: 8.1557x; 1.2346x over previous
//
#include <hip/hip_runtime.h>
#include <hip/hip_bf16.h>
#include <type_traits>

typedef __hip_bfloat16 bf16;
typedef short v8s __attribute__((ext_vector_type(8)));
typedef short v2s __attribute__((ext_vector_type(2)));
typedef float v4f __attribute__((ext_vector_type(4)));

__device__ __forceinline__ float b2f(bf16 v) { return __bfloat162float(v); }
__device__ __forceinline__ bf16  f2b(float v) { return __float2bfloat16(v); }
__device__ __forceinline__ short f2bs(float v) {
    bf16 b = f2b(v); short s; __builtin_memcpy(&s, &b, 2); return s;
}
__device__ __forceinline__ float bs2f(short s) {
    bf16 b; __builtin_memcpy(&b, &s, 2); return b2f(b);
}

#define NB 128
#define NN 128
#define KNN 16
#define M_NODES (NB * NN)          // 16384
#define NPOS ((long)M_NODES * KNN) // 262144 edge rows
#define NREP 16                    // stats replicas (atomic decontention)
// replica layout: 512 floats each -> sum at [c], sumsq at [256+c]

__device__ __forceinline__ void fold_stats(const float* __restrict__ st, int c,
                                           float& sum, float& sq) {
    sum = 0.f; sq = 0.f;
#pragma unroll
    for (int r = 0; r < NREP; ++r) { sum += st[r * 512 + c]; sq += st[r * 512 + 256 + c]; }
}

// ---------------- zero a small float buffer ----------------
__global__ void zero_kernel(float* __restrict__ p, int n) {
    int i = blockIdx.x * blockDim.x + threadIdx.x;
    if (i < n) p[i] = 0.f;
}

// ---------------- edge-layer weight precompute: transposed bf16 ----------------
__global__ __launch_bounds__(256) void wconv_kernel(const float* __restrict__ W,
        short* __restrict__ Wt, int O) {
    int d = blockIdx.x * 256 + threadIdx.x;      // d = c*O + k
    int c = d / O, k = d - c * O;
    Wt[d] = f2bs(W[(size_t)k * O + c]);
}

// ---------------- layer-0 weight precompute: Wd = bf16(Wt-Wb), Wb, transposed [O,Fpad] --
__global__ __launch_bounds__(256) void wconv0_kernel(const float* __restrict__ W,
        short* __restrict__ Wd, short* __restrict__ Wb, int F, int Fpad, int O) {
    int d = blockIdx.x * 256 + threadIdx.x;      // d = c*Fpad + k
    if (d >= O * Fpad) return;
    int c = d / Fpad, k = d - c * Fpad;
    if (k < F) {
        float wt = W[(size_t)k * O + c];
        float wb = W[(size_t)(F + k) * O + c];
        Wd[d] = f2bs(wt - wb);
        Wb[d] = f2bs(wb);
    } else { Wd[d] = 0; Wb[d] = 0; }
}

// ---------------- kNN part 1: per-node squared norm ----------------
__global__ __launch_bounds__(256) void sq_kernel(const float* __restrict__ x, int C, int D,
                                                 float* __restrict__ sq) {
    int n = blockIdx.x * 256 + threadIdx.x;
    if (n >= M_NODES) return;
    float s = 0.f;
    for (int d = 0; d < D; ++d) { float v = x[(size_t)n * C + d]; s += v * v; }
    sq[n] = s;
}

// ---------------- kNN part 2: d2 tile GEMM (f32 exact) ----------------
__global__ __launch_bounds__(256) void dist_kernel(const float* __restrict__ x, int C, int D,
                                                   const float* __restrict__ sq,
                                                   float* __restrict__ d2) {
    __shared__ float As[16][65];
    __shared__ float Bs[16][65];
    const int tid = threadIdx.x;
    const int tx = tid & 15, ty = tid >> 4;
    const int m0 = blockIdx.y * 64;
    const int b  = m0 >> 7;
    const int c0 = blockIdx.x * 64;
    float acc[4][4];
#pragma unroll
    for (int r = 0; r < 4; ++r)
#pragma unroll
        for (int c = 0; c < 4; ++c) acc[r][c] = 0.f;
    for (int k0 = 0; k0 < D; k0 += 16) {
        for (int l = tid; l < 1024; l += 256) {
            int k = l & 15, m = l >> 4;
            int kk = k0 + k;
            As[k][m] = (kk < D) ? x[(size_t)(m0 + m) * C + kk] : 0.f;
            Bs[k][m] = (kk < D) ? x[(size_t)(b * NN + c0 + m) * C + kk] : 0.f;
        }
        __syncthreads();
        for (int k = 0; k < 16; ++k) {
            float av[4], bv[4];
#pragma unroll
            for (int r = 0; r < 4; ++r) av[r] = As[k][ty + 16 * r];
#pragma unroll
            for (int c = 0; c < 4; ++c) bv[c] = Bs[k][tx + 16 * c];
#pragma unroll
            for (int r = 0; r < 4; ++r)
#pragma unroll
                for (int c = 0; c < 4; ++c) acc[r][c] += av[r] * bv[c];
        }
        __syncthreads();
    }
#pragma unroll
    for (int r = 0; r < 4; ++r)
#pragma unroll
        for (int c = 0; c < 4; ++c) {
            int m = m0 + ty + 16 * r;
            int jl = c0 + tx + 16 * c;
            int jg = b * NN + jl;
            float v = sq[m] + sq[jg] - 2.0f * acc[r][c];
            if (m == jg) v += 1e9f;
            d2[(size_t)m * NN + jl] = v;
        }
}

// ---------------- kNN part 3: wave-per-node top-16 ----------------
__global__ __launch_bounds__(256) void knn_select_kernel(const float* __restrict__ d2,
                                                         int* __restrict__ idx) {
    const int node = blockIdx.x * 4 + (threadIdx.x >> 6);
    const int lane = threadIdx.x & 63;
    const float* row = d2 + (size_t)node * NN;
    float v0 = row[lane], v1 = row[lane + 64];
    int j0 = lane, j1 = lane + 64;
    int myIdx = 0;
#pragma unroll
    for (int k = 0; k < KNN; ++k) {
        float bv; int bj;
        if (v1 < v0 || (v1 == v0 && j1 < j0)) { bv = v1; bj = j1; }
        else                                 { bv = v0; bj = j0; }
#pragma unroll
        for (int off = 32; off; off >>= 1) {
            float ov = __shfl_xor(bv, off);
            int oj = __shfl_xor(bj, off);
            if (ov < bv || (ov == bv && oj < bj)) { bv = ov; bj = oj; }
        }
        if (bj == j0) v0 = 3.0e38f;
        if (bj == j1) v1 = 3.0e38f;
        if (lane == k) myIdx = bj;
    }
    if (lane < KNN) idx[(size_t)node * KNN + lane] = myIdx;
}

// ---------------- MFMA node GEMM: T1 = x@Wd + bias, T2 = x@Wb (f32 out) ----------------
template<int O>
__global__ __launch_bounds__(256, 2) void node_gemm_mfma(
    const float* __restrict__ x, int F, int Fpad,
    const short* __restrict__ Wd, const short* __restrict__ Wb,
    const float* __restrict__ bias,
    float* __restrict__ T1, float* __restrict__ T2)
{
    constexpr int CPW = O / 64;
    __shared__ __align__(16) short Am[64][232];   // Fpad <= 224, +8 pad
    const int tid = threadIdx.x;
    const int lane = tid & 63, wave = tid >> 6;
    const int l15 = lane & 15, quad = lane >> 4;
    const int m0 = blockIdx.x * 64;
    for (int l = tid; l < 64 * Fpad; l += 256) {
        int m = l / Fpad, k = l - m * Fpad;
        Am[m][k] = (k < F) ? f2bs(x[(size_t)(m0 + m) * F + k]) : (short)0;
    }
    __syncthreads();
#pragma unroll
    for (int p = 0; p < 2; ++p) {
        const short* __restrict__ Wg = p ? Wb : Wd;
        float* __restrict__ T = p ? T2 : T1;
        v4f acc[4][CPW];
#pragma unroll
        for (int rt = 0; rt < 4; ++rt)
#pragma unroll
            for (int j = 0; j < CPW; ++j)
#pragma unroll
                for (int r = 0; r < 4; ++r) acc[rt][j][r] = 0.f;
        for (int k0 = 0; k0 < Fpad; k0 += 32) {
            v8s av[4];
#pragma unroll
            for (int rt = 0; rt < 4; ++rt)
                av[rt] = *(const v8s*)&Am[rt * 16 + l15][k0 + quad * 8];
#pragma unroll
            for (int j = 0; j < CPW; ++j) {
                int c = (wave * CPW + j) * 16 + l15;
                v8s bv = *(const v8s*)&Wg[(size_t)c * Fpad + k0 + quad * 8];
#pragma unroll
                for (int rt = 0; rt < 4; ++rt)
                    acc[rt][j] = __builtin_amdgcn_mfma_f32_16x16x32_bf16(av[rt], bv, acc[rt][j], 0, 0, 0);
            }
        }
#pragma unroll
        for (int j = 0; j < CPW; ++j) {
            int c = (wave * CPW + j) * 16 + l15;
            float bb = p ? 0.f : bias[c];
#pragma unroll
            for (int rt = 0; rt < 4; ++rt)
#pragma unroll
                for (int r = 0; r < 4; ++r)
                    T[(size_t)(m0 + rt * 16 + quad * 4 + r) * O + c] = acc[rt][j][r] + bb;
        }
    }
}

// ---------------- stats0: LDS-staged per-batch (T2 chunk + idx in LDS) ----------------
// Block = (batch b, channel chunk). Thread owns channel c, iterates its node group:
// T1[n][c] read once (coalesced); 16 neighbors from LDS (broadcast j, consecutive c).
template<int O>
__global__ __launch_bounds__(256) void stats0_lds_kernel(
    const float* __restrict__ T1, const float* __restrict__ T2,
    const int* __restrict__ idx, float* __restrict__ st0)
{
    constexpr int CH = (O > 128) ? 128 : O;   // channels per block (64 or 128)
    constexpr int NG = 256 / CH;              // node groups (2 or 4)
    constexpr int NPG = NN / NG;              // nodes per group (64 or 32)
    __shared__ float T2s[NN][CH];
    __shared__ int idxs[NN * KNN];
    __shared__ float redS[NG][CH], redQ[NG][CH];
    const int tid = threadIdx.x;
    const int nchunk = O / CH;
    const int b = blockIdx.x / nchunk;
    const int c0 = (blockIdx.x - b * nchunk) * CH;
    const int rep = blockIdx.x & (NREP - 1);

    for (int l = tid; l < NN * CH; l += 256) {
        int n = l / CH, c = l - n * CH;
        T2s[n][c] = T2[(size_t)(b * NN + n) * O + c0 + c];
    }
    for (int l = tid; l < NN * KNN; l += 256) idxs[l] = idx[(size_t)b * NN * KNN + l];
    __syncthreads();

    const int c = tid & (CH - 1);
    const int g = tid / CH;
    float s = 0.f, q = 0.f;
    for (int n = g * NPG; n < (g + 1) * NPG; ++n) {
        float t1 = T1[(size_t)(b * NN + n) * O + c0 + c];
#pragma unroll
        for (int k = 0; k < KNN; ++k) {
            int j = idxs[n * KNN + k];
            float v = t1 + T2s[j][c];
            s += v; q += v * v;
        }
    }
    redS[g][c] = s; redQ[g][c] = q;
    __syncthreads();
    if (g == 0) {
#pragma unroll
        for (int gg = 1; gg < NG; ++gg) { s += redS[gg][c]; q += redQ[gg][c]; }
        atomicAdd(&st0[rep * 512 + c0 + c], s);
        atomicAdd(&st0[rep * 512 + 256 + c0 + c], q);
    }
}

// ========================= column-owned MFMA GEMM kernels ==========================

// ---------------- gemm1: A0-build -> h1 = A0@W1 + b1 -> h + st1 ----------------
template<int O>
__global__ __launch_bounds__(256, 4) void gemm1_kernel(
    const float* __restrict__ T1, const float* __restrict__ T2, const int* __restrict__ idx,
    const short* __restrict__ W1, const float* __restrict__ bias1,
    const float* __restrict__ gm0, const float* __restrict__ bt0,
    const float* __restrict__ st0, float* __restrict__ st1,
    short* __restrict__ h, float inv_n)
{
    constexpr int CPW = O / 64;
    constexpr int OSH = (O == 64) ? 6 : (O == 128 ? 7 : 8);
    constexpr int AP = O + 8;
    __shared__ __align__(16) short Am[64][AP];
    __shared__ float T1s[4 * O];              // 4 node rows staged once
    __shared__ float sc0[O], sh0[O];
    __shared__ int gArr[64];
    const int tid = threadIdx.x;
    const int lane = tid & 63, wave = tid >> 6;
    const int l15 = lane & 15, quad = lane >> 4;
    const int e0 = blockIdx.x * 64;
    const int nb0 = e0 >> 4;
    const int rep = blockIdx.x & (NREP - 1);

    if (tid < O) {
        float sum, sq;
        fold_stats(st0, tid, sum, sq);
        float mean = sum * inv_n;
        float var = fmaxf(sq * inv_n - mean * mean, 0.f);
        float s = rsqrtf(var + 1e-5f) * gm0[tid];
        sc0[tid] = s; sh0[tid] = bt0[tid] - mean * s;
    }
    for (int l = tid; l < 4 * O; l += 256)
        T1s[l] = T1[(size_t)(nb0 + (l >> OSH)) * O + (l & (O - 1))];
    if (tid < 64) {
        int e = e0 + tid;
        int nd = e >> 4;
        gArr[tid] = ((nd >> 7) << 7) + idx[e];
    }
    __syncthreads();

    for (int l = tid; l < 32 * O; l += 256) {
        int m = l >> (OSH - 1);
        int c = (l & (O / 2 - 1)) * 2;
        const float2 t2 = *(const float2*)&T2[(size_t)gArr[m] * O + c];
        const int tb = (m >> 4) * O + c;
        float v0 = fmaxf((T1s[tb] + t2.x) * sc0[c] + sh0[c], 0.f);
        float v1 = fmaxf((T1s[tb + 1] + t2.y) * sc0[c + 1] + sh0[c + 1], 0.f);
        v2s pr; pr[0] = f2bs(v0); pr[1] = f2bs(v1);
        *(v2s*)&Am[m][c] = pr;
    }
    __syncthreads();

    v4f acc[4][CPW];
#pragma unroll
    for (int rt = 0; rt < 4; ++rt)
#pragma unroll
        for (int j = 0; j < CPW; ++j)
#pragma unroll
            for (int r = 0; r < 4; ++r) acc[rt][j][r] = 0.f;

    v8s bvc[CPW];
#pragma unroll
    for (int j = 0; j < CPW; ++j) {
        int c = (wave * CPW + j) * 16 + l15;
        bvc[j] = *(const v8s*)&W1[(size_t)c * O + quad * 8];
    }
#pragma unroll
    for (int k0 = 0; k0 < O; k0 += 32) {
        v8s bvn[CPW];
        if (k0 + 32 < O) {
#pragma unroll
            for (int j = 0; j < CPW; ++j) {
                int c = (wave * CPW + j) * 16 + l15;
                bvn[j] = *(const v8s*)&W1[(size_t)c * O + k0 + 32 + quad * 8];
            }
        }
        v8s av[4];
#pragma unroll
        for (int rt = 0; rt < 4; ++rt)
            av[rt] = *(const v8s*)&Am[rt * 16 + l15][k0 + quad * 8];
#pragma unroll
        for (int j = 0; j < CPW; ++j)
#pragma unroll
            for (int rt = 0; rt < 4; ++rt)
                acc[rt][j] = __builtin_amdgcn_mfma_f32_16x16x32_bf16(av[rt], bvc[j], acc[rt][j], 0, 0, 0);
        if (k0 + 32 < O) {
#pragma unroll
            for (int j = 0; j < CPW; ++j) bvc[j] = bvn[j];
        }
    }
#pragma unroll
    for (int j = 0; j < CPW; ++j) {
        float bb = bias1[(wave * CPW + j) * 16 + l15];
#pragma unroll
        for (int rt = 0; rt < 4; ++rt)
#pragma unroll
            for (int r = 0; r < 4; ++r) acc[rt][j][r] += bb;
    }
#pragma unroll
    for (int j = 0; j < CPW; ++j) {
        int c = (wave * CPW + j) * 16 + l15;
        float s = 0.f, q = 0.f;
#pragma unroll
        for (int rt = 0; rt < 4; ++rt)
#pragma unroll
            for (int r = 0; r < 4; ++r) { float v = acc[rt][j][r]; s += v; q += v * v; }
        s += __shfl_down(s, 32); s += __shfl_down(s, 16);
        q += __shfl_down(q, 32); q += __shfl_down(q, 16);
        if (quad == 0) { atomicAdd(&st1[rep * 512 + c], s); atomicAdd(&st1[rep * 512 + 256 + c], q); }
    }
    __syncthreads();
#pragma unroll
    for (int j = 0; j < CPW; ++j) {
        int c = (wave * CPW + j) * 16 + l15;
#pragma unroll
        for (int rt = 0; rt < 4; ++rt)
#pragma unroll
            for (int r = 0; r < 4; ++r)
                Am[rt * 16 + quad * 4 + r][c] = f2bs(acc[rt][j][r]);
    }
    __syncthreads();
    for (int g = tid; g < 8 * O; g += 256) {
        int row = g >> (OSH - 3);
        int c8 = (g & (O / 8 - 1)) * 8;
        *(v8s*)&h[(size_t)(e0 + row) * O + c8] = *(const v8s*)&Am[row][c8];
    }
}

// ---------------- gemm2: h -> bn1+relu -> h2 = A1@W2 + b2 -> h (in place) + st2 ------
template<int O>
__global__ __launch_bounds__(256, 4) void gemm2_kernel(
    short* __restrict__ h,
    const short* __restrict__ W2, const float* __restrict__ bias2,
    const float* __restrict__ gm1, const float* __restrict__ bt1,
    const float* __restrict__ st1, float* __restrict__ st2, float inv_n)
{
    constexpr int CPW = O / 64;
    constexpr int OSH = (O == 64) ? 6 : (O == 128 ? 7 : 8);
    constexpr int AP = O + 8;
    __shared__ __align__(16) short Am[64][AP];
    __shared__ float sc1[O], sh1[O];
    const int tid = threadIdx.x;
    const int lane = tid & 63, wave = tid >> 6;
    const int l15 = lane & 15, quad = lane >> 4;
    const int e0 = blockIdx.x * 64;
    const int rep = blockIdx.x & (NREP - 1);

    if (tid < O) {
        float sum, sq;
        fold_stats(st1, tid, sum, sq);
        float mean = sum * inv_n;
        float var = fmaxf(sq * inv_n - mean * mean, 0.f);
        float s = rsqrtf(var + 1e-5f) * gm1[tid];
        sc1[tid] = s; sh1[tid] = bt1[tid] - mean * s;
    }
    __syncthreads();

    for (int g = tid; g < 8 * O; g += 256) {
        int row = g >> (OSH - 3);
        int c8 = (g & (O / 8 - 1)) * 8;
        v8s hv = *(const v8s*)&h[(size_t)(e0 + row) * O + c8];
        v8s ov;
#pragma unroll
        for (int j = 0; j < 8; ++j) {
            float v = bs2f(hv[j]) * sc1[c8 + j] + sh1[c8 + j];
            ov[j] = f2bs(fmaxf(v, 0.f));
        }
        *(v8s*)&Am[row][c8] = ov;
    }
    __syncthreads();

    v4f acc[4][CPW];
#pragma unroll
    for (int rt = 0; rt < 4; ++rt)
#pragma unroll
        for (int j = 0; j < CPW; ++j)
#pragma unroll
            for (int r = 0; r < 4; ++r) acc[rt][j][r] = 0.f;

    v8s bvc[CPW];
#pragma unroll
    for (int j = 0; j < CPW; ++j) {
        int c = (wave * CPW + j) * 16 + l15;
        bvc[j] = *(const v8s*)&W2[(size_t)c * O + quad * 8];
    }
#pragma unroll
    for (int k0 = 0; k0 < O; k0 += 32) {
        v8s bvn[CPW];
        if (k0 + 32 < O) {
#pragma unroll
            for (int j = 0; j < CPW; ++j) {
                int c = (wave * CPW + j) * 16 + l15;
                bvn[j] = *(const v8s*)&W2[(size_t)c * O + k0 + 32 + quad * 8];
            }
        }
        v8s av[4];
#pragma unroll
        for (int rt = 0; rt < 4; ++rt)
            av[rt] = *(const v8s*)&Am[rt * 16 + l15][k0 + quad * 8];
#pragma unroll
        for (int j = 0; j < CPW; ++j)
#pragma unroll
            for (int rt = 0; rt < 4; ++rt)
                acc[rt][j] = __builtin_amdgcn_mfma_f32_16x16x32_bf16(av[rt], bvc[j], acc[rt][j], 0, 0, 0);
        if (k0 + 32 < O) {
#pragma unroll
            for (int j = 0; j < CPW; ++j) bvc[j] = bvn[j];
        }
    }
#pragma unroll
    for (int j = 0; j < CPW; ++j) {
        float bb = bias2[(wave * CPW + j) * 16 + l15];
#pragma unroll
        for (int rt = 0; rt < 4; ++rt)
#pragma unroll
            for (int r = 0; r < 4; ++r) acc[rt][j][r] += bb;
    }
#pragma unroll
    for (int j = 0; j < CPW; ++j) {
        int c = (wave * CPW + j) * 16 + l15;
        float s = 0.f, q = 0.f;
#pragma unroll
        for (int rt = 0; rt < 4; ++rt)
#pragma unroll
            for (int r = 0; r < 4; ++r) { float v = acc[rt][j][r]; s += v; q += v * v; }
        s += __shfl_down(s, 32); s += __shfl_down(s, 16);
        q += __shfl_down(q, 32); q += __shfl_down(q, 16);
        if (quad == 0) { atomicAdd(&st2[rep * 512 + c], s); atomicAdd(&st2[rep * 512 + 256 + c], q); }
    }
    __syncthreads();
#pragma unroll
    for (int j = 0; j < CPW; ++j) {
        int c = (wave * CPW + j) * 16 + l15;
#pragma unroll
        for (int rt = 0; rt < 4; ++rt)
#pragma unroll
            for (int r = 0; r < 4; ++r)
                Am[rt * 16 + quad * 4 + r][c] = f2bs(acc[rt][j][r]);
    }
    __syncthreads();
    for (int g = tid; g < 8 * O; g += 256) {
        int row = g >> (OSH - 3);
        int c8 = (g & (O / 8 - 1)) * 8;
        *(v8s*)&h[(size_t)(e0 + row) * O + c8] = *(const v8s*)&Am[row][c8];
    }
}

// ---------------- finish: stream h2, bn2+relu, k-mean, skip-concat ----------------
template<int O>
__global__ __launch_bounds__(256) void finish_kernel(
    const short* __restrict__ h,
    const float* __restrict__ st2, const float* __restrict__ gm2, const float* __restrict__ bt2,
    const float* __restrict__ xold, float* __restrict__ xnew, int F, float inv_n)
{
    constexpr int G = 256 / O;
    constexpr int RPG = 64 / G;
    constexpr int NPG = RPG / 16;
    const int tid = threadIdx.x;
    const int c = tid & (O - 1);
    const int rg = tid / O;
    const int e0 = blockIdx.x * 64;
    const int nb0 = e0 >> 4;
    float sum, sq;
    fold_stats(st2, c, sum, sq);
    float mean = sum * inv_n;
    float var = fmaxf(sq * inv_n - mean * mean, 0.f);
    float sc = rsqrtf(var + 1e-5f) * gm2[c];
    float sh = bt2[c] - mean * sc;
    float s[NPG];
#pragma unroll
    for (int i = 0; i < NPG; ++i) s[i] = 0.f;
    const int m0 = rg * RPG;
#pragma unroll
    for (int r = 0; r < RPG; ++r) {
        float v = bs2f(h[(size_t)(e0 + m0 + r) * O + c]) * sc + sh;
        s[r >> 4] += fmaxf(v, 0.f);
    }
    const int Cnew = O + F;
#pragma unroll
    for (int i = 0; i < NPG; ++i)
        xnew[(size_t)(nb0 + rg * NPG + i) * Cnew + c] = s[i] * (1.0f / 16.0f);
    for (int l = tid; l < 4 * F; l += 256) {
        int nd = l / F, cc = l - nd * F;
        xnew[(size_t)(nb0 + nd) * Cnew + O + cc] = xold[(size_t)(nb0 + nd) * F + cc];
    }
}

// ---------------- global mean pool ----------------
__global__ __launch_bounds__(256) void pool_kernel(const float* __restrict__ x, float* __restrict__ pooled, int C) {
    int b = blockIdx.x, t = threadIdx.x;
    for (int c = t; c < C; c += 256) {
        float s = 0.f;
        for (int n = 0; n < NN; ++n) s += x[(size_t)(b * NN + n) * C + c];
        pooled[b * C + c] = s * (1.0f / NN);
    }
}

// ---------------- fc1 + fc2 ----------------
__global__ __launch_bounds__(256) void fc_kernel(const float* __restrict__ pooled,
                                                 const float* __restrict__ W1, const float* __restrict__ b1,
                                                 const float* __restrict__ W2, const float* __restrict__ b2,
                                                 float* __restrict__ out, int C) {
    __shared__ float px[451];
    __shared__ float h1[256];
    int b = blockIdx.x, t = threadIdx.x;
    for (int c = t; c < C; c += 256) px[c] = pooled[b * C + c];
    __syncthreads();
    float s = 0.f;
    for (int i = 0; i < C; ++i) s += px[i] * W1[(size_t)i * 256 + t];
    h1[t] = s + b1[t];
    __syncthreads();
    if (t < 5) {
        float s2 = 0.f;
        for (int j = 0; j < 256; ++j) s2 += h1[j] * W2[j * 5 + t];
        out[b * 5 + t] = s2 + b2[t];
    }
}

extern "C" void kernel_launch(void* const* d_in, const int* in_sizes, int n_in,
                              void* d_out, int out_size, void* d_ws, size_t ws_size,
                              hipStream_t stream) {
    const float* xin = (const float*)d_in[0];
    auto Wp = [&](int c, int l) { return (const float*)d_in[1 + c * 12 + l * 4 + 0]; };
    auto Bp = [&](int c, int l) { return (const float*)d_in[1 + c * 12 + l * 4 + 1]; };
    auto Gp = [&](int c, int l) { return (const float*)d_in[1 + c * 12 + l * 4 + 2]; };
    auto Ep = [&](int c, int l) { return (const float*)d_in[1 + c * 12 + l * 4 + 3]; };
    const float* fcW1 = (const float*)d_in[37];
    const float* fcb1 = (const float*)d_in[38];
    const float* fcW2 = (const float*)d_in[39];
    const float* fcb2 = (const float*)d_in[40];

    char* ws = (char*)d_ws;
    size_t off = 0;
    auto alloc = [&](size_t bytes) -> void* {
        void* p = ws + off;
        off += (bytes + 255) & ~(size_t)255;
        return p;
    };
    const int M = M_NODES;
    float* x1     = (float*)alloc((size_t)M * 67 * 4);
    float* x2     = (float*)alloc((size_t)M * 195 * 4);
    float* x3     = (float*)alloc((size_t)M * 451 * 4);
    float* T1     = (float*)alloc((size_t)M * 256 * 4);
    float* T2     = (float*)alloc((size_t)M * 256 * 4);
    int*   idxb   = (int*)alloc((size_t)M * KNN * 4);
    float* stats  = (float*)alloc((size_t)3 * NREP * 512 * 4);   // st0/st1/st2 x 16 replicas
    float* pooled = (float*)alloc((size_t)NB * 451 * 4);
    short* W1b    = (short*)alloc(256 * 256 * 2);
    short* W2b    = (short*)alloc(256 * 256 * 2);
    short* W0d    = (short*)alloc(256 * 224 * 2);
    short* W0b    = (short*)alloc(256 * 224 * 2);
    float* d2buf  = (float*)alloc((size_t)M * NN * 4);
    float* sqbuf  = (float*)alloc((size_t)M * 4);
    short* hbuf   = (short*)alloc((size_t)NPOS * 256 * 2); // 134 MiB (ws verified to fit)
    (void)in_sizes; (void)n_in; (void)out_size; (void)ws_size;

    float* st0 = stats;
    float* st1 = stats + NREP * 512;
    float* st2 = stats + 2 * NREP * 512;
    const float inv_n = 1.0f / (float)NPOS;

    auto run_conv = [&](const float* xc, float* xn, int F, int D, int O, int c) {
        const int Fpad = (F + 31) & ~31;
        sq_kernel<<<M / 256, 256, 0, stream>>>(xc, F, D, sqbuf);
        dist_kernel<<<dim3(2, M / 64), 256, 0, stream>>>(xc, F, D, sqbuf, d2buf);
        knn_select_kernel<<<M / 4, 256, 0, stream>>>(d2buf, idxb);
        wconv0_kernel<<<(O * Fpad + 255) / 256, 256, 0, stream>>>(Wp(c, 0), W0d, W0b, F, Fpad, O);
        wconv_kernel<<<O * O / 256, 256, 0, stream>>>(Wp(c, 1), W1b, O);
        wconv_kernel<<<O * O / 256, 256, 0, stream>>>(Wp(c, 2), W2b, O);
        zero_kernel<<<3 * NREP * 2, 256, 0, stream>>>(stats, 3 * NREP * 512);
        const int grid = (int)(NPOS / 64);
        auto launch = [&](auto tag) {
            constexpr int OO = decltype(tag)::value;
            node_gemm_mfma<OO><<<M / 64, 256, 0, stream>>>(xc, F, Fpad, W0d, W0b, Bp(c, 0), T1, T2);
            stats0_lds_kernel<OO><<<NB * (OO > 128 ? 2 : 1), 256, 0, stream>>>(T1, T2, idxb, st0);
            gemm1_kernel<OO><<<grid, 256, 0, stream>>>(T1, T2, idxb, W1b, Bp(c, 1),
                Gp(c, 0), Ep(c, 0), st0, st1, hbuf, inv_n);
            gemm2_kernel<OO><<<grid, 256, 0, stream>>>(hbuf, W2b, Bp(c, 2),
                Gp(c, 1), Ep(c, 1), st1, st2, inv_n);
            finish_kernel<OO><<<grid, 256, 0, stream>>>(hbuf, st2, Gp(c, 2), Ep(c, 2),
                xc, xn, F, inv_n);
        };
        if (O == 64)       launch(std::integral_constant<int, 64>{});
        else if (O == 128) launch(std::integral_constant<int, 128>{});
        else               launch(std::integral_constant<int, 256>{});
    };

    run_conv(xin, x1, 3, 2, 64, 0);     // -> x1: C=67
    run_conv(x1, x2, 67, 67, 128, 1);   // -> x2: C=195
    run_conv(x2, x3, 195, 195, 256, 2); // -> x3: C=451
    pool_kernel<<<NB, 256, 0, stream>>>(x3, pooled, 451);
    fc_kernel<<<NB, 256, 0, stream>>>(pooled, fcW1, fcb1, fcW2, fcb2, (float*)d_out, 451);
}

// Round 14
// 990.575 us; speedup vs baseline: 8.4463x; 1.0356x over previous
//
#include <hip/hip_runtime.h>
#include <hip/hip_bf16.h>
#include <type_traits>

typedef __hip_bfloat16 bf16;
typedef short v8s __attribute__((ext_vector_type(8)));
typedef short v2s __attribute__((ext_vector_type(2)));
typedef float v4f __attribute__((ext_vector_type(4)));

__device__ __forceinline__ float b2f(bf16 v) { return __bfloat162float(v); }
__device__ __forceinline__ bf16  f2b(float v) { return __float2bfloat16(v); }
__device__ __forceinline__ short f2bs(float v) {
    bf16 b = f2b(v); short s; __builtin_memcpy(&s, &b, 2); return s;
}
__device__ __forceinline__ float bs2f(short s) {
    bf16 b; __builtin_memcpy(&b, &s, 2); return b2f(b);
}

#define NB 128
#define NN 128
#define KNN 16
#define M_NODES (NB * NN)          // 16384
#define NPOS ((long)M_NODES * KNN) // 262144 edge rows
#define NREP 16                    // stats replicas (atomic decontention)

__device__ __forceinline__ void fold_stats(const float* __restrict__ st, int c,
                                           float& sum, float& sq) {
    sum = 0.f; sq = 0.f;
#pragma unroll
    for (int r = 0; r < NREP; ++r) { sum += st[r * 512 + c]; sq += st[r * 512 + 256 + c]; }
}

// XCD batch-affinity swizzle for the 4096-tile edge kernels (32 tiles per batch).
// Assumes dispatch-slot -> XCD is round-robin (bid & 7). All 32 tiles of a batch
// land on one XCD -> that XCD's L2 holds only its 16 batches' T2/idx slices (~2 MB).
// Pure permutation of work -> correctness-neutral even if the mapping guess is wrong.
__device__ __forceinline__ int swz_tile(int bid) {
    int xcd = bid & 7;
    int slot = bid >> 3;               // 512 slots per XCD class
    int batch = xcd * 16 + (slot >> 5);
    int tile = slot & 31;
    return batch * 32 + tile;
}

// ---------------- zero a small float buffer ----------------
__global__ void zero_kernel(float* __restrict__ p, int n) {
    int i = blockIdx.x * blockDim.x + threadIdx.x;
    if (i < n) p[i] = 0.f;
}

// ---------------- edge-layer weight precompute: transposed bf16 ----------------
__global__ __launch_bounds__(256) void wconv_kernel(const float* __restrict__ W,
        short* __restrict__ Wt, int O) {
    int d = blockIdx.x * 256 + threadIdx.x;      // d = c*O + k
    int c = d / O, k = d - c * O;
    Wt[d] = f2bs(W[(size_t)k * O + c]);
}

// ---------------- layer-0 weight precompute: Wd = bf16(Wt-Wb), Wb, transposed [O,Fpad] --
__global__ __launch_bounds__(256) void wconv0_kernel(const float* __restrict__ W,
        short* __restrict__ Wd, short* __restrict__ Wb, int F, int Fpad, int O) {
    int d = blockIdx.x * 256 + threadIdx.x;      // d = c*Fpad + k
    if (d >= O * Fpad) return;
    int c = d / Fpad, k = d - c * Fpad;
    if (k < F) {
        float wt = W[(size_t)k * O + c];
        float wb = W[(size_t)(F + k) * O + c];
        Wd[d] = f2bs(wt - wb);
        Wb[d] = f2bs(wb);
    } else { Wd[d] = 0; Wb[d] = 0; }
}

// ---------------- kNN part 1: per-node squared norm ----------------
__global__ __launch_bounds__(256) void sq_kernel(const float* __restrict__ x, int C, int D,
                                                 float* __restrict__ sq) {
    int n = blockIdx.x * 256 + threadIdx.x;
    if (n >= M_NODES) return;
    float s = 0.f;
    for (int d = 0; d < D; ++d) { float v = x[(size_t)n * C + d]; s += v * v; }
    sq[n] = s;
}

// ---------------- kNN part 2: d2 tile GEMM (f32 exact) ----------------
__global__ __launch_bounds__(256) void dist_kernel(const float* __restrict__ x, int C, int D,
                                                   const float* __restrict__ sq,
                                                   float* __restrict__ d2) {
    __shared__ float As[16][65];
    __shared__ float Bs[16][65];
    const int tid = threadIdx.x;
    const int tx = tid & 15, ty = tid >> 4;
    const int m0 = blockIdx.y * 64;
    const int b  = m0 >> 7;
    const int c0 = blockIdx.x * 64;
    float acc[4][4];
#pragma unroll
    for (int r = 0; r < 4; ++r)
#pragma unroll
        for (int c = 0; c < 4; ++c) acc[r][c] = 0.f;
    for (int k0 = 0; k0 < D; k0 += 16) {
        for (int l = tid; l < 1024; l += 256) {
            int k = l & 15, m = l >> 4;
            int kk = k0 + k;
            As[k][m] = (kk < D) ? x[(size_t)(m0 + m) * C + kk] : 0.f;
            Bs[k][m] = (kk < D) ? x[(size_t)(b * NN + c0 + m) * C + kk] : 0.f;
        }
        __syncthreads();
        for (int k = 0; k < 16; ++k) {
            float av[4], bv[4];
#pragma unroll
            for (int r = 0; r < 4; ++r) av[r] = As[k][ty + 16 * r];
#pragma unroll
            for (int c = 0; c < 4; ++c) bv[c] = Bs[k][tx + 16 * c];
#pragma unroll
            for (int r = 0; r < 4; ++r)
#pragma unroll
                for (int c = 0; c < 4; ++c) acc[r][c] += av[r] * bv[c];
        }
        __syncthreads();
    }
#pragma unroll
    for (int r = 0; r < 4; ++r)
#pragma unroll
        for (int c = 0; c < 4; ++c) {
            int m = m0 + ty + 16 * r;
            int jl = c0 + tx + 16 * c;
            int jg = b * NN + jl;
            float v = sq[m] + sq[jg] - 2.0f * acc[r][c];
            if (m == jg) v += 1e9f;
            d2[(size_t)m * NN + jl] = v;
        }
}

// ---------------- kNN part 3: wave-per-node top-16 ----------------
__global__ __launch_bounds__(256) void knn_select_kernel(const float* __restrict__ d2,
                                                         int* __restrict__ idx) {
    const int node = blockIdx.x * 4 + (threadIdx.x >> 6);
    const int lane = threadIdx.x & 63;
    const float* row = d2 + (size_t)node * NN;
    float v0 = row[lane], v1 = row[lane + 64];
    int j0 = lane, j1 = lane + 64;
    int myIdx = 0;
#pragma unroll
    for (int k = 0; k < KNN; ++k) {
        float bv; int bj;
        if (v1 < v0 || (v1 == v0 && j1 < j0)) { bv = v1; bj = j1; }
        else                                 { bv = v0; bj = j0; }
#pragma unroll
        for (int off = 32; off; off >>= 1) {
            float ov = __shfl_xor(bv, off);
            int oj = __shfl_xor(bj, off);
            if (ov < bv || (ov == bv && oj < bj)) { bv = ov; bj = oj; }
        }
        if (bj == j0) v0 = 3.0e38f;
        if (bj == j1) v1 = 3.0e38f;
        if (lane == k) myIdx = bj;
    }
    if (lane < KNN) idx[(size_t)node * KNN + lane] = myIdx;
}

// ---------------- MFMA node GEMM: T1 = x@Wd + bias, T2 = x@Wb (f32 out) ----------------
template<int O>
__global__ __launch_bounds__(256, 2) void node_gemm_mfma(
    const float* __restrict__ x, int F, int Fpad,
    const short* __restrict__ Wd, const short* __restrict__ Wb,
    const float* __restrict__ bias,
    float* __restrict__ T1, float* __restrict__ T2)
{
    constexpr int CPW = O / 64;
    __shared__ __align__(16) short Am[64][232];   // Fpad <= 224, +8 pad
    const int tid = threadIdx.x;
    const int lane = tid & 63, wave = tid >> 6;
    const int l15 = lane & 15, quad = lane >> 4;
    const int m0 = blockIdx.x * 64;
    for (int l = tid; l < 64 * Fpad; l += 256) {
        int m = l / Fpad, k = l - m * Fpad;
        Am[m][k] = (k < F) ? f2bs(x[(size_t)(m0 + m) * F + k]) : (short)0;
    }
    __syncthreads();
#pragma unroll
    for (int p = 0; p < 2; ++p) {
        const short* __restrict__ Wg = p ? Wb : Wd;
        float* __restrict__ T = p ? T2 : T1;
        v4f acc[4][CPW];
#pragma unroll
        for (int rt = 0; rt < 4; ++rt)
#pragma unroll
            for (int j = 0; j < CPW; ++j)
#pragma unroll
                for (int r = 0; r < 4; ++r) acc[rt][j][r] = 0.f;
        for (int k0 = 0; k0 < Fpad; k0 += 32) {
            v8s av[4];
#pragma unroll
            for (int rt = 0; rt < 4; ++rt)
                av[rt] = *(const v8s*)&Am[rt * 16 + l15][k0 + quad * 8];
#pragma unroll
            for (int j = 0; j < CPW; ++j) {
                int c = (wave * CPW + j) * 16 + l15;
                v8s bv = *(const v8s*)&Wg[(size_t)c * Fpad + k0 + quad * 8];
#pragma unroll
                for (int rt = 0; rt < 4; ++rt)
                    acc[rt][j] = __builtin_amdgcn_mfma_f32_16x16x32_bf16(av[rt], bv, acc[rt][j], 0, 0, 0);
            }
        }
#pragma unroll
        for (int j = 0; j < CPW; ++j) {
            int c = (wave * CPW + j) * 16 + l15;
            float bb = p ? 0.f : bias[c];
#pragma unroll
            for (int rt = 0; rt < 4; ++rt)
#pragma unroll
                for (int r = 0; r < 4; ++r)
                    T[(size_t)(m0 + rt * 16 + quad * 4 + r) * O + c] = acc[rt][j][r] + bb;
        }
    }
}

// ---------------- stats0: LDS-staged per-batch ----------------
template<int O>
__global__ __launch_bounds__(256) void stats0_lds_kernel(
    const float* __restrict__ T1, const float* __restrict__ T2,
    const int* __restrict__ idx, float* __restrict__ st0)
{
    constexpr int CH = (O > 128) ? 128 : O;
    constexpr int NG = 256 / CH;
    constexpr int NPG = NN / NG;
    __shared__ float T2s[NN][CH];
    __shared__ int idxs[NN * KNN];
    __shared__ float redS[NG][CH], redQ[NG][CH];
    const int tid = threadIdx.x;
    const int nchunk = O / CH;
    const int b = blockIdx.x / nchunk;
    const int c0 = (blockIdx.x - b * nchunk) * CH;
    const int rep = blockIdx.x & (NREP - 1);

    for (int l = tid; l < NN * CH; l += 256) {
        int n = l / CH, c = l - n * CH;
        T2s[n][c] = T2[(size_t)(b * NN + n) * O + c0 + c];
    }
    for (int l = tid; l < NN * KNN; l += 256) idxs[l] = idx[(size_t)b * NN * KNN + l];
    __syncthreads();

    const int c = tid & (CH - 1);
    const int g = tid / CH;
    float s = 0.f, q = 0.f;
    for (int n = g * NPG; n < (g + 1) * NPG; ++n) {
        float t1 = T1[(size_t)(b * NN + n) * O + c0 + c];
#pragma unroll
        for (int k = 0; k < KNN; ++k) {
            int j = idxs[n * KNN + k];
            float v = t1 + T2s[j][c];
            s += v; q += v * v;
        }
    }
    redS[g][c] = s; redQ[g][c] = q;
    __syncthreads();
    if (g == 0) {
#pragma unroll
        for (int gg = 1; gg < NG; ++gg) { s += redS[gg][c]; q += redQ[gg][c]; }
        atomicAdd(&st0[rep * 512 + c0 + c], s);
        atomicAdd(&st0[rep * 512 + 256 + c0 + c], q);
    }
}

// ========================= column-owned MFMA GEMM kernels ==========================

// ---------------- gemm1: A0-build -> h1 = A0@W1 + b1 -> h + st1 ----------------
template<int O>
__global__ __launch_bounds__(256, 4) void gemm1_kernel(
    const float* __restrict__ T1, const float* __restrict__ T2, const int* __restrict__ idx,
    const short* __restrict__ W1, const float* __restrict__ bias1,
    const float* __restrict__ gm0, const float* __restrict__ bt0,
    const float* __restrict__ st0, float* __restrict__ st1,
    short* __restrict__ h, float inv_n)
{
    constexpr int CPW = O / 64;
    constexpr int OSH = (O == 64) ? 6 : (O == 128 ? 7 : 8);
    constexpr int AP = O + 8;
    __shared__ __align__(16) short Am[64][AP];
    __shared__ float T1s[4 * O];
    __shared__ float sc0[O], sh0[O];
    __shared__ int gArr[64];
    const int tid = threadIdx.x;
    const int lane = tid & 63, wave = tid >> 6;
    const int l15 = lane & 15, quad = lane >> 4;
    const int work = swz_tile(blockIdx.x);
    const int e0 = work * 64;
    const int nb0 = e0 >> 4;
    const int rep = work & (NREP - 1);

    // gArr first: it gates the T2 gather after the barrier.
    if (tid < 64) {
        int e = e0 + tid;
        int nd = e >> 4;
        gArr[tid] = ((nd >> 7) << 7) + idx[e];
    }
    for (int l = tid; l < 4 * O; l += 256)
        T1s[l] = T1[(size_t)(nb0 + (l >> OSH)) * O + (l & (O - 1))];
    if (tid < O) {
        float sum, sq;
        fold_stats(st0, tid, sum, sq);
        float mean = sum * inv_n;
        float var = fmaxf(sq * inv_n - mean * mean, 0.f);
        float s = rsqrtf(var + 1e-5f) * gm0[tid];
        sc0[tid] = s; sh0[tid] = bt0[tid] - mean * s;
    }
    __syncthreads();

    for (int l = tid; l < 32 * O; l += 256) {
        int m = l >> (OSH - 1);
        int c = (l & (O / 2 - 1)) * 2;
        const float2 t2 = *(const float2*)&T2[(size_t)gArr[m] * O + c];
        const int tb = (m >> 4) * O + c;
        float v0 = fmaxf((T1s[tb] + t2.x) * sc0[c] + sh0[c], 0.f);
        float v1 = fmaxf((T1s[tb + 1] + t2.y) * sc0[c + 1] + sh0[c + 1], 0.f);
        v2s pr; pr[0] = f2bs(v0); pr[1] = f2bs(v1);
        *(v2s*)&Am[m][c] = pr;
    }
    __syncthreads();

    v4f acc[4][CPW];
#pragma unroll
    for (int rt = 0; rt < 4; ++rt)
#pragma unroll
        for (int j = 0; j < CPW; ++j)
#pragma unroll
            for (int r = 0; r < 4; ++r) acc[rt][j][r] = 0.f;

    v8s bvc[CPW];
#pragma unroll
    for (int j = 0; j < CPW; ++j) {
        int c = (wave * CPW + j) * 16 + l15;
        bvc[j] = *(const v8s*)&W1[(size_t)c * O + quad * 8];
    }
#pragma unroll
    for (int k0 = 0; k0 < O; k0 += 32) {
        v8s bvn[CPW];
        if (k0 + 32 < O) {
#pragma unroll
            for (int j = 0; j < CPW; ++j) {
                int c = (wave * CPW + j) * 16 + l15;
                bvn[j] = *(const v8s*)&W1[(size_t)c * O + k0 + 32 + quad * 8];
            }
        }
        v8s av[4];
#pragma unroll
        for (int rt = 0; rt < 4; ++rt)
            av[rt] = *(const v8s*)&Am[rt * 16 + l15][k0 + quad * 8];
#pragma unroll
        for (int j = 0; j < CPW; ++j)
#pragma unroll
            for (int rt = 0; rt < 4; ++rt)
                acc[rt][j] = __builtin_amdgcn_mfma_f32_16x16x32_bf16(av[rt], bvc[j], acc[rt][j], 0, 0, 0);
        if (k0 + 32 < O) {
#pragma unroll
            for (int j = 0; j < CPW; ++j) bvc[j] = bvn[j];
        }
    }
#pragma unroll
    for (int j = 0; j < CPW; ++j) {
        float bb = bias1[(wave * CPW + j) * 16 + l15];
#pragma unroll
        for (int rt = 0; rt < 4; ++rt)
#pragma unroll
            for (int r = 0; r < 4; ++r) acc[rt][j][r] += bb;
    }
#pragma unroll
    for (int j = 0; j < CPW; ++j) {
        int c = (wave * CPW + j) * 16 + l15;
        float s = 0.f, q = 0.f;
#pragma unroll
        for (int rt = 0; rt < 4; ++rt)
#pragma unroll
            for (int r = 0; r < 4; ++r) { float v = acc[rt][j][r]; s += v; q += v * v; }
        s += __shfl_down(s, 32); s += __shfl_down(s, 16);
        q += __shfl_down(q, 32); q += __shfl_down(q, 16);
        if (quad == 0) { atomicAdd(&st1[rep * 512 + c], s); atomicAdd(&st1[rep * 512 + 256 + c], q); }
    }
    __syncthreads();
#pragma unroll
    for (int j = 0; j < CPW; ++j) {
        int c = (wave * CPW + j) * 16 + l15;
#pragma unroll
        for (int rt = 0; rt < 4; ++rt)
#pragma unroll
            for (int r = 0; r < 4; ++r)
                Am[rt * 16 + quad * 4 + r][c] = f2bs(acc[rt][j][r]);
    }
    __syncthreads();
    for (int g = tid; g < 8 * O; g += 256) {
        int row = g >> (OSH - 3);
        int c8 = (g & (O / 8 - 1)) * 8;
        *(v8s*)&h[(size_t)(e0 + row) * O + c8] = *(const v8s*)&Am[row][c8];
    }
}

// ---------------- gemm2: h -> bn1+relu -> h2 = A1@W2 + b2 -> h (in place) + st2 ------
template<int O>
__global__ __launch_bounds__(256, 4) void gemm2_kernel(
    short* __restrict__ h,
    const short* __restrict__ W2, const float* __restrict__ bias2,
    const float* __restrict__ gm1, const float* __restrict__ bt1,
    const float* __restrict__ st1, float* __restrict__ st2, float inv_n)
{
    constexpr int CPW = O / 64;
    constexpr int OSH = (O == 64) ? 6 : (O == 128 ? 7 : 8);
    constexpr int AP = O + 8;
    __shared__ __align__(16) short Am[64][AP];
    __shared__ float sc1[O], sh1[O];
    const int tid = threadIdx.x;
    const int lane = tid & 63, wave = tid >> 6;
    const int l15 = lane & 15, quad = lane >> 4;
    const int work = swz_tile(blockIdx.x);
    const int e0 = work * 64;
    const int rep = work & (NREP - 1);

    if (tid < O) {
        float sum, sq;
        fold_stats(st1, tid, sum, sq);
        float mean = sum * inv_n;
        float var = fmaxf(sq * inv_n - mean * mean, 0.f);
        float s = rsqrtf(var + 1e-5f) * gm1[tid];
        sc1[tid] = s; sh1[tid] = bt1[tid] - mean * s;
    }
    __syncthreads();

    for (int g = tid; g < 8 * O; g += 256) {
        int row = g >> (OSH - 3);
        int c8 = (g & (O / 8 - 1)) * 8;
        v8s hv = *(const v8s*)&h[(size_t)(e0 + row) * O + c8];
        v8s ov;
#pragma unroll
        for (int j = 0; j < 8; ++j) {
            float v = bs2f(hv[j]) * sc1[c8 + j] + sh1[c8 + j];
            ov[j] = f2bs(fmaxf(v, 0.f));
        }
        *(v8s*)&Am[row][c8] = ov;
    }
    __syncthreads();

    v4f acc[4][CPW];
#pragma unroll
    for (int rt = 0; rt < 4; ++rt)
#pragma unroll
        for (int j = 0; j < CPW; ++j)
#pragma unroll
            for (int r = 0; r < 4; ++r) acc[rt][j][r] = 0.f;

    v8s bvc[CPW];
#pragma unroll
    for (int j = 0; j < CPW; ++j) {
        int c = (wave * CPW + j) * 16 + l15;
        bvc[j] = *(const v8s*)&W2[(size_t)c * O + quad * 8];
    }
#pragma unroll
    for (int k0 = 0; k0 < O; k0 += 32) {
        v8s bvn[CPW];
        if (k0 + 32 < O) {
#pragma unroll
            for (int j = 0; j < CPW; ++j) {
                int c = (wave * CPW + j) * 16 + l15;
                bvn[j] = *(const v8s*)&W2[(size_t)c * O + k0 + 32 + quad * 8];
            }
        }
        v8s av[4];
#pragma unroll
        for (int rt = 0; rt < 4; ++rt)
            av[rt] = *(const v8s*)&Am[rt * 16 + l15][k0 + quad * 8];
#pragma unroll
        for (int j = 0; j < CPW; ++j)
#pragma unroll
            for (int rt = 0; rt < 4; ++rt)
                acc[rt][j] = __builtin_amdgcn_mfma_f32_16x16x32_bf16(av[rt], bvc[j], acc[rt][j], 0, 0, 0);
        if (k0 + 32 < O) {
#pragma unroll
            for (int j = 0; j < CPW; ++j) bvc[j] = bvn[j];
        }
    }
#pragma unroll
    for (int j = 0; j < CPW; ++j) {
        float bb = bias2[(wave * CPW + j) * 16 + l15];
#pragma unroll
        for (int rt = 0; rt < 4; ++rt)
#pragma unroll
            for (int r = 0; r < 4; ++r) acc[rt][j][r] += bb;
    }
#pragma unroll
    for (int j = 0; j < CPW; ++j) {
        int c = (wave * CPW + j) * 16 + l15;
        float s = 0.f, q = 0.f;
#pragma unroll
        for (int rt = 0; rt < 4; ++rt)
#pragma unroll
            for (int r = 0; r < 4; ++r) { float v = acc[rt][j][r]; s += v; q += v * v; }
        s += __shfl_down(s, 32); s += __shfl_down(s, 16);
        q += __shfl_down(q, 32); q += __shfl_down(q, 16);
        if (quad == 0) { atomicAdd(&st2[rep * 512 + c], s); atomicAdd(&st2[rep * 512 + 256 + c], q); }
    }
    __syncthreads();
#pragma unroll
    for (int j = 0; j < CPW; ++j) {
        int c = (wave * CPW + j) * 16 + l15;
#pragma unroll
        for (int rt = 0; rt < 4; ++rt)
#pragma unroll
            for (int r = 0; r < 4; ++r)
                Am[rt * 16 + quad * 4 + r][c] = f2bs(acc[rt][j][r]);
    }
    __syncthreads();
    for (int g = tid; g < 8 * O; g += 256) {
        int row = g >> (OSH - 3);
        int c8 = (g & (O / 8 - 1)) * 8;
        *(v8s*)&h[(size_t)(e0 + row) * O + c8] = *(const v8s*)&Am[row][c8];
    }
}

// ---------------- finish: stream h2, bn2+relu, k-mean, skip-concat ----------------
template<int O>
__global__ __launch_bounds__(256) void finish_kernel(
    const short* __restrict__ h,
    const float* __restrict__ st2, const float* __restrict__ gm2, const float* __restrict__ bt2,
    const float* __restrict__ xold, float* __restrict__ xnew, int F, float inv_n)
{
    constexpr int G = 256 / O;
    constexpr int RPG = 64 / G;
    constexpr int NPG = RPG / 16;
    const int tid = threadIdx.x;
    const int c = tid & (O - 1);
    const int rg = tid / O;
    const int work = swz_tile(blockIdx.x);
    const int e0 = work * 64;
    const int nb0 = e0 >> 4;
    float sum, sq;
    fold_stats(st2, c, sum, sq);
    float mean = sum * inv_n;
    float var = fmaxf(sq * inv_n - mean * mean, 0.f);
    float sc = rsqrtf(var + 1e-5f) * gm2[c];
    float sh = bt2[c] - mean * sc;
    float s[NPG];
#pragma unroll
    for (int i = 0; i < NPG; ++i) s[i] = 0.f;
    const int m0 = rg * RPG;
#pragma unroll
    for (int r = 0; r < RPG; ++r) {
        float v = bs2f(h[(size_t)(e0 + m0 + r) * O + c]) * sc + sh;
        s[r >> 4] += fmaxf(v, 0.f);
    }
    const int Cnew = O + F;
#pragma unroll
    for (int i = 0; i < NPG; ++i)
        xnew[(size_t)(nb0 + rg * NPG + i) * Cnew + c] = s[i] * (1.0f / 16.0f);
    for (int l = tid; l < 4 * F; l += 256) {
        int nd = l / F, cc = l - nd * F;
        xnew[(size_t)(nb0 + nd) * Cnew + O + cc] = xold[(size_t)(nb0 + nd) * F + cc];
    }
}

// ---------------- global mean pool ----------------
__global__ __launch_bounds__(256) void pool_kernel(const float* __restrict__ x, float* __restrict__ pooled, int C) {
    int b = blockIdx.x, t = threadIdx.x;
    for (int c = t; c < C; c += 256) {
        float s = 0.f;
        for (int n = 0; n < NN; ++n) s += x[(size_t)(b * NN + n) * C + c];
        pooled[b * C + c] = s * (1.0f / NN);
    }
}

// ---------------- fc1 + fc2 ----------------
__global__ __launch_bounds__(256) void fc_kernel(const float* __restrict__ pooled,
                                                 const float* __restrict__ W1, const float* __restrict__ b1,
                                                 const float* __restrict__ W2, const float* __restrict__ b2,
                                                 float* __restrict__ out, int C) {
    __shared__ float px[451];
    __shared__ float h1[256];
    int b = blockIdx.x, t = threadIdx.x;
    for (int c = t; c < C; c += 256) px[c] = pooled[b * C + c];
    __syncthreads();
    float s = 0.f;
    for (int i = 0; i < C; ++i) s += px[i] * W1[(size_t)i * 256 + t];
    h1[t] = s + b1[t];
    __syncthreads();
    if (t < 5) {
        float s2 = 0.f;
        for (int j = 0; j < 256; ++j) s2 += h1[j] * W2[j * 5 + t];
        out[b * 5 + t] = s2 + b2[t];
    }
}

extern "C" void kernel_launch(void* const* d_in, const int* in_sizes, int n_in,
                              void* d_out, int out_size, void* d_ws, size_t ws_size,
                              hipStream_t stream) {
    const float* xin = (const float*)d_in[0];
    auto Wp = [&](int c, int l) { return (const float*)d_in[1 + c * 12 + l * 4 + 0]; };
    auto Bp = [&](int c, int l) { return (const float*)d_in[1 + c * 12 + l * 4 + 1]; };
    auto Gp = [&](int c, int l) { return (const float*)d_in[1 + c * 12 + l * 4 + 2]; };
    auto Ep = [&](int c, int l) { return (const float*)d_in[1 + c * 12 + l * 4 + 3]; };
    const float* fcW1 = (const float*)d_in[37];
    const float* fcb1 = (const float*)d_in[38];
    const float* fcW2 = (const float*)d_in[39];
    const float* fcb2 = (const float*)d_in[40];

    char* ws = (char*)d_ws;
    size_t off = 0;
    auto alloc = [&](size_t bytes) -> void* {
        void* p = ws + off;
        off += (bytes + 255) & ~(size_t)255;
        return p;
    };
    const int M = M_NODES;
    float* x1     = (float*)alloc((size_t)M * 67 * 4);
    float* x2     = (float*)alloc((size_t)M * 195 * 4);
    float* x3     = (float*)alloc((size_t)M * 451 * 4);
    float* T1     = (float*)alloc((size_t)M * 256 * 4);
    float* T2     = (float*)alloc((size_t)M * 256 * 4);
    int*   idxb   = (int*)alloc((size_t)M * KNN * 4);
    float* stats  = (float*)alloc((size_t)3 * NREP * 512 * 4);
    float* pooled = (float*)alloc((size_t)NB * 451 * 4);
    short* W1b    = (short*)alloc(256 * 256 * 2);
    short* W2b    = (short*)alloc(256 * 256 * 2);
    short* W0d    = (short*)alloc(256 * 224 * 2);
    short* W0b    = (short*)alloc(256 * 224 * 2);
    float* d2buf  = (float*)alloc((size_t)M * NN * 4);
    float* sqbuf  = (float*)alloc((size_t)M * 4);
    short* hbuf   = (short*)alloc((size_t)NPOS * 256 * 2);
    (void)in_sizes; (void)n_in; (void)out_size; (void)ws_size;

    float* st0 = stats;
    float* st1 = stats + NREP * 512;
    float* st2 = stats + 2 * NREP * 512;
    const float inv_n = 1.0f / (float)NPOS;

    auto run_conv = [&](const float* xc, float* xn, int F, int D, int O, int c) {
        const int Fpad = (F + 31) & ~31;
        sq_kernel<<<M / 256, 256, 0, stream>>>(xc, F, D, sqbuf);
        dist_kernel<<<dim3(2, M / 64), 256, 0, stream>>>(xc, F, D, sqbuf, d2buf);
        knn_select_kernel<<<M / 4, 256, 0, stream>>>(d2buf, idxb);
        wconv0_kernel<<<(O * Fpad + 255) / 256, 256, 0, stream>>>(Wp(c, 0), W0d, W0b, F, Fpad, O);
        wconv_kernel<<<O * O / 256, 256, 0, stream>>>(Wp(c, 1), W1b, O);
        wconv_kernel<<<O * O / 256, 256, 0, stream>>>(Wp(c, 2), W2b, O);
        zero_kernel<<<3 * NREP * 2, 256, 0, stream>>>(stats, 3 * NREP * 512);
        const int grid = (int)(NPOS / 64);
        auto launch = [&](auto tag) {
            constexpr int OO = decltype(tag)::value;
            node_gemm_mfma<OO><<<M / 64, 256, 0, stream>>>(xc, F, Fpad, W0d, W0b, Bp(c, 0), T1, T2);
            stats0_lds_kernel<OO><<<NB * (OO > 128 ? 2 : 1), 256, 0, stream>>>(T1, T2, idxb, st0);
            gemm1_kernel<OO><<<grid, 256, 0, stream>>>(T1, T2, idxb, W1b, Bp(c, 1),
                Gp(c, 0), Ep(c, 0), st0, st1, hbuf, inv_n);
            gemm2_kernel<OO><<<grid, 256, 0, stream>>>(hbuf, W2b, Bp(c, 2),
                Gp(c, 1), Ep(c, 1), st1, st2, inv_n);
            finish_kernel<OO><<<grid, 256, 0, stream>>>(hbuf, st2, Gp(c, 2), Ep(c, 2),
                xc, xn, F, inv_n);
        };
        if (O == 64)       launch(std::integral_constant<int, 64>{});
        else if (O == 128) launch(std::integral_constant<int, 128>{});
        else               launch(std::integral_constant<int, 256>{});
    };

    run_conv(xin, x1, 3, 2, 64, 0);     // -> x1: C=67
    run_conv(x1, x2, 67, 67, 128, 1);   // -> x2: C=195
    run_conv(x2, x3, 195, 195, 256, 2); // -> x3: C=451
    pool_kernel<<<NB, 256, 0, stream>>>(x3, pooled, 451);
    fc_kernel<<<NB, 256, 0, stream>>>(pooled, fcW1, fcb1, fcW2, fcb2, (float*)d_out, 451);
}

// Round 15
// 870.884 us; speedup vs baseline: 9.6071x; 1.1374x over previous
//
#include <hip/hip_runtime.h>
#include <hip/hip_bf16.h>
#include <type_traits>

typedef __hip_bfloat16 bf16;
typedef short v8s __attribute__((ext_vector_type(8)));
typedef short v2s __attribute__((ext_vector_type(2)));
typedef float v4f __attribute__((ext_vector_type(4)));

__device__ __forceinline__ float b2f(bf16 v) { return __bfloat162float(v); }
__device__ __forceinline__ bf16  f2b(float v) { return __float2bfloat16(v); }
__device__ __forceinline__ short f2bs(float v) {
    bf16 b = f2b(v); short s; __builtin_memcpy(&s, &b, 2); return s;
}
__device__ __forceinline__ float bs2f(short s) {
    bf16 b; __builtin_memcpy(&b, &s, 2); return b2f(b);
}

#define NB 128
#define NN 128
#define KNN 16
#define M_NODES (NB * NN)          // 16384
#define NPOS ((long)M_NODES * KNN) // 262144 edge rows
#define NREP 16                    // stats replicas

__device__ __forceinline__ void fold_stats(const float* __restrict__ st, int c,
                                           float& sum, float& sq) {
    sum = 0.f; sq = 0.f;
#pragma unroll
    for (int r = 0; r < NREP; ++r) { sum += st[r * 512 + c]; sq += st[r * 512 + 256 + c]; }
}

// XCD batch-affinity swizzle. TPB = tiles per batch. All tiles of a batch land on
// one XCD (assuming slot->XCD round-robin). Pure permutation -> correctness-neutral.
template<int TPB>
__device__ __forceinline__ int swz_tile(int bid) {
    int xcd = bid & 7;
    int slot = bid >> 3;
    int batch = xcd * 16 + slot / TPB;
    int tile = slot - (slot / TPB) * TPB;
    return batch * TPB + tile;
}

// ---------------- fused prep: zero stats + layer0/1/2 weight precompute ----------------
__global__ __launch_bounds__(256) void prep_kernel(
    const float* __restrict__ W0, const float* __restrict__ W1, const float* __restrict__ W2,
    short* __restrict__ W0d, short* __restrict__ W0b,
    short* __restrict__ W1b, short* __restrict__ W2b,
    float* __restrict__ stats, int F, int Fpad, int O)
{
    int i = blockIdx.x * 256 + threadIdx.x;
    const int nz = 3 * NREP * 512;
    if (i < nz) { stats[i] = 0.f; return; }
    i -= nz;
    const int n0 = O * Fpad;
    if (i < n0) {
        int c = i / Fpad, k = i - c * Fpad;
        if (k < F) {
            float wt = W0[(size_t)k * O + c];
            float wb = W0[(size_t)(F + k) * O + c];
            W0d[i] = f2bs(wt - wb);
            W0b[i] = f2bs(wb);
        } else { W0d[i] = 0; W0b[i] = 0; }
        return;
    }
    i -= n0;
    const int n1 = O * O;
    if (i < n1) {
        int c = i / O, k = i - c * O;
        W1b[i] = f2bs(W1[(size_t)k * O + c]);
        return;
    }
    i -= n1;
    if (i < n1) {
        int c = i / O, k = i - c * O;
        W2b[i] = f2bs(W2[(size_t)k * O + c]);
    }
}

// ---------------- kNN: d2 tile GEMM with inline norms (bit-identical to sq+dist) ------
__global__ __launch_bounds__(256) void dist_kernel(const float* __restrict__ x, int C, int D,
                                                   float* __restrict__ d2) {
    __shared__ float As[16][65];
    __shared__ float Bs[16][65];
    const int tid = threadIdx.x;
    const int tx = tid & 15, ty = tid >> 4;
    const int m0 = blockIdx.y * 64;
    const int b  = m0 >> 7;
    const int c0 = blockIdx.x * 64;
    float acc[4][4], rn[4], cn[4];
#pragma unroll
    for (int r = 0; r < 4; ++r) { rn[r] = 0.f; cn[r] = 0.f;
#pragma unroll
        for (int c = 0; c < 4; ++c) acc[r][c] = 0.f; }
    for (int k0 = 0; k0 < D; k0 += 16) {
        for (int l = tid; l < 1024; l += 256) {
            int k = l & 15, m = l >> 4;
            int kk = k0 + k;
            As[k][m] = (kk < D) ? x[(size_t)(m0 + m) * C + kk] : 0.f;
            Bs[k][m] = (kk < D) ? x[(size_t)(b * NN + c0 + m) * C + kk] : 0.f;
        }
        __syncthreads();
        for (int k = 0; k < 16; ++k) {
            float av[4], bv[4];
#pragma unroll
            for (int r = 0; r < 4; ++r) { av[r] = As[k][ty + 16 * r]; rn[r] += av[r] * av[r]; }
#pragma unroll
            for (int c = 0; c < 4; ++c) { bv[c] = Bs[k][tx + 16 * c]; cn[c] += bv[c] * bv[c]; }
#pragma unroll
            for (int r = 0; r < 4; ++r)
#pragma unroll
                for (int c = 0; c < 4; ++c) acc[r][c] += av[r] * bv[c];
        }
        __syncthreads();
    }
#pragma unroll
    for (int r = 0; r < 4; ++r)
#pragma unroll
        for (int c = 0; c < 4; ++c) {
            int m = m0 + ty + 16 * r;
            int jl = c0 + tx + 16 * c;
            int jg = b * NN + jl;
            float v = rn[r] + cn[c] - 2.0f * acc[r][c];
            if (m == jg) v += 1e9f;
            d2[(size_t)m * NN + jl] = v;
        }
}

// ---------------- kNN: wave-per-node top-16 ----------------
__global__ __launch_bounds__(256) void knn_select_kernel(const float* __restrict__ d2,
                                                         int* __restrict__ idx) {
    const int node = blockIdx.x * 4 + (threadIdx.x >> 6);
    const int lane = threadIdx.x & 63;
    const float* row = d2 + (size_t)node * NN;
    float v0 = row[lane], v1 = row[lane + 64];
    int j0 = lane, j1 = lane + 64;
    int myIdx = 0;
#pragma unroll
    for (int k = 0; k < KNN; ++k) {
        float bv; int bj;
        if (v1 < v0 || (v1 == v0 && j1 < j0)) { bv = v1; bj = j1; }
        else                                 { bv = v0; bj = j0; }
#pragma unroll
        for (int off = 32; off; off >>= 1) {
            float ov = __shfl_xor(bv, off);
            int oj = __shfl_xor(bj, off);
            if (ov < bv || (ov == bv && oj < bj)) { bv = ov; bj = oj; }
        }
        if (bj == j0) v0 = 3.0e38f;
        if (bj == j1) v1 = 3.0e38f;
        if (lane == k) myIdx = bj;
    }
    if (lane < KNN) idx[(size_t)node * KNN + lane] = myIdx;
}

// ---------------- MFMA node GEMM: T1 = x@Wd + bias, T2 = x@Wb ----------------
template<int O>
__global__ __launch_bounds__(256, 2) void node_gemm_mfma(
    const float* __restrict__ x, int F, int Fpad,
    const short* __restrict__ Wd, const short* __restrict__ Wb,
    const float* __restrict__ bias,
    float* __restrict__ T1, float* __restrict__ T2)
{
    constexpr int CPW = O / 64;
    __shared__ __align__(16) short Am[64][232];
    const int tid = threadIdx.x;
    const int lane = tid & 63, wave = tid >> 6;
    const int l15 = lane & 15, quad = lane >> 4;
    const int m0 = blockIdx.x * 64;
    for (int l = tid; l < 64 * Fpad; l += 256) {
        int m = l / Fpad, k = l - m * Fpad;
        Am[m][k] = (k < F) ? f2bs(x[(size_t)(m0 + m) * F + k]) : (short)0;
    }
    __syncthreads();
#pragma unroll
    for (int p = 0; p < 2; ++p) {
        const short* __restrict__ Wg = p ? Wb : Wd;
        float* __restrict__ T = p ? T2 : T1;
        v4f acc[4][CPW];
#pragma unroll
        for (int rt = 0; rt < 4; ++rt)
#pragma unroll
            for (int j = 0; j < CPW; ++j)
#pragma unroll
                for (int r = 0; r < 4; ++r) acc[rt][j][r] = 0.f;
        for (int k0 = 0; k0 < Fpad; k0 += 32) {
#pragma unroll
            for (int rt = 0; rt < 4; ++rt) {
                v8s av = *(const v8s*)&Am[rt * 16 + l15][k0 + quad * 8];
#pragma unroll
                for (int j = 0; j < CPW; ++j) {
                    int c = (wave * CPW + j) * 16 + l15;
                    v8s bv = *(const v8s*)&Wg[(size_t)c * Fpad + k0 + quad * 8];
                    acc[rt][j] = __builtin_amdgcn_mfma_f32_16x16x32_bf16(av, bv, acc[rt][j], 0, 0, 0);
                }
            }
        }
#pragma unroll
        for (int j = 0; j < CPW; ++j) {
            int c = (wave * CPW + j) * 16 + l15;
            float bb = p ? 0.f : bias[c];
#pragma unroll
            for (int rt = 0; rt < 4; ++rt)
#pragma unroll
                for (int r = 0; r < 4; ++r)
                    T[(size_t)(m0 + rt * 16 + quad * 4 + r) * O + c] = acc[rt][j][r] + bb;
        }
    }
}

// ---------------- stats0: LDS-staged per-batch ----------------
template<int O>
__global__ __launch_bounds__(256) void stats0_lds_kernel(
    const float* __restrict__ T1, const float* __restrict__ T2,
    const int* __restrict__ idx, float* __restrict__ st0)
{
    constexpr int CH = (O > 128) ? 128 : O;
    constexpr int NG = 256 / CH;
    constexpr int NPG = NN / NG;
    __shared__ float T2s[NN][CH];
    __shared__ int idxs[NN * KNN];
    __shared__ float redS[NG][CH], redQ[NG][CH];
    const int tid = threadIdx.x;
    const int nchunk = O / CH;
    const int b = blockIdx.x / nchunk;
    const int c0 = (blockIdx.x - b * nchunk) * CH;
    const int rep = blockIdx.x & (NREP - 1);

    for (int l = tid; l < NN * CH; l += 256) {
        int n = l / CH, c = l - n * CH;
        T2s[n][c] = T2[(size_t)(b * NN + n) * O + c0 + c];
    }
    for (int l = tid; l < NN * KNN; l += 256) idxs[l] = idx[(size_t)b * NN * KNN + l];
    __syncthreads();

    const int c = tid & (CH - 1);
    const int g = tid / CH;
    float s = 0.f, q = 0.f;
    for (int n = g * NPG; n < (g + 1) * NPG; ++n) {
        float t1 = T1[(size_t)(b * NN + n) * O + c0 + c];
#pragma unroll
        for (int k = 0; k < KNN; ++k) {
            int j = idxs[n * KNN + k];
            float v = t1 + T2s[j][c];
            s += v; q += v * v;
        }
    }
    redS[g][c] = s; redQ[g][c] = q;
    __syncthreads();
    if (g == 0) {
#pragma unroll
        for (int gg = 1; gg < NG; ++gg) { s += redS[gg][c]; q += redQ[gg][c]; }
        atomicAdd(&st0[rep * 512 + c0 + c], s);
        atomicAdd(&st0[rep * 512 + 256 + c0 + c], q);
    }
}

// ========================= column-owned MFMA GEMM kernels ==========================
// ROWS = 16384/O rows per block (constant tile area); wave owns O/4 cols for all rows.

// ---------------- gemm1: A0-build -> h1 = A0@W1 + b1 -> h + st1 ----------------
template<int O, int ROWS>
__global__ __launch_bounds__(256, 4) void gemm1_kernel(
    const float* __restrict__ T1, const float* __restrict__ T2, const int* __restrict__ idx,
    const short* __restrict__ W1, const float* __restrict__ bias1,
    const float* __restrict__ gm0, const float* __restrict__ bt0,
    const float* __restrict__ st0, float* __restrict__ st1,
    short* __restrict__ h, float inv_n)
{
    constexpr int CPW = O / 64;
    constexpr int RT = ROWS / 16;
    constexpr int OSH = (O == 64) ? 6 : (O == 128 ? 7 : 8);
    constexpr int AP = O + 8;
    constexpr int TPB = 2048 / ROWS;
    __shared__ __align__(16) short Am[ROWS][AP];
    __shared__ float sc0[O], sh0[O];
    __shared__ int gArr[ROWS];
    const int tid = threadIdx.x;
    const int lane = tid & 63, wave = tid >> 6;
    const int l15 = lane & 15, quad = lane >> 4;
    const int work = swz_tile<TPB>(blockIdx.x);
    const int e0 = work * ROWS;
    const int nb0 = e0 >> 4;
    const int rep = work & (NREP - 1);

    for (int l = tid; l < ROWS; l += 256) {
        int e = e0 + l;
        int nd = e >> 4;
        gArr[l] = ((nd >> 7) << 7) + idx[e];
    }
    if (tid < O) {
        float sum, sq;
        fold_stats(st0, tid, sum, sq);
        float mean = sum * inv_n;
        float var = fmaxf(sq * inv_n - mean * mean, 0.f);
        float s = rsqrtf(var + 1e-5f) * gm0[tid];
        sc0[tid] = s; sh0[tid] = bt0[tid] - mean * s;
    }
    __syncthreads();

    for (int l = tid; l < ROWS * O / 2; l += 256) {
        int m = l >> (OSH - 1);
        int c = (l & (O / 2 - 1)) * 2;
        const float2 t1 = *(const float2*)&T1[(size_t)(nb0 + (m >> 4)) * O + c];
        const float2 t2 = *(const float2*)&T2[(size_t)gArr[m] * O + c];
        float v0 = fmaxf((t1.x + t2.x) * sc0[c] + sh0[c], 0.f);
        float v1 = fmaxf((t1.y + t2.y) * sc0[c + 1] + sh0[c + 1], 0.f);
        v2s pr; pr[0] = f2bs(v0); pr[1] = f2bs(v1);
        *(v2s*)&Am[m][c] = pr;
    }
    __syncthreads();

    v4f acc[RT][CPW];
#pragma unroll
    for (int rt = 0; rt < RT; ++rt)
#pragma unroll
        for (int j = 0; j < CPW; ++j)
#pragma unroll
            for (int r = 0; r < 4; ++r) acc[rt][j][r] = 0.f;

    v8s bvc[CPW];
#pragma unroll
    for (int j = 0; j < CPW; ++j) {
        int c = (wave * CPW + j) * 16 + l15;
        bvc[j] = *(const v8s*)&W1[(size_t)c * O + quad * 8];
    }
#pragma unroll
    for (int k0 = 0; k0 < O; k0 += 32) {
        v8s bvn[CPW];
        if (k0 + 32 < O) {
#pragma unroll
            for (int j = 0; j < CPW; ++j) {
                int c = (wave * CPW + j) * 16 + l15;
                bvn[j] = *(const v8s*)&W1[(size_t)c * O + k0 + 32 + quad * 8];
            }
        }
#pragma unroll
        for (int rt = 0; rt < RT; ++rt) {
            v8s av = *(const v8s*)&Am[rt * 16 + l15][k0 + quad * 8];
#pragma unroll
            for (int j = 0; j < CPW; ++j)
                acc[rt][j] = __builtin_amdgcn_mfma_f32_16x16x32_bf16(av, bvc[j], acc[rt][j], 0, 0, 0);
        }
        if (k0 + 32 < O) {
#pragma unroll
            for (int j = 0; j < CPW; ++j) bvc[j] = bvn[j];
        }
    }
#pragma unroll
    for (int j = 0; j < CPW; ++j) {
        float bb = bias1[(wave * CPW + j) * 16 + l15];
#pragma unroll
        for (int rt = 0; rt < RT; ++rt)
#pragma unroll
            for (int r = 0; r < 4; ++r) acc[rt][j][r] += bb;
    }
#pragma unroll
    for (int j = 0; j < CPW; ++j) {
        int c = (wave * CPW + j) * 16 + l15;
        float s = 0.f, q = 0.f;
#pragma unroll
        for (int rt = 0; rt < RT; ++rt)
#pragma unroll
            for (int r = 0; r < 4; ++r) { float v = acc[rt][j][r]; s += v; q += v * v; }
        s += __shfl_down(s, 32); s += __shfl_down(s, 16);
        q += __shfl_down(q, 32); q += __shfl_down(q, 16);
        if (quad == 0) { atomicAdd(&st1[rep * 512 + c], s); atomicAdd(&st1[rep * 512 + 256 + c], q); }
    }
    __syncthreads();
#pragma unroll
    for (int j = 0; j < CPW; ++j) {
        int c = (wave * CPW + j) * 16 + l15;
#pragma unroll
        for (int rt = 0; rt < RT; ++rt)
#pragma unroll
            for (int r = 0; r < 4; ++r)
                Am[rt * 16 + quad * 4 + r][c] = f2bs(acc[rt][j][r]);
    }
    __syncthreads();
    for (int g = tid; g < ROWS * O / 8; g += 256) {
        int row = g >> (OSH - 3);
        int c8 = (g & (O / 8 - 1)) * 8;
        *(v8s*)&h[(size_t)(e0 + row) * O + c8] = *(const v8s*)&Am[row][c8];
    }
}

// ---------------- gemm2: h -> bn1+relu -> h2 = A1@W2 + b2 -> h (in place) + st2 ------
template<int O, int ROWS>
__global__ __launch_bounds__(256, 4) void gemm2_kernel(
    short* __restrict__ h,
    const short* __restrict__ W2, const float* __restrict__ bias2,
    const float* __restrict__ gm1, const float* __restrict__ bt1,
    const float* __restrict__ st1, float* __restrict__ st2, float inv_n)
{
    constexpr int CPW = O / 64;
    constexpr int RT = ROWS / 16;
    constexpr int OSH = (O == 64) ? 6 : (O == 128 ? 7 : 8);
    constexpr int AP = O + 8;
    constexpr int TPB = 2048 / ROWS;
    __shared__ __align__(16) short Am[ROWS][AP];
    __shared__ float sc1[O], sh1[O];
    const int tid = threadIdx.x;
    const int lane = tid & 63, wave = tid >> 6;
    const int l15 = lane & 15, quad = lane >> 4;
    const int work = swz_tile<TPB>(blockIdx.x);
    const int e0 = work * ROWS;
    const int rep = work & (NREP - 1);

    if (tid < O) {
        float sum, sq;
        fold_stats(st1, tid, sum, sq);
        float mean = sum * inv_n;
        float var = fmaxf(sq * inv_n - mean * mean, 0.f);
        float s = rsqrtf(var + 1e-5f) * gm1[tid];
        sc1[tid] = s; sh1[tid] = bt1[tid] - mean * s;
    }
    __syncthreads();

    for (int g = tid; g < ROWS * O / 8; g += 256) {
        int row = g >> (OSH - 3);
        int c8 = (g & (O / 8 - 1)) * 8;
        v8s hv = *(const v8s*)&h[(size_t)(e0 + row) * O + c8];
        v8s ov;
#pragma unroll
        for (int j = 0; j < 8; ++j) {
            float v = bs2f(hv[j]) * sc1[c8 + j] + sh1[c8 + j];
            ov[j] = f2bs(fmaxf(v, 0.f));
        }
        *(v8s*)&Am[row][c8] = ov;
    }
    __syncthreads();

    v4f acc[RT][CPW];
#pragma unroll
    for (int rt = 0; rt < RT; ++rt)
#pragma unroll
        for (int j = 0; j < CPW; ++j)
#pragma unroll
            for (int r = 0; r < 4; ++r) acc[rt][j][r] = 0.f;

    v8s bvc[CPW];
#pragma unroll
    for (int j = 0; j < CPW; ++j) {
        int c = (wave * CPW + j) * 16 + l15;
        bvc[j] = *(const v8s*)&W2[(size_t)c * O + quad * 8];
    }
#pragma unroll
    for (int k0 = 0; k0 < O; k0 += 32) {
        v8s bvn[CPW];
        if (k0 + 32 < O) {
#pragma unroll
            for (int j = 0; j < CPW; ++j) {
                int c = (wave * CPW + j) * 16 + l15;
                bvn[j] = *(const v8s*)&W2[(size_t)c * O + k0 + 32 + quad * 8];
            }
        }
#pragma unroll
        for (int rt = 0; rt < RT; ++rt) {
            v8s av = *(const v8s*)&Am[rt * 16 + l15][k0 + quad * 8];
#pragma unroll
            for (int j = 0; j < CPW; ++j)
                acc[rt][j] = __builtin_amdgcn_mfma_f32_16x16x32_bf16(av, bvc[j], acc[rt][j], 0, 0, 0);
        }
        if (k0 + 32 < O) {
#pragma unroll
            for (int j = 0; j < CPW; ++j) bvc[j] = bvn[j];
        }
    }
#pragma unroll
    for (int j = 0; j < CPW; ++j) {
        float bb = bias2[(wave * CPW + j) * 16 + l15];
#pragma unroll
        for (int rt = 0; rt < RT; ++rt)
#pragma unroll
            for (int r = 0; r < 4; ++r) acc[rt][j][r] += bb;
    }
#pragma unroll
    for (int j = 0; j < CPW; ++j) {
        int c = (wave * CPW + j) * 16 + l15;
        float s = 0.f, q = 0.f;
#pragma unroll
        for (int rt = 0; rt < RT; ++rt)
#pragma unroll
            for (int r = 0; r < 4; ++r) { float v = acc[rt][j][r]; s += v; q += v * v; }
        s += __shfl_down(s, 32); s += __shfl_down(s, 16);
        q += __shfl_down(q, 32); q += __shfl_down(q, 16);
        if (quad == 0) { atomicAdd(&st2[rep * 512 + c], s); atomicAdd(&st2[rep * 512 + 256 + c], q); }
    }
    __syncthreads();
#pragma unroll
    for (int j = 0; j < CPW; ++j) {
        int c = (wave * CPW + j) * 16 + l15;
#pragma unroll
        for (int rt = 0; rt < RT; ++rt)
#pragma unroll
            for (int r = 0; r < 4; ++r)
                Am[rt * 16 + quad * 4 + r][c] = f2bs(acc[rt][j][r]);
    }
    __syncthreads();
    for (int g = tid; g < ROWS * O / 8; g += 256) {
        int row = g >> (OSH - 3);
        int c8 = (g & (O / 8 - 1)) * 8;
        *(v8s*)&h[(size_t)(e0 + row) * O + c8] = *(const v8s*)&Am[row][c8];
    }
}

// ---------------- finish: stream h2, bn2+relu, k-mean, skip-concat ----------------
template<int O, int ROWS>
__global__ __launch_bounds__(256) void finish_kernel(
    const short* __restrict__ h,
    const float* __restrict__ st2, const float* __restrict__ gm2, const float* __restrict__ bt2,
    const float* __restrict__ xold, float* __restrict__ xnew, int F, float inv_n)
{
    constexpr int G = 256 / O;          // channel-groups of threads
    constexpr int RPG = ROWS / G;       // rows per group (=64 for all shapes)
    constexpr int NPG = RPG / 16;       // nodes per group (=4)
    constexpr int NPB = ROWS / 16;      // nodes per block
    constexpr int TPB = 2048 / ROWS;
    const int tid = threadIdx.x;
    const int c = tid & (O - 1);
    const int rg = tid / O;
    const int work = swz_tile<TPB>(blockIdx.x);
    const int e0 = work * ROWS;
    const int nb0 = e0 >> 4;
    float sum, sq;
    fold_stats(st2, c, sum, sq);
    float mean = sum * inv_n;
    float var = fmaxf(sq * inv_n - mean * mean, 0.f);
    float sc = rsqrtf(var + 1e-5f) * gm2[c];
    float sh = bt2[c] - mean * sc;
    float s[NPG];
#pragma unroll
    for (int i = 0; i < NPG; ++i) s[i] = 0.f;
    const int m0 = rg * RPG;
#pragma unroll
    for (int r = 0; r < RPG; ++r) {
        float v = bs2f(h[(size_t)(e0 + m0 + r) * O + c]) * sc + sh;
        s[r >> 4] += fmaxf(v, 0.f);
    }
    const int Cnew = O + F;
#pragma unroll
    for (int i = 0; i < NPG; ++i)
        xnew[(size_t)(nb0 + rg * NPG + i) * Cnew + c] = s[i] * (1.0f / 16.0f);
    for (int l = tid; l < NPB * F; l += 256) {
        int nd = l / F, cc = l - nd * F;
        xnew[(size_t)(nb0 + nd) * Cnew + O + cc] = xold[(size_t)(nb0 + nd) * F + cc];
    }
}

// ---------------- global mean pool ----------------
__global__ __launch_bounds__(256) void pool_kernel(const float* __restrict__ x, float* __restrict__ pooled, int C) {
    int b = blockIdx.x, t = threadIdx.x;
    for (int c = t; c < C; c += 256) {
        float s = 0.f;
        for (int n = 0; n < NN; ++n) s += x[(size_t)(b * NN + n) * C + c];
        pooled[b * C + c] = s * (1.0f / NN);
    }
}

// ---------------- fc1 + fc2 ----------------
__global__ __launch_bounds__(256) void fc_kernel(const float* __restrict__ pooled,
                                                 const float* __restrict__ W1, const float* __restrict__ b1,
                                                 const float* __restrict__ W2, const float* __restrict__ b2,
                                                 float* __restrict__ out, int C) {
    __shared__ float px[451];
    __shared__ float h1[256];
    int b = blockIdx.x, t = threadIdx.x;
    for (int c = t; c < C; c += 256) px[c] = pooled[b * C + c];
    __syncthreads();
    float s = 0.f;
    for (int i = 0; i < C; ++i) s += px[i] * W1[(size_t)i * 256 + t];
    h1[t] = s + b1[t];
    __syncthreads();
    if (t < 5) {
        float s2 = 0.f;
        for (int j = 0; j < 256; ++j) s2 += h1[j] * W2[j * 5 + t];
        out[b * 5 + t] = s2 + b2[t];
    }
}

extern "C" void kernel_launch(void* const* d_in, const int* in_sizes, int n_in,
                              void* d_out, int out_size, void* d_ws, size_t ws_size,
                              hipStream_t stream) {
    const float* xin = (const float*)d_in[0];
    auto Wp = [&](int c, int l) { return (const float*)d_in[1 + c * 12 + l * 4 + 0]; };
    auto Bp = [&](int c, int l) { return (const float*)d_in[1 + c * 12 + l * 4 + 1]; };
    auto Gp = [&](int c, int l) { return (const float*)d_in[1 + c * 12 + l * 4 + 2]; };
    auto Ep = [&](int c, int l) { return (const float*)d_in[1 + c * 12 + l * 4 + 3]; };
    const float* fcW1 = (const float*)d_in[37];
    const float* fcb1 = (const float*)d_in[38];
    const float* fcW2 = (const float*)d_in[39];
    const float* fcb2 = (const float*)d_in[40];

    char* ws = (char*)d_ws;
    size_t off = 0;
    auto alloc = [&](size_t bytes) -> void* {
        void* p = ws + off;
        off += (bytes + 255) & ~(size_t)255;
        return p;
    };
    const int M = M_NODES;
    float* x1     = (float*)alloc((size_t)M * 67 * 4);
    float* x2     = (float*)alloc((size_t)M * 195 * 4);
    float* x3     = (float*)alloc((size_t)M * 451 * 4);
    float* T1     = (float*)alloc((size_t)M * 256 * 4);
    float* T2     = (float*)alloc((size_t)M * 256 * 4);
    int*   idxb   = (int*)alloc((size_t)M * KNN * 4);
    float* stats  = (float*)alloc((size_t)3 * NREP * 512 * 4);
    float* pooled = (float*)alloc((size_t)NB * 451 * 4);
    short* W1b    = (short*)alloc(256 * 256 * 2);
    short* W2b    = (short*)alloc(256 * 256 * 2);
    short* W0d    = (short*)alloc(256 * 224 * 2);
    short* W0b    = (short*)alloc(256 * 224 * 2);
    float* d2buf  = (float*)alloc((size_t)M * NN * 4);
    short* hbuf   = (short*)alloc((size_t)NPOS * 256 * 2);
    (void)in_sizes; (void)n_in; (void)out_size; (void)ws_size;

    float* st0 = stats;
    float* st1 = stats + NREP * 512;
    float* st2 = stats + 2 * NREP * 512;
    const float inv_n = 1.0f / (float)NPOS;

    auto run_conv = [&](const float* xc, float* xn, int F, int D, int O, int c) {
        const int Fpad = (F + 31) & ~31;
        dist_kernel<<<dim3(2, M / 64), 256, 0, stream>>>(xc, F, D, d2buf);
        knn_select_kernel<<<M / 4, 256, 0, stream>>>(d2buf, idxb);
        const int prepN = 3 * NREP * 512 + O * Fpad + 2 * O * O;
        prep_kernel<<<(prepN + 255) / 256, 256, 0, stream>>>(Wp(c, 0), Wp(c, 1), Wp(c, 2),
            W0d, W0b, W1b, W2b, stats, F, Fpad, O);
        auto launch = [&](auto tag) {
            constexpr int OO = decltype(tag)::value;
            constexpr int RR = 16384 / OO;        // 256/128/64 rows per tile
            const int grid = (int)(NPOS / RR);
            node_gemm_mfma<OO><<<M / 64, 256, 0, stream>>>(xc, F, Fpad, W0d, W0b, Bp(c, 0), T1, T2);
            stats0_lds_kernel<OO><<<NB * (OO > 128 ? 2 : 1), 256, 0, stream>>>(T1, T2, idxb, st0);
            gemm1_kernel<OO, RR><<<grid, 256, 0, stream>>>(T1, T2, idxb, W1b, Bp(c, 1),
                Gp(c, 0), Ep(c, 0), st0, st1, hbuf, inv_n);
            gemm2_kernel<OO, RR><<<grid, 256, 0, stream>>>(hbuf, W2b, Bp(c, 2),
                Gp(c, 1), Ep(c, 1), st1, st2, inv_n);
            finish_kernel<OO, RR><<<grid, 256, 0, stream>>>(hbuf, st2, Gp(c, 2), Ep(c, 2),
                xc, xn, F, inv_n);
        };
        if (O == 64)       launch(std::integral_constant<int, 64>{});
        else if (O == 128) launch(std::integral_constant<int, 128>{});
        else               launch(std::integral_constant<int, 256>{});
    };

    run_conv(xin, x1, 3, 2, 64, 0);     // -> x1: C=67
    run_conv(x1, x2, 67, 67, 128, 1);   // -> x2: C=195
    run_conv(x2, x3, 195, 195, 256, 2); // -> x3: C=451
    pool_kernel<<<NB, 256, 0, stream>>>(x3, pooled, 451);
    fc_kernel<<<NB, 256, 0, stream>>>(pooled, fcW1, fcb1, fcW2, fcb2, (float*)d_out, 451);
}